// Round 3
// baseline (1929.768 us; speedup 1.0000x reference)
//
#include <hip/hip_runtime.h>
#include <hip/hip_bf16.h>

#define D_MODEL 768
#define SEQ     1024
#define NB      8
#define NHEAD   12
#define HS      64
#define NLAYER  4
#define DFF     3072
#define NCLS    16
#define MROWS   (NB*SEQ)   // 8192

typedef float f32x4  __attribute__((ext_vector_type(4)));
typedef short bf16x8 __attribute__((ext_vector_type(8)));

__device__ __forceinline__ short f2bf_s(float x) {
    __hip_bfloat16 h = __float2bfloat16(x);
    union { __hip_bfloat16 h; short s; } u; u.h = h; return u.s;
}

// async global->LDS, 16B per lane; lds base must be wave-uniform (HW adds lane*16)
__device__ __forceinline__ void gld16(const void* g, void* l) {
    __builtin_amdgcn_global_load_lds((const __attribute__((address_space(1))) void*)g,
                                     (__attribute__((address_space(3))) void*)l, 16, 0, 0);
}

// ---------------------------------------------------------------- embedding
__global__ __launch_bounds__(256) void embed_kernel(
    const int* __restrict__ x, const float* __restrict__ tok,
    const float* __restrict__ pos, float* __restrict__ h)
{
    int row = blockIdx.x;
    int s   = row & (SEQ - 1);
    int t   = threadIdx.x;
    int id  = x[row];
    const float* te = tok + (size_t)id * D_MODEL;
    const float* pe = pos + (size_t)s  * D_MODEL;
    float* hr = h + (size_t)row * D_MODEL;
    for (int d = t; d < D_MODEL; d += 256) hr[d] = te[d] + pe[d];
}

// ---------------------------------------------------------------- layernorm
template<int BF16OUT>
__global__ __launch_bounds__(256) void ln_kernel(
    const float* __restrict__ in, const float* __restrict__ w,
    const float* __restrict__ b, void* __restrict__ outv,
    int row_stride, int row_offset)
{
    __shared__ float part[8];
    int r = blockIdx.x;
    const float* xr = in + (size_t)(r * row_stride + row_offset) * D_MODEL;
    int t = threadIdx.x, wave = t >> 6, lane = t & 63;
    float v0 = xr[t], v1 = xr[t + 256], v2 = xr[t + 512];
    float s = v0 + v1 + v2;
    #pragma unroll
    for (int off = 32; off; off >>= 1) s += __shfl_xor(s, off);
    if (lane == 0) part[wave] = s;
    __syncthreads();
    float mu = (part[0] + part[1] + part[2] + part[3]) * (1.f / D_MODEL);
    float d0 = v0 - mu, d1 = v1 - mu, d2 = v2 - mu;
    float q = d0*d0 + d1*d1 + d2*d2;
    #pragma unroll
    for (int off = 32; off; off >>= 1) q += __shfl_xor(q, off);
    if (lane == 0) part[4 + wave] = q;
    __syncthreads();
    float rstd = rsqrtf((part[4] + part[5] + part[6] + part[7]) * (1.f / D_MODEL) + 1e-5f);
    float y0 = d0 * rstd * w[t]       + b[t];
    float y1 = d1 * rstd * w[t + 256] + b[t + 256];
    float y2 = d2 * rstd * w[t + 512] + b[t + 512];
    if (BF16OUT) {
        __hip_bfloat16* yr = (__hip_bfloat16*)outv + (size_t)r * D_MODEL;
        yr[t] = __float2bfloat16(y0); yr[t+256] = __float2bfloat16(y1); yr[t+512] = __float2bfloat16(y2);
    } else {
        float* yr = (float*)outv + (size_t)r * D_MODEL;
        yr[t] = y0; yr[t+256] = y1; yr[t+512] = y2;
    }
}

// --------------------------------------------- weight convert+transpose to bf16
template<int MODE>
__global__ __launch_bounds__(256) void convw_kernel(
    const float* __restrict__ W, __hip_bfloat16* __restrict__ BT,
    int K, int N, size_t in_stride, size_t out_stride)
{
    __shared__ __hip_bfloat16 sT[64][72];
    W  += (size_t)blockIdx.z * in_stride;
    BT += (size_t)blockIdx.z * out_stride;
    int k0 = blockIdx.x * 64, n0 = blockIdx.y * 64;
    int t = threadIdx.x;
    int kl = t >> 4, nl4 = (t & 15) * 4;
    #pragma unroll
    for (int i = 0; i < 4; i++) {
        int k = k0 + kl + i * 16;
        int n = n0 + nl4;
        const float* src = (MODE == 0) ? (W + (size_t)k * N + n)
                                       : (W + ((size_t)(n >> 6) * K + k) * 64 + (n & 63));
        float4 v = *(const float4*)src;
        sT[nl4 + 0][kl + i*16] = __float2bfloat16(v.x);
        sT[nl4 + 1][kl + i*16] = __float2bfloat16(v.y);
        sT[nl4 + 2][kl + i*16] = __float2bfloat16(v.z);
        sT[nl4 + 3][kl + i*16] = __float2bfloat16(v.w);
    }
    __syncthreads();
    int nl = t >> 2, seg = (t & 3) * 16;
    uint4* dst = (uint4*)(BT + (size_t)(n0 + nl) * K + k0 + seg);
    dst[0] = *(uint4*)&sT[nl][seg];
    dst[1] = *(uint4*)&sT[nl][seg + 8];
}

// ---------------------------------------------------------------- 256x256 8-wave phase-split GEMM
// BM=BN=256, BK=64, 8 waves (2Mx4N), 512 thr, LDS 128KB (2 K-tile dbuf).
// Per K-tile: ONE vmcnt(0) + ONE barrier, then 4 lgkm-counted phases:
//   barrier -> issue bF(8)+a01(4) ds_reads -> issue STAGE(t+1) 8 gld16 ->
//   p0: issue a23; lgkmcnt(4); 16 MFMA(mi0,1)   p1: issue a45; lgkmcnt(4); MFMA(mi2,3)
//   p2: issue a67; lgkmcnt(4); MFMA(mi4,5)      p3: lgkmcnt(0); MFMA(mi6,7)
// Sync proof: own lgkmcnt(0)@p3 + next-tile barrier => all waves' reads of buf[t-1]
// done before STAGE(t+1) overwrites it; vmcnt(0)+barrier => all stage(t) landed
// before any ds_read of tile t. vmcnt(0) has a full tile of compute in front of it
// (stage issued right after previous barrier). setprio(1) around MFMA clusters (T5).
// OMODE: 1 = QKV bf16 scatter  2 = bf16 out (+bias,relu)  3 = split-K f32 atomicAdd
template<int OMODE>
__global__ __launch_bounds__(512, 1) void gemm256(
    const __hip_bfloat16* __restrict__ A, const __hip_bfloat16* __restrict__ BT,
    const float* __restrict__ bias, const float* __restrict__ res,
    void* __restrict__ Cv, int M, int N, int K, int relu)
{
    __shared__ short sA[2][256 * 64];
    __shared__ short sB[2][256 * 64];
    int t = threadIdx.x;
    int wave = t >> 6, lane = t & 63;
    int l16 = lane & 15, quad = (lane >> 4) & 3;
    int wm = wave >> 2, wn = wave & 3;
    int bm = blockIdx.x * 256, bn = blockIdx.y * 256;

    int kbeg = 0, kend = K;
    if (OMODE == 3) { int KS = K >> 1; kbeg = blockIdx.z * KS; kend = kbeg + KS; }
    int nt = (kend - kbeg) >> 6;

    int rowL = lane >> 3;
    int sgl = ((lane & 7) ^ ((lane >> 3) & 7)) * 8;   // XOR-swizzled 16B seg (shorts)

    const f32x4 zf = {0.f, 0.f, 0.f, 0.f};
    f32x4 acc[8][4];
    #pragma unroll
    for (int mi = 0; mi < 8; mi++)
        #pragma unroll
        for (int ni = 0; ni < 4; ni++) acc[mi][ni] = zf;

    #define STAGE256(d, kk) do { \
        _Pragma("unroll") \
        for (int i = 0; i < 4; i++) { \
            int c = i * 8 + wave; \
            gld16(A  + (size_t)(bm + c * 8 + rowL) * K + (kk) + sgl, &sA[d][c * 512]); \
            gld16(BT + (size_t)(bn + c * 8 + rowL) * K + (kk) + sgl, &sB[d][c * 512]); \
        } \
    } while (0)

    #define LDA256(d, mi, kk) \
        (*(const bf16x8*)&sA[d][((wm << 7) + (mi) * 16 + l16) * 64 + ((((kk) * 4 + quad) ^ (l16 & 7)) * 8)])
    #define LDB256(d, ni, kk) \
        (*(const bf16x8*)&sB[d][((wn << 6) + (ni) * 16 + l16) * 64 + ((((kk) * 4 + quad) ^ (l16 & 7)) * 8)])

    #define MFMA_PAIR(m0) do { \
        _Pragma("unroll") \
        for (int mi = (m0); mi < (m0) + 2; mi++) \
            _Pragma("unroll") \
            for (int ni = 0; ni < 4; ni++) \
                _Pragma("unroll") \
                for (int kk = 0; kk < 2; kk++) \
                    acc[mi][ni] = __builtin_amdgcn_mfma_f32_16x16x32_bf16(aF[mi][kk], bF[ni][kk], acc[mi][ni], 0, 0, 0); \
    } while (0)

    STAGE256(0, kbeg);

    #pragma unroll 1
    for (int t2 = 0; t2 < nt; ++t2) {
        int d = t2 & 1;
        asm volatile("s_waitcnt vmcnt(0)" ::: "memory");
        __builtin_amdgcn_sched_barrier(0);
        __builtin_amdgcn_s_barrier();
        __builtin_amdgcn_sched_barrier(0);

        bf16x8 bF[4][2], aF[8][2];
        // group 1: 12 reads (all bF + a0,a1)
        #pragma unroll
        for (int ni = 0; ni < 4; ni++)
            #pragma unroll
            for (int kk = 0; kk < 2; kk++) bF[ni][kk] = LDB256(d, ni, kk);
        #pragma unroll
        for (int kk = 0; kk < 2; kk++) { aF[0][kk] = LDA256(d, 0, kk); aF[1][kk] = LDA256(d, 1, kk); }

        if (t2 + 1 < nt) STAGE256(d ^ 1, kbeg + (t2 + 1) * 64);   // full tile of compute before next vmcnt

        // phase 0
        #pragma unroll
        for (int kk = 0; kk < 2; kk++) { aF[2][kk] = LDA256(d, 2, kk); aF[3][kk] = LDA256(d, 3, kk); }
        asm volatile("s_waitcnt lgkmcnt(4)" ::: "memory");
        __builtin_amdgcn_sched_barrier(0);
        __builtin_amdgcn_s_setprio(1); MFMA_PAIR(0); __builtin_amdgcn_s_setprio(0);
        // phase 1
        #pragma unroll
        for (int kk = 0; kk < 2; kk++) { aF[4][kk] = LDA256(d, 4, kk); aF[5][kk] = LDA256(d, 5, kk); }
        asm volatile("s_waitcnt lgkmcnt(4)" ::: "memory");
        __builtin_amdgcn_sched_barrier(0);
        __builtin_amdgcn_s_setprio(1); MFMA_PAIR(2); __builtin_amdgcn_s_setprio(0);
        // phase 2
        #pragma unroll
        for (int kk = 0; kk < 2; kk++) { aF[6][kk] = LDA256(d, 6, kk); aF[7][kk] = LDA256(d, 7, kk); }
        asm volatile("s_waitcnt lgkmcnt(4)" ::: "memory");
        __builtin_amdgcn_sched_barrier(0);
        __builtin_amdgcn_s_setprio(1); MFMA_PAIR(4); __builtin_amdgcn_s_setprio(0);
        // phase 3
        asm volatile("s_waitcnt lgkmcnt(0)" ::: "memory");
        __builtin_amdgcn_sched_barrier(0);
        __builtin_amdgcn_s_setprio(1); MFMA_PAIR(6); __builtin_amdgcn_s_setprio(0);
    }
    #undef STAGE256
    #undef LDA256
    #undef LDB256
    #undef MFMA_PAIR

    #pragma unroll
    for (int mi = 0; mi < 8; mi++) {
        #pragma unroll
        for (int ni = 0; ni < 4; ni++) {
            int row0 = bm + wm * 128 + mi * 16 + quad * 4;
            int col  = bn + wn * 64 + ni * 16 + l16;
            #pragma unroll
            for (int r = 0; r < 4; r++) {
                int row = row0 + r;
                float v = acc[mi][ni][r];
                if (OMODE == 3) {
                    float* C = (float*)Cv;
                    if (blockIdx.z == 0 && bias) v += bias[col];
                    unsafeAtomicAdd(&C[(size_t)row * N + col], v);
                    continue;
                }
                if (bias) v += bias[col];
                if (relu) v = fmaxf(v, 0.f);
                if (OMODE == 1) {
                    int which = col / D_MODEL, cc = col % D_MODEL;
                    int bb = row >> 10, ss = row & 1023, hh = cc >> 6, e = cc & 63;
                    ((__hip_bfloat16*)Cv)[(size_t)which * MROWS * D_MODEL +
                        (((size_t)(bb * NHEAD + hh)) * SEQ + ss) * HS + e] = __float2bfloat16(v);
                } else {
                    ((__hip_bfloat16*)Cv)[(size_t)row * N + col] = __float2bfloat16(v);
                }
            }
        }
    }
    (void)M; (void)res;
}

// ---------------------------------------------------------------- bf16 MFMA GEMM (128^2, counted-vmcnt pipeline) — used for Wo
template<int OMODE>
__global__ __launch_bounds__(256, 3) void gemm128(
    const __hip_bfloat16* __restrict__ A, const __hip_bfloat16* __restrict__ BT,
    const float* __restrict__ bias, const float* __restrict__ res,
    void* __restrict__ Cv, int M, int N, int K, int relu)
{
    __shared__ short sA[3][128 * 32];
    __shared__ short sB[3][128 * 32];
    int t = threadIdx.x;
    int wave = t >> 6, lane = t & 63;
    int l16 = lane & 15, quad = (lane >> 4) & 3;
    int wm = wave >> 1, wn = wave & 1;
    int bm = blockIdx.x * 128, bn = blockIdx.y * 128;

    int kbeg = 0, kend = K;
    if (OMODE == 3) { int KS = K >> 1; kbeg = blockIdx.z * KS; kend = kbeg + KS; }
    int nsteps = (kend - kbeg) >> 5;

    int u = lane >> 2;
    int skey = ((u & 3) ^ ((u >> 2) & 3));
    int sseg = (lane & 3) ^ skey;
    int c0 = wave * 2, c1 = wave * 2 + 1;
    int rA0 = c0 * 16 + u, rA1 = c1 * 16 + u;
    int fkey = ((l16 & 3) ^ ((l16 >> 2) & 3));

    const f32x4 zf = {0.f, 0.f, 0.f, 0.f};
    f32x4 acc[4][4];
    #pragma unroll
    for (int mi = 0; mi < 4; mi++)
        #pragma unroll
        for (int ni = 0; ni < 4; ni++) acc[mi][ni] = zf;

    const __hip_bfloat16* pA0 = A  + (size_t)(bm + rA0) * K + kbeg + sseg * 8;
    const __hip_bfloat16* pA1 = A  + (size_t)(bm + rA1) * K + kbeg + sseg * 8;
    const __hip_bfloat16* pB0 = BT + (size_t)(bn + rA0) * K + kbeg + sseg * 8;
    const __hip_bfloat16* pB1 = BT + (size_t)(bn + rA1) * K + kbeg + sseg * 8;

    #define STAGE(bufi, kk) do { \
        gld16(pA0 + (kk), &sA[bufi][c0 * 512]); \
        gld16(pA1 + (kk), &sA[bufi][c1 * 512]); \
        gld16(pB0 + (kk), &sB[bufi][c0 * 512]); \
        gld16(pB1 + (kk), &sB[bufi][c1 * 512]); \
    } while (0)

    STAGE(0, 0);
    if (nsteps > 1) STAGE(1, 32);

    int bufr = 0, bufs = 2;
    for (int it = 0; it < nsteps; ++it) {
        if (it + 1 < nsteps) { asm volatile("s_waitcnt vmcnt(4)" ::: "memory"); }
        else                 { asm volatile("s_waitcnt vmcnt(0)" ::: "memory"); }
        __builtin_amdgcn_sched_barrier(0);
        __builtin_amdgcn_s_barrier();
        __builtin_amdgcn_sched_barrier(0);

        const short* curA = &sA[bufr][0];
        const short* curB = &sB[bufr][0];
        bf16x8 aF[4], bF[4];
        #pragma unroll
        for (int mi = 0; mi < 4; mi++)
            aF[mi] = *(const bf16x8*)&curA[(wm * 64 + mi * 16 + l16) * 32 + ((quad ^ fkey) * 8)];
        #pragma unroll
        for (int ni = 0; ni < 4; ni++)
            bF[ni] = *(const bf16x8*)&curB[(wn * 64 + ni * 16 + l16) * 32 + ((quad ^ fkey) * 8)];

        asm volatile("s_waitcnt lgkmcnt(0)" ::: "memory");
        __builtin_amdgcn_sched_barrier(0);
        __builtin_amdgcn_s_barrier();
        __builtin_amdgcn_sched_barrier(0);

        if (it + 2 < nsteps) STAGE(bufs, (it + 2) * 32);

        #pragma unroll
        for (int ni = 0; ni < 4; ni++)
            #pragma unroll
            for (int mi = 0; mi < 4; mi++)
                acc[mi][ni] = __builtin_amdgcn_mfma_f32_16x16x32_bf16(aF[mi], bF[ni], acc[mi][ni], 0, 0, 0);

        bufr = (bufr == 2) ? 0 : bufr + 1;
        bufs = (bufs == 2) ? 0 : bufs + 1;
    }
    #undef STAGE

    #pragma unroll
    for (int mi = 0; mi < 4; mi++) {
        #pragma unroll
        for (int ni = 0; ni < 4; ni++) {
            int row0 = bm + wm * 64 + mi * 16 + quad * 4;
            int col  = bn + wn * 64 + ni * 16 + l16;
            #pragma unroll
            for (int r = 0; r < 4; r++) {
                int row = row0 + r;
                float v = acc[mi][ni][r];
                if (OMODE == 3) {
                    float* C = (float*)Cv;
                    if (blockIdx.z == 0 && bias) v += bias[col];
                    unsafeAtomicAdd(&C[(size_t)row * N + col], v);
                    continue;
                }
                if (OMODE != 1 && bias) v += bias[col];
                if (relu) v = fmaxf(v, 0.f);
                if (OMODE == 0) {
                    float* C = (float*)Cv;
                    if (res) v += res[(size_t)row * N + col];
                    C[(size_t)row * N + col] = v;
                } else if (OMODE == 1) {
                    int which = col / D_MODEL, cc = col % D_MODEL;
                    int bb = row >> 10, ss = row & 1023, hh = cc >> 6, e = cc & 63;
                    ((__hip_bfloat16*)Cv)[(size_t)which * MROWS * D_MODEL +
                        (((size_t)(bb * NHEAD + hh)) * SEQ + ss) * HS + e] = __float2bfloat16(v);
                } else {
                    ((__hip_bfloat16*)Cv)[(size_t)row * N + col] = __float2bfloat16(v);
                }
            }
        }
    }
    (void)M;
}

// ---------------------------------------------------------------- V transpose: (bh,s,e) -> (bh,e,s)
__global__ __launch_bounds__(256) void vtrans_kernel(
    const __hip_bfloat16* __restrict__ vb, __hip_bfloat16* __restrict__ vt)
{
    __shared__ short tile[64][66];
    int bh = blockIdx.x, st = blockIdx.y;
    const short* src = (const short*)vb + ((size_t)bh * SEQ + st * 64) * HS;
    int t = threadIdx.x;
    #pragma unroll
    for (int i = 0; i < 2; i++) {
        int slot = t + i * 256;
        int row = slot >> 3, seg = slot & 7;
        *(uint4*)&tile[row][seg * 8] = *(const uint4*)(src + row * HS + seg * 8);
    }
    __syncthreads();
    short* dst = (short*)vt + (size_t)bh * HS * SEQ + st * 64;
    #pragma unroll
    for (int i = 0; i < 2; i++) {
        int slot = t + i * 256;
        int e = slot >> 3, seg = slot & 7;
        union { uint4 u; short s[8]; } pk;
        #pragma unroll
        for (int j = 0; j < 8; j++) pk.s[j] = tile[seg * 8 + j][e];
        *(uint4*)(dst + (size_t)e * SEQ + seg * 8) = pk.u;
    }
}

// ---------------------------------------------------------------- MFMA flash attention v3 (S^T orientation)
__global__ __launch_bounds__(128, 2) void attn_mfma_kernel(
    const __hip_bfloat16* __restrict__ q, const __hip_bfloat16* __restrict__ k,
    const __hip_bfloat16* __restrict__ v, const int* __restrict__ mask,
    __hip_bfloat16* __restrict__ ao)
{
    __shared__ short sK[2][64 * 64];
    __shared__ short sVT[2][64 * 64];
    __shared__ short sP[2][64 * 64];
    __shared__ float mskf[SEQ];
    int bid = blockIdx.x;
    int xcd = bid & 7, j = bid >> 3;
    int bh  = ((j >> 3) << 3) | xcd;
    int qt8 = j & 7;
    int b = bh / NHEAD, hh = bh % NHEAD;
    int t = threadIdx.x, w = t >> 6, lane = t & 63;
    int l16 = lane & 15, quad = lane >> 4;
    const float scale = 0.036084391824351615f;  // 768^-0.5
    const f32x4 zf = {0.f, 0.f, 0.f, 0.f};

    #pragma unroll
    for (int i = 0; i < 8; i++) {
        int idx = t + i * 128;
        mskf[idx] = mask[b * SEQ + idx] ? 0.f : -1e30f;
    }

    int qb0 = qt8 * 128 + w * 64;
    const __hip_bfloat16* qbase = q + ((size_t)bh * SEQ + qb0) * HS;
    bf16x8 qf[4][2];
    #pragma unroll
    for (int qt = 0; qt < 4; qt++)
        #pragma unroll
        for (int s = 0; s < 2; s++)
            qf[qt][s] = *(const bf16x8*)(qbase + (qt * 16 + l16) * HS + s * 32 + quad * 8);

    f32x4 accO[4][4];
    float m_st[4], l_st[4];
    #pragma unroll
    for (int dt = 0; dt < 4; dt++)
        #pragma unroll
        for (int qt = 0; qt < 4; qt++) accO[dt][qt] = zf;
    #pragma unroll
    for (int qt = 0; qt < 4; qt++) { m_st[qt] = -1e30f; l_st[qt] = 0.f; }

    int rowL = lane >> 3;
    int sgl = ((lane & 7) ^ ((lane >> 3) & 7)) * 8;
    const __hip_bfloat16* kg0 = k + ((size_t)bh * SEQ) * HS;
    const __hip_bfloat16* vtg0 = v + (size_t)bh * HS * SEQ;
    short* myP = &sP[w][0];

    #pragma unroll
    for (int i = 0; i < 4; i++) {
        int c = w * 4 + i;
        int rr = c * 8 + rowL;
        gld16(kg0  + (size_t)rr * HS  + sgl, (char*)&sK[0][0]  + c * 1024);
        gld16(vtg0 + (size_t)rr * SEQ + sgl, (char*)&sVT[0][0] + c * 1024);
    }
    __syncthreads();

    int buf = 0;
    for (int kc = 0; kc < 16; kc++) {
        if (kc < 15) {
            const __hip_bfloat16* kg  = kg0  + (size_t)(kc + 1) * 64 * HS;
            const __hip_bfloat16* vtg = vtg0 + (kc + 1) * 64;
            #pragma unroll
            for (int i = 0; i < 4; i++) {
                int c = w * 4 + i;
                int rr = c * 8 + rowL;
                gld16(kg  + (size_t)rr * HS  + sgl, (char*)&sK[buf ^ 1][0]  + c * 1024);
                gld16(vtg + (size_t)rr * SEQ + sgl, (char*)&sVT[buf ^ 1][0] + c * 1024);
            }
        }
        short* cK  = &sK[buf][0];
        short* cVT = &sVT[buf][0];

        bf16x8 vf[4][2];
        #pragma unroll
        for (int dt = 0; dt < 4; dt++)
            #pragma unroll
            for (int s = 0; s < 2; s++)
                vf[dt][s] = *(bf16x8*)&cVT[(dt * 16 + l16) * 64 + (((s * 4 + quad) ^ (l16 & 7)) * 8)];
        f32x4 sc[4][4];
        #pragma unroll
        for (int kt = 0; kt < 4; kt++) {
            bf16x8 kf0 = *(bf16x8*)&cK[(kt * 16 + l16) * 64 + ((quad ^ (l16 & 7)) * 8)];
            bf16x8 kf1 = *(bf16x8*)&cK[(kt * 16 + l16) * 64 + (((4 + quad) ^ (l16 & 7)) * 8)];
            #pragma unroll
            for (int qt = 0; qt < 4; qt++) {
                f32x4 c = __builtin_amdgcn_mfma_f32_16x16x32_bf16(kf0, qf[qt][0], zf, 0, 0, 0);
                sc[kt][qt] = __builtin_amdgcn_mfma_f32_16x16x32_bf16(kf1, qf[qt][1], c, 0, 0, 0);
            }
        }
        #pragma unroll
        for (int kt = 0; kt < 4; kt++) {
            f32x4 mk = *(f32x4*)&mskf[kc * 64 + kt * 16 + quad * 4];
            #pragma unroll
            for (int qt = 0; qt < 4; qt++)
                #pragma unroll
                for (int r = 0; r < 4; r++)
                    sc[kt][qt][r] = sc[kt][qt][r] * scale + mk[r];
        }
        #pragma unroll
        for (int qt = 0; qt < 4; qt++) {
            float rm = -1e30f;
            #pragma unroll
            for (int kt = 0; kt < 4; kt++)
                #pragma unroll
                for (int r = 0; r < 4; r++) rm = fmaxf(rm, sc[kt][qt][r]);
            rm = fmaxf(rm, __shfl_xor(rm, 16));
            rm = fmaxf(rm, __shfl_xor(rm, 32));
            float mnew = fmaxf(m_st[qt], rm);
            float corr = __expf(m_st[qt] - mnew);
            m_st[qt] = mnew;
            float ps = 0.f;
            #pragma unroll
            for (int kt = 0; kt < 4; kt++) {
                union { uint2 u; short s[4]; } pk;
                #pragma unroll
                for (int r = 0; r < 4; r++) {
                    float p = __expf(sc[kt][qt][r] - mnew);
                    ps += p;
                    pk.s[r] = f2bf_s(p);
                }
                *(uint2*)&myP[(qt * 16 + l16) * 64 +
                              (((kt * 2 + (quad >> 1)) ^ (l16 & 7)) * 8) + (quad & 1) * 4] = pk.u;
            }
            ps += __shfl_xor(ps, 16);
            ps += __shfl_xor(ps, 32);
            l_st[qt] = l_st[qt] * corr + ps;
            #pragma unroll
            for (int dt = 0; dt < 4; dt++) accO[dt][qt] *= corr;
        }
        asm volatile("" ::: "memory");
        #pragma unroll
        for (int qt = 0; qt < 4; qt++) {
            bf16x8 pf0 = *(bf16x8*)&myP[(qt * 16 + l16) * 64 + ((quad ^ (l16 & 7)) * 8)];
            bf16x8 pf1 = *(bf16x8*)&myP[(qt * 16 + l16) * 64 + (((4 + quad) ^ (l16 & 7)) * 8)];
            #pragma unroll
            for (int dt = 0; dt < 4; dt++) {
                accO[dt][qt] = __builtin_amdgcn_mfma_f32_16x16x32_bf16(vf[dt][0], pf0, accO[dt][qt], 0, 0, 0);
                accO[dt][qt] = __builtin_amdgcn_mfma_f32_16x16x32_bf16(vf[dt][1], pf1, accO[dt][qt], 0, 0, 0);
            }
        }
        __syncthreads();
        buf ^= 1;
    }

    #pragma unroll
    for (int qt = 0; qt < 4; qt++) {
        float inv = 1.f / l_st[qt];
        int row = qb0 + qt * 16 + l16;
        __hip_bfloat16* orow = ao + ((size_t)(b * SEQ + row)) * D_MODEL + hh * HS;
        #pragma unroll
        for (int dt = 0; dt < 4; dt++) {
            union { uint2 u; short s[4]; } pk;
            #pragma unroll
            for (int r = 0; r < 4; r++) pk.s[r] = f2bf_s(accO[dt][qt][r] * inv);
            *(uint2*)(orow + dt * 16 + quad * 4) = pk.u;
        }
    }
}

// ---------------------------------------------------------------- head FC1: (8,768)@(768,3072)+relu
__global__ __launch_bounds__(256) void fc1_kernel(
    const float* __restrict__ A, const float* __restrict__ W,
    const float* __restrict__ bias, float* __restrict__ out)
{
    __shared__ float sa[D_MODEL];
    int row = blockIdx.x, t = threadIdx.x;
    for (int i = t; i < D_MODEL; i += 256) sa[i] = A[(size_t)row * D_MODEL + i];
    __syncthreads();
    int col = blockIdx.y * 256 + t;
    float s = 0.f;
    #pragma unroll 8
    for (int kk = 0; kk < D_MODEL; kk++) s = fmaf(sa[kk], W[(size_t)kk * DFF + col], s);
    s += bias[col];
    out[(size_t)row * DFF + col] = fmaxf(s, 0.f);
}

// ---------------------------------------------------------------- head FC2: (8,3072)@(3072,16)
__global__ __launch_bounds__(256) void fc2_kernel(
    const float* __restrict__ A, const float* __restrict__ W,
    const float* __restrict__ bias, float* __restrict__ out)
{
    __shared__ float wred[4][NCLS];
    int row = blockIdx.x, t = threadIdx.x;
    int wave = t >> 6, lane = t & 63;
    const float* a = A + (size_t)row * DFF;
    float acc[NCLS];
    #pragma unroll
    for (int c = 0; c < NCLS; c++) acc[c] = 0.f;
    for (int kk = t; kk < DFF; kk += 256) {
        float av = a[kk];
        const float4* wr = (const float4*)(W + (size_t)kk * NCLS);
        float4 w0 = wr[0], w1 = wr[1], w2 = wr[2], w3 = wr[3];
        acc[0]  = fmaf(av, w0.x, acc[0]);  acc[1]  = fmaf(av, w0.y, acc[1]);
        acc[2]  = fmaf(av, w0.z, acc[2]);  acc[3]  = fmaf(av, w0.w, acc[3]);
        acc[4]  = fmaf(av, w1.x, acc[4]);  acc[5]  = fmaf(av, w1.y, acc[5]);
        acc[6]  = fmaf(av, w1.z, acc[6]);  acc[7]  = fmaf(av, w1.w, acc[7]);
        acc[8]  = fmaf(av, w2.x, acc[8]);  acc[9]  = fmaf(av, w2.y, acc[9]);
        acc[10] = fmaf(av, w2.z, acc[10]); acc[11] = fmaf(av, w2.w, acc[11]);
        acc[12] = fmaf(av, w3.x, acc[12]); acc[13] = fmaf(av, w3.y, acc[13]);
        acc[14] = fmaf(av, w3.z, acc[14]); acc[15] = fmaf(av, w3.w, acc[15]);
    }
    #pragma unroll
    for (int c = 0; c < NCLS; c++)
        #pragma unroll
        for (int off = 32; off; off >>= 1) acc[c] += __shfl_down(acc[c], off);
    if (lane == 0)
        #pragma unroll
        for (int c = 0; c < NCLS; c++) wred[wave][c] = acc[c];
    __syncthreads();
    if (t < NCLS)
        out[row * NCLS + t] = wred[0][t] + wred[1][t] + wred[2][t] + wred[3][t] + bias[t];
}

// ---------------------------------------------------------------- launch
extern "C" void kernel_launch(void* const* d_in, const int* in_sizes, int n_in,
                              void* d_out, int out_size, void* d_ws, size_t ws_size,
                              hipStream_t stream)
{
    const int*   x     = (const int*)  d_in[0];
    const int*   amask = (const int*)  d_in[1];
    const float* tok   = (const float*)d_in[2];
    const float* pos   = (const float*)d_in[3];
    const float* Wq    = (const float*)d_in[4];
    const float* Wk    = (const float*)d_in[5];
    const float* Wv    = (const float*)d_in[6];
    const float* Wo    = (const float*)d_in[7];
    const float* bo    = (const float*)d_in[8];
    const float* ln1w  = (const float*)d_in[9];
    const float* ln1b  = (const float*)d_in[10];
    const float* ln2w  = (const float*)d_in[11];
    const float* ln2b  = (const float*)d_in[12];
    const float* W1    = (const float*)d_in[13];
    const float* b1    = (const float*)d_in[14];
    const float* W2    = (const float*)d_in[15];
    const float* b2    = (const float*)d_in[16];
    const float* lnfw  = (const float*)d_in[17];
    const float* lnfb  = (const float*)d_in[18];
    const float* cW1   = (const float*)d_in[19];
    const float* cb1   = (const float*)d_in[20];
    const float* cW2   = (const float*)d_in[21];
    const float* cb2   = (const float*)d_in[22];

    char* base = (char*)d_ws;
    const size_t MD = (size_t)MROWS * D_MODEL;
    float* h = (float*)base;                         base += MD * 4;
    __hip_bfloat16* xn = (__hip_bfloat16*)base;      base += MD * 2;
    __hip_bfloat16* qb = (__hip_bfloat16*)base;      base += MD * 2;
    __hip_bfloat16* kb = (__hip_bfloat16*)base;      base += MD * 2;
    __hip_bfloat16* vb = (__hip_bfloat16*)base;      base += MD * 2;
    __hip_bfloat16* vT = (__hip_bfloat16*)base;      base += MD * 2;
    __hip_bfloat16* ff = (__hip_bfloat16*)base;      base += (size_t)MROWS * DFF * 2;
    float* lnf = (float*)base;                       base += (size_t)NB * D_MODEL * 4;
    float* cls = (float*)base;                       base += (size_t)NB * DFF * 4;
    __hip_bfloat16* wQKV = (__hip_bfloat16*)base;    base += (size_t)NLAYER * 3 * D_MODEL * D_MODEL * 2;
    __hip_bfloat16* wTo = (__hip_bfloat16*)base;     base += (size_t)NLAYER * D_MODEL * D_MODEL * 2;
    __hip_bfloat16* wT1 = (__hip_bfloat16*)base;     base += (size_t)NLAYER * D_MODEL * DFF * 2;
    __hip_bfloat16* wT2 = (__hip_bfloat16*)base;     base += (size_t)NLAYER * DFF * D_MODEL * 2;

    const size_t SQW = (size_t)D_MODEL * D_MODEL;
    const size_t SFF = (size_t)D_MODEL * DFF;

    convw_kernel<1><<<dim3(12,12,4), 256, 0, stream>>>(Wq, wQKV + 0 * SQW, D_MODEL, D_MODEL, SQW, 3 * SQW);
    convw_kernel<1><<<dim3(12,12,4), 256, 0, stream>>>(Wk, wQKV + 1 * SQW, D_MODEL, D_MODEL, SQW, 3 * SQW);
    convw_kernel<1><<<dim3(12,12,4), 256, 0, stream>>>(Wv, wQKV + 2 * SQW, D_MODEL, D_MODEL, SQW, 3 * SQW);
    convw_kernel<0><<<dim3(12,12,4), 256, 0, stream>>>(Wo, wTo, D_MODEL, D_MODEL, SQW, SQW);
    convw_kernel<0><<<dim3(12,48,4), 256, 0, stream>>>(W1, wT1, D_MODEL, DFF, SFF, SFF);
    convw_kernel<0><<<dim3(48,12,4), 256, 0, stream>>>(W2, wT2, DFF, D_MODEL, SFF, SFF);

    embed_kernel<<<MROWS, 256, 0, stream>>>(x, tok, pos, h);

    dim3 gQKV(MROWS / 256, (3 * D_MODEL) / 256);        // 32 x 9
    dim3 gF1(MROWS / 256, DFF / 256);                   // 32 x 12
    dim3 gF2(MROWS / 256, D_MODEL / 256, 2);            // 32 x 3 x 2 (split-K)
    dim3 gDS(MROWS / 128, D_MODEL / 128, 2);            // Wo 128^2 split-K
    for (int l = 0; l < NLAYER; l++) {
        ln_kernel<1><<<MROWS, 256, 0, stream>>>(h, ln1w + l * D_MODEL, ln1b + l * D_MODEL, xn, 1, 0);
        gemm256<1><<<gQKV, 512, 0, stream>>>(xn, wQKV + l * 3 * SQW, nullptr, nullptr, qb, MROWS, 3 * D_MODEL, D_MODEL, 0);
        vtrans_kernel<<<dim3(NB * NHEAD, SEQ / 64), 256, 0, stream>>>(vb, vT);
        attn_mfma_kernel<<<NB * NHEAD * 8, 128, 0, stream>>>(qb, kb, vT, amask, xn);
        gemm128<3><<<gDS, 256, 0, stream>>>(xn, wTo + l * SQW, bo + l * D_MODEL, nullptr, h, MROWS, D_MODEL, D_MODEL, 0);
        ln_kernel<1><<<MROWS, 256, 0, stream>>>(h, ln2w + l * D_MODEL, ln2b + l * D_MODEL, xn, 1, 0);
        gemm256<2><<<gF1, 512, 0, stream>>>(xn, wT1 + l * SFF, b1 + l * DFF, nullptr, ff, MROWS, DFF, D_MODEL, 1);
        gemm256<3><<<gF2, 512, 0, stream>>>(ff, wT2 + l * SFF, b2 + l * D_MODEL, nullptr, h, MROWS, D_MODEL, DFF, 0);
    }
    ln_kernel<0><<<NB, 256, 0, stream>>>(h, lnfw, lnfb, lnf, SEQ, SEQ - 1);
    fc1_kernel<<<dim3(NB, DFF / 256), 256, 0, stream>>>(lnf, cW1, cb1, cls);
    fc2_kernel<<<NB, 256, 0, stream>>>(cls, cW2, cb2, (float*)d_out);
}

// Round 4
// 1899.118 us; speedup vs baseline: 1.0161x; 1.0161x over previous
//
#include <hip/hip_runtime.h>
#include <hip/hip_bf16.h>

#define D_MODEL 768
#define SEQ     1024
#define NB      8
#define NHEAD   12
#define HS      64
#define NLAYER  4
#define DFF     3072
#define NCLS    16
#define MROWS   (NB*SEQ)   // 8192

typedef float f32x4  __attribute__((ext_vector_type(4)));
typedef short bf16x8 __attribute__((ext_vector_type(8)));

__device__ __forceinline__ short f2bf_s(float x) {
    __hip_bfloat16 h = __float2bfloat16(x);
    union { __hip_bfloat16 h; short s; } u; u.h = h; return u.s;
}

// async global->LDS, 16B per lane; lds base must be wave-uniform (HW adds lane*16)
__device__ __forceinline__ void gld16(const void* g, void* l) {
    __builtin_amdgcn_global_load_lds((const __attribute__((address_space(1))) void*)g,
                                     (__attribute__((address_space(3))) void*)l, 16, 0, 0);
}

// ---------------------------------------------------------------- embedding
__global__ __launch_bounds__(256) void embed_kernel(
    const int* __restrict__ x, const float* __restrict__ tok,
    const float* __restrict__ pos, float* __restrict__ h)
{
    int row = blockIdx.x;
    int s   = row & (SEQ - 1);
    int t   = threadIdx.x;
    int id  = x[row];
    const float* te = tok + (size_t)id * D_MODEL;
    const float* pe = pos + (size_t)s  * D_MODEL;
    float* hr = h + (size_t)row * D_MODEL;
    for (int d = t; d < D_MODEL; d += 256) hr[d] = te[d] + pe[d];
}

// ---------------------------------------------------------------- layernorm
template<int BF16OUT>
__global__ __launch_bounds__(256) void ln_kernel(
    const float* __restrict__ in, const float* __restrict__ w,
    const float* __restrict__ b, void* __restrict__ outv,
    int row_stride, int row_offset)
{
    __shared__ float part[8];
    int r = blockIdx.x;
    const float* xr = in + (size_t)(r * row_stride + row_offset) * D_MODEL;
    int t = threadIdx.x, wave = t >> 6, lane = t & 63;
    float v0 = xr[t], v1 = xr[t + 256], v2 = xr[t + 512];
    float s = v0 + v1 + v2;
    #pragma unroll
    for (int off = 32; off; off >>= 1) s += __shfl_xor(s, off);
    if (lane == 0) part[wave] = s;
    __syncthreads();
    float mu = (part[0] + part[1] + part[2] + part[3]) * (1.f / D_MODEL);
    float d0 = v0 - mu, d1 = v1 - mu, d2 = v2 - mu;
    float q = d0*d0 + d1*d1 + d2*d2;
    #pragma unroll
    for (int off = 32; off; off >>= 1) q += __shfl_xor(q, off);
    if (lane == 0) part[4 + wave] = q;
    __syncthreads();
    float rstd = rsqrtf((part[4] + part[5] + part[6] + part[7]) * (1.f / D_MODEL) + 1e-5f);
    float y0 = d0 * rstd * w[t]       + b[t];
    float y1 = d1 * rstd * w[t + 256] + b[t + 256];
    float y2 = d2 * rstd * w[t + 512] + b[t + 512];
    if (BF16OUT) {
        __hip_bfloat16* yr = (__hip_bfloat16*)outv + (size_t)r * D_MODEL;
        yr[t] = __float2bfloat16(y0); yr[t+256] = __float2bfloat16(y1); yr[t+512] = __float2bfloat16(y2);
    } else {
        float* yr = (float*)outv + (size_t)r * D_MODEL;
        yr[t] = y0; yr[t+256] = y1; yr[t+512] = y2;
    }
}

// --------------------------------------------- weight convert+transpose to bf16
template<int MODE>
__global__ __launch_bounds__(256) void convw_kernel(
    const float* __restrict__ W, __hip_bfloat16* __restrict__ BT,
    int K, int N, size_t in_stride, size_t out_stride)
{
    __shared__ __hip_bfloat16 sT[64][72];
    W  += (size_t)blockIdx.z * in_stride;
    BT += (size_t)blockIdx.z * out_stride;
    int k0 = blockIdx.x * 64, n0 = blockIdx.y * 64;
    int t = threadIdx.x;
    int kl = t >> 4, nl4 = (t & 15) * 4;
    #pragma unroll
    for (int i = 0; i < 4; i++) {
        int k = k0 + kl + i * 16;
        int n = n0 + nl4;
        const float* src = (MODE == 0) ? (W + (size_t)k * N + n)
                                       : (W + ((size_t)(n >> 6) * K + k) * 64 + (n & 63));
        float4 v = *(const float4*)src;
        sT[nl4 + 0][kl + i*16] = __float2bfloat16(v.x);
        sT[nl4 + 1][kl + i*16] = __float2bfloat16(v.y);
        sT[nl4 + 2][kl + i*16] = __float2bfloat16(v.z);
        sT[nl4 + 3][kl + i*16] = __float2bfloat16(v.w);
    }
    __syncthreads();
    int nl = t >> 2, seg = (t & 3) * 16;
    uint4* dst = (uint4*)(BT + (size_t)(n0 + nl) * K + k0 + seg);
    dst[0] = *(uint4*)&sT[nl][seg];
    dst[1] = *(uint4*)&sT[nl][seg + 8];
}

// ---------------------------------------------------------------- 256x256 8-phase GEMM (m201 port)
// BM=BN=256, BK=64, 8 waves (2M x 4N), 512 thr, LDS 128KB = 2dbuf x 2half x 128x64 x {A,B} x 2B.
// 2 K-tiles per iteration (dbuf0 phases 0-3, dbuf1 phases 4-7). Per phase:
//   {4 ds_read (12 at quadrant-0) -> stage ONE half-tile (2 gld16) -> [vmcnt @ph3/ph7]
//    -> barrier -> lgkmcnt(0) -> setprio(1) 16 MFMA setprio(0) -> barrier}
// Counted vmcnt(4), never 0 in steady state; 2 half-tiles stay in flight across waits.
// Stage schedule (derived from consumption: B-half freed after its tile's quadrant-0,
// A-half after quadrant-3; dbuf-d A freed only after all 4 quadrants of its tile):
//   ph0: T+1 A-lo (dbuf1)   ph1: T+1 A-hi   ph2: T+2 B-lo (dbuf0)  ph3: T+2 B-hi + vmcnt
//   ph4: T+2 A-lo (dbuf0)   ph5: T+2 A-hi   ph6: T+3 B-lo (dbuf1)  ph7: T+3 B-hi + vmcnt
// RAW: tile T confirmed at prev ph7 vmcnt(4)+barrier before ph0 reads; tile T+1 at ph3.
// WAR: every stage is >=1 post-lgkmcnt(0) barrier after the last read of that half.
// OMODE: 1 = QKV bf16 scatter  2 = bf16 out (+bias,relu)  3 = split-K f32 atomicAdd
template<int OMODE>
__global__ __launch_bounds__(512, 2) void gemm256(
    const __hip_bfloat16* __restrict__ A, const __hip_bfloat16* __restrict__ BT,
    const float* __restrict__ bias, const float* __restrict__ res,
    void* __restrict__ Cv, int M, int N, int K, int relu)
{
    __shared__ short sA[2][2][128 * 64];
    __shared__ short sB[2][2][128 * 64];
    int t = threadIdx.x;
    int wave = t >> 6, lane = t & 63;
    int l16 = lane & 15, quad = (lane >> 4) & 3;
    int wm = wave >> 2, wn = wave & 3;
    int bm = blockIdx.x * 256, bn = blockIdx.y * 256;

    int kbeg = 0, kend = K;
    if (OMODE == 3) { int KS = K >> 1; kbeg = blockIdx.z * KS; kend = kbeg + KS; }
    int nt = (kend - kbeg) >> 6;
    int npairs = nt >> 1;           // nt even for all shapes used here

    int rowL = lane >> 3;
    int sgl = ((lane & 7) ^ rowL) * 8;   // inverse-swizzled global seg (shorts)
    int c0 = wave, c1 = 8 + wave;

    const f32x4 zf = {0.f, 0.f, 0.f, 0.f};
    f32x4 acc[8][4];
    #pragma unroll
    for (int mi = 0; mi < 8; mi++)
        #pragma unroll
        for (int ni = 0; ni < 4; ni++) acc[mi][ni] = zf;
    bf16x8 bF[4][2];

    // stage one half-tile (128 rows x 64 cols): 2 gld16/thread, wave-uniform LDS base
    #define STG_A(d, h, kt) do { \
        gld16(A + (size_t)(bm + (h)*128 + c0*8 + rowL) * K + kbeg + (kt)*64 + sgl, &sA[d][h][c0*512]); \
        gld16(A + (size_t)(bm + (h)*128 + c1*8 + rowL) * K + kbeg + (kt)*64 + sgl, &sA[d][h][c1*512]); \
    } while (0)
    #define STG_B(d, h, kt) do { \
        gld16(BT + (size_t)(bn + (h)*128 + c0*8 + rowL) * K + kbeg + (kt)*64 + sgl, &sB[d][h][c0*512]); \
        gld16(BT + (size_t)(bn + (h)*128 + c1*8 + rowL) * K + kbeg + (kt)*64 + sgl, &sB[d][h][c1*512]); \
    } while (0)

    #define LDA8(d, mi, kk) \
        (*(const bf16x8*)&sA[d][wm][((mi) * 16 + l16) * 64 + ((((kk) * 4 + quad) ^ (l16 & 7)) * 8)])
    #define LDB8(d, ni, kk) \
        (*(const bf16x8*)&sB[d][wn >> 1][((wn & 1) * 64 + (ni) * 16 + l16) * 64 + ((((kk) * 4 + quad) ^ (l16 & 7)) * 8)])

    #define PHASE(d, p, STAGE_STMT, VMW) do { \
        bf16x8 a00 = LDA8(d, 2*(p),     0), a01 = LDA8(d, 2*(p),     1); \
        bf16x8 a10 = LDA8(d, 2*(p) + 1, 0), a11 = LDA8(d, 2*(p) + 1, 1); \
        if ((p) == 0) { \
            _Pragma("unroll") \
            for (int ni = 0; ni < 4; ni++) { bF[ni][0] = LDB8(d, ni, 0); bF[ni][1] = LDB8(d, ni, 1); } \
        } \
        STAGE_STMT; \
        VMW; \
        __builtin_amdgcn_sched_barrier(0); \
        __builtin_amdgcn_s_barrier(); \
        __builtin_amdgcn_sched_barrier(0); \
        asm volatile("s_waitcnt lgkmcnt(0)" ::: "memory"); \
        __builtin_amdgcn_sched_barrier(0); \
        __builtin_amdgcn_s_setprio(1); \
        _Pragma("unroll") \
        for (int ni = 0; ni < 4; ni++) { \
            acc[2*(p)][ni]     = __builtin_amdgcn_mfma_f32_16x16x32_bf16(a00, bF[ni][0], acc[2*(p)][ni], 0, 0, 0); \
            acc[2*(p)][ni]     = __builtin_amdgcn_mfma_f32_16x16x32_bf16(a01, bF[ni][1], acc[2*(p)][ni], 0, 0, 0); \
            acc[2*(p) + 1][ni] = __builtin_amdgcn_mfma_f32_16x16x32_bf16(a10, bF[ni][0], acc[2*(p) + 1][ni], 0, 0, 0); \
            acc[2*(p) + 1][ni] = __builtin_amdgcn_mfma_f32_16x16x32_bf16(a11, bF[ni][1], acc[2*(p) + 1][ni], 0, 0, 0); \
        } \
        __builtin_amdgcn_s_setprio(0); \
        __builtin_amdgcn_s_barrier(); \
    } while (0)

    // prologue: tile0 (all 4 halves, dbuf0) + tile1 B halves (dbuf1) = 12 loads
    STG_A(0, 0, 0); STG_A(0, 1, 0); STG_B(0, 0, 0); STG_B(0, 1, 0);
    STG_B(1, 0, 1); STG_B(1, 1, 1);
    asm volatile("s_waitcnt vmcnt(4)" ::: "memory");   // tile0 complete; tile1 B in flight
    __builtin_amdgcn_sched_barrier(0);
    __builtin_amdgcn_s_barrier();
    __builtin_amdgcn_sched_barrier(0);

    #pragma unroll 1
    for (int j = 0; j < npairs; ++j) {
        int T = 2 * j;
        bool nl_ = (j + 1 < npairs);
        PHASE(0, 0, STG_A(1, 0, T + 1), );
        PHASE(0, 1, STG_A(1, 1, T + 1), );
        PHASE(0, 2, if (nl_) STG_B(0, 0, T + 2), );
        PHASE(0, 3, if (nl_) STG_B(0, 1, T + 2),
              if (nl_) { asm volatile("s_waitcnt vmcnt(4)" ::: "memory"); }
              else     { asm volatile("s_waitcnt vmcnt(0)" ::: "memory"); });
        PHASE(1, 0, if (nl_) STG_A(0, 0, T + 2), );
        PHASE(1, 1, if (nl_) STG_A(0, 1, T + 2), );
        PHASE(1, 2, if (nl_) STG_B(1, 0, T + 3), );
        PHASE(1, 3, if (nl_) STG_B(1, 1, T + 3),
              if (nl_) { asm volatile("s_waitcnt vmcnt(4)" ::: "memory"); }
              else     { asm volatile("s_waitcnt vmcnt(0)" ::: "memory"); });
    }
    #undef STG_A
    #undef STG_B
    #undef LDA8
    #undef LDB8
    #undef PHASE

    #pragma unroll
    for (int mi = 0; mi < 8; mi++) {
        #pragma unroll
        for (int ni = 0; ni < 4; ni++) {
            int row0 = bm + wm * 128 + mi * 16 + quad * 4;
            int col  = bn + wn * 64 + ni * 16 + l16;
            #pragma unroll
            for (int r = 0; r < 4; r++) {
                int row = row0 + r;
                float v = acc[mi][ni][r];
                if (OMODE == 3) {
                    float* C = (float*)Cv;
                    if (blockIdx.z == 0 && bias) v += bias[col];
                    unsafeAtomicAdd(&C[(size_t)row * N + col], v);
                    continue;
                }
                if (bias) v += bias[col];
                if (relu) v = fmaxf(v, 0.f);
                if (OMODE == 1) {
                    int which = col / D_MODEL, cc = col % D_MODEL;
                    int bb = row >> 10, ss = row & 1023, hh = cc >> 6, e = cc & 63;
                    ((__hip_bfloat16*)Cv)[(size_t)which * MROWS * D_MODEL +
                        (((size_t)(bb * NHEAD + hh)) * SEQ + ss) * HS + e] = __float2bfloat16(v);
                } else {
                    ((__hip_bfloat16*)Cv)[(size_t)row * N + col] = __float2bfloat16(v);
                }
            }
        }
    }
    (void)M; (void)res;
}

// ---------------------------------------------------------------- bf16 MFMA GEMM (128^2, counted-vmcnt) — Wo
template<int OMODE>
__global__ __launch_bounds__(256, 3) void gemm128(
    const __hip_bfloat16* __restrict__ A, const __hip_bfloat16* __restrict__ BT,
    const float* __restrict__ bias, const float* __restrict__ res,
    void* __restrict__ Cv, int M, int N, int K, int relu)
{
    __shared__ short sA[3][128 * 32];
    __shared__ short sB[3][128 * 32];
    int t = threadIdx.x;
    int wave = t >> 6, lane = t & 63;
    int l16 = lane & 15, quad = (lane >> 4) & 3;
    int wm = wave >> 1, wn = wave & 1;
    int bm = blockIdx.x * 128, bn = blockIdx.y * 128;

    int kbeg = 0, kend = K;
    if (OMODE == 3) { int KS = K >> 1; kbeg = blockIdx.z * KS; kend = kbeg + KS; }
    int nsteps = (kend - kbeg) >> 5;

    int u = lane >> 2;
    int skey = ((u & 3) ^ ((u >> 2) & 3));
    int sseg = (lane & 3) ^ skey;
    int c0 = wave * 2, c1 = wave * 2 + 1;
    int rA0 = c0 * 16 + u, rA1 = c1 * 16 + u;
    int fkey = ((l16 & 3) ^ ((l16 >> 2) & 3));

    const f32x4 zf = {0.f, 0.f, 0.f, 0.f};
    f32x4 acc[4][4];
    #pragma unroll
    for (int mi = 0; mi < 4; mi++)
        #pragma unroll
        for (int ni = 0; ni < 4; ni++) acc[mi][ni] = zf;

    const __hip_bfloat16* pA0 = A  + (size_t)(bm + rA0) * K + kbeg + sseg * 8;
    const __hip_bfloat16* pA1 = A  + (size_t)(bm + rA1) * K + kbeg + sseg * 8;
    const __hip_bfloat16* pB0 = BT + (size_t)(bn + rA0) * K + kbeg + sseg * 8;
    const __hip_bfloat16* pB1 = BT + (size_t)(bn + rA1) * K + kbeg + sseg * 8;

    #define STAGE(bufi, kk) do { \
        gld16(pA0 + (kk), &sA[bufi][c0 * 512]); \
        gld16(pA1 + (kk), &sA[bufi][c1 * 512]); \
        gld16(pB0 + (kk), &sB[bufi][c0 * 512]); \
        gld16(pB1 + (kk), &sB[bufi][c1 * 512]); \
    } while (0)

    STAGE(0, 0);
    if (nsteps > 1) STAGE(1, 32);

    int bufr = 0, bufs = 2;
    for (int it = 0; it < nsteps; ++it) {
        if (it + 1 < nsteps) { asm volatile("s_waitcnt vmcnt(4)" ::: "memory"); }
        else                 { asm volatile("s_waitcnt vmcnt(0)" ::: "memory"); }
        __builtin_amdgcn_sched_barrier(0);
        __builtin_amdgcn_s_barrier();
        __builtin_amdgcn_sched_barrier(0);

        const short* curA = &sA[bufr][0];
        const short* curB = &sB[bufr][0];
        bf16x8 aF[4], bF[4];
        #pragma unroll
        for (int mi = 0; mi < 4; mi++)
            aF[mi] = *(const bf16x8*)&curA[(wm * 64 + mi * 16 + l16) * 32 + ((quad ^ fkey) * 8)];
        #pragma unroll
        for (int ni = 0; ni < 4; ni++)
            bF[ni] = *(const bf16x8*)&curB[(wn * 64 + ni * 16 + l16) * 32 + ((quad ^ fkey) * 8)];

        asm volatile("s_waitcnt lgkmcnt(0)" ::: "memory");
        __builtin_amdgcn_sched_barrier(0);
        __builtin_amdgcn_s_barrier();
        __builtin_amdgcn_sched_barrier(0);

        if (it + 2 < nsteps) STAGE(bufs, (it + 2) * 32);

        #pragma unroll
        for (int ni = 0; ni < 4; ni++)
            #pragma unroll
            for (int mi = 0; mi < 4; mi++)
                acc[mi][ni] = __builtin_amdgcn_mfma_f32_16x16x32_bf16(aF[mi], bF[ni], acc[mi][ni], 0, 0, 0);

        bufr = (bufr == 2) ? 0 : bufr + 1;
        bufs = (bufs == 2) ? 0 : bufs + 1;
    }
    #undef STAGE

    #pragma unroll
    for (int mi = 0; mi < 4; mi++) {
        #pragma unroll
        for (int ni = 0; ni < 4; ni++) {
            int row0 = bm + wm * 64 + mi * 16 + quad * 4;
            int col  = bn + wn * 64 + ni * 16 + l16;
            #pragma unroll
            for (int r = 0; r < 4; r++) {
                int row = row0 + r;
                float v = acc[mi][ni][r];
                if (OMODE == 3) {
                    float* C = (float*)Cv;
                    if (blockIdx.z == 0 && bias) v += bias[col];
                    unsafeAtomicAdd(&C[(size_t)row * N + col], v);
                    continue;
                }
                if (OMODE != 1 && bias) v += bias[col];
                if (relu) v = fmaxf(v, 0.f);
                if (OMODE == 0) {
                    float* C = (float*)Cv;
                    if (res) v += res[(size_t)row * N + col];
                    C[(size_t)row * N + col] = v;
                } else if (OMODE == 1) {
                    int which = col / D_MODEL, cc = col % D_MODEL;
                    int bb = row >> 10, ss = row & 1023, hh = cc >> 6, e = cc & 63;
                    ((__hip_bfloat16*)Cv)[(size_t)which * MROWS * D_MODEL +
                        (((size_t)(bb * NHEAD + hh)) * SEQ + ss) * HS + e] = __float2bfloat16(v);
                } else {
                    ((__hip_bfloat16*)Cv)[(size_t)row * N + col] = __float2bfloat16(v);
                }
            }
        }
    }
    (void)M;
}

// ---------------------------------------------------------------- V transpose: (bh,s,e) -> (bh,e,s)
__global__ __launch_bounds__(256) void vtrans_kernel(
    const __hip_bfloat16* __restrict__ vb, __hip_bfloat16* __restrict__ vt)
{
    __shared__ short tile[64][66];
    int bh = blockIdx.x, st = blockIdx.y;
    const short* src = (const short*)vb + ((size_t)bh * SEQ + st * 64) * HS;
    int t = threadIdx.x;
    #pragma unroll
    for (int i = 0; i < 2; i++) {
        int slot = t + i * 256;
        int row = slot >> 3, seg = slot & 7;
        *(uint4*)&tile[row][seg * 8] = *(const uint4*)(src + row * HS + seg * 8);
    }
    __syncthreads();
    short* dst = (short*)vt + (size_t)bh * HS * SEQ + st * 64;
    #pragma unroll
    for (int i = 0; i < 2; i++) {
        int slot = t + i * 256;
        int e = slot >> 3, seg = slot & 7;
        union { uint4 u; short s[8]; } pk;
        #pragma unroll
        for (int j = 0; j < 8; j++) pk.s[j] = tile[seg * 8 + j][e];
        *(uint4*)(dst + (size_t)e * SEQ + seg * 8) = pk.u;
    }
}

// ---------------------------------------------------------------- MFMA flash attention v3 (S^T orientation)
__global__ __launch_bounds__(128, 2) void attn_mfma_kernel(
    const __hip_bfloat16* __restrict__ q, const __hip_bfloat16* __restrict__ k,
    const __hip_bfloat16* __restrict__ v, const int* __restrict__ mask,
    __hip_bfloat16* __restrict__ ao)
{
    __shared__ short sK[2][64 * 64];
    __shared__ short sVT[2][64 * 64];
    __shared__ short sP[2][64 * 64];
    __shared__ float mskf[SEQ];
    int bid = blockIdx.x;
    int xcd = bid & 7, j = bid >> 3;
    int bh  = ((j >> 3) << 3) | xcd;
    int qt8 = j & 7;
    int b = bh / NHEAD, hh = bh % NHEAD;
    int t = threadIdx.x, w = t >> 6, lane = t & 63;
    int l16 = lane & 15, quad = lane >> 4;
    const float scale = 0.036084391824351615f;  // 768^-0.5
    const f32x4 zf = {0.f, 0.f, 0.f, 0.f};

    #pragma unroll
    for (int i = 0; i < 8; i++) {
        int idx = t + i * 128;
        mskf[idx] = mask[b * SEQ + idx] ? 0.f : -1e30f;
    }

    int qb0 = qt8 * 128 + w * 64;
    const __hip_bfloat16* qbase = q + ((size_t)bh * SEQ + qb0) * HS;
    bf16x8 qf[4][2];
    #pragma unroll
    for (int qt = 0; qt < 4; qt++)
        #pragma unroll
        for (int s = 0; s < 2; s++)
            qf[qt][s] = *(const bf16x8*)(qbase + (qt * 16 + l16) * HS + s * 32 + quad * 8);

    f32x4 accO[4][4];
    float m_st[4], l_st[4];
    #pragma unroll
    for (int dt = 0; dt < 4; dt++)
        #pragma unroll
        for (int qt = 0; qt < 4; qt++) accO[dt][qt] = zf;
    #pragma unroll
    for (int qt = 0; qt < 4; qt++) { m_st[qt] = -1e30f; l_st[qt] = 0.f; }

    int rowL = lane >> 3;
    int sgl = ((lane & 7) ^ ((lane >> 3) & 7)) * 8;
    const __hip_bfloat16* kg0 = k + ((size_t)bh * SEQ) * HS;
    const __hip_bfloat16* vtg0 = v + (size_t)bh * HS * SEQ;
    short* myP = &sP[w][0];

    #pragma unroll
    for (int i = 0; i < 4; i++) {
        int c = w * 4 + i;
        int rr = c * 8 + rowL;
        gld16(kg0  + (size_t)rr * HS  + sgl, (char*)&sK[0][0]  + c * 1024);
        gld16(vtg0 + (size_t)rr * SEQ + sgl, (char*)&sVT[0][0] + c * 1024);
    }
    __syncthreads();

    int buf = 0;
    for (int kc = 0; kc < 16; kc++) {
        if (kc < 15) {
            const __hip_bfloat16* kg  = kg0  + (size_t)(kc + 1) * 64 * HS;
            const __hip_bfloat16* vtg = vtg0 + (kc + 1) * 64;
            #pragma unroll
            for (int i = 0; i < 4; i++) {
                int c = w * 4 + i;
                int rr = c * 8 + rowL;
                gld16(kg  + (size_t)rr * HS  + sgl, (char*)&sK[buf ^ 1][0]  + c * 1024);
                gld16(vtg + (size_t)rr * SEQ + sgl, (char*)&sVT[buf ^ 1][0] + c * 1024);
            }
        }
        short* cK  = &sK[buf][0];
        short* cVT = &sVT[buf][0];

        bf16x8 vf[4][2];
        #pragma unroll
        for (int dt = 0; dt < 4; dt++)
            #pragma unroll
            for (int s = 0; s < 2; s++)
                vf[dt][s] = *(bf16x8*)&cVT[(dt * 16 + l16) * 64 + (((s * 4 + quad) ^ (l16 & 7)) * 8)];
        f32x4 sc[4][4];
        #pragma unroll
        for (int kt = 0; kt < 4; kt++) {
            bf16x8 kf0 = *(bf16x8*)&cK[(kt * 16 + l16) * 64 + ((quad ^ (l16 & 7)) * 8)];
            bf16x8 kf1 = *(bf16x8*)&cK[(kt * 16 + l16) * 64 + (((4 + quad) ^ (l16 & 7)) * 8)];
            #pragma unroll
            for (int qt = 0; qt < 4; qt++) {
                f32x4 c = __builtin_amdgcn_mfma_f32_16x16x32_bf16(kf0, qf[qt][0], zf, 0, 0, 0);
                sc[kt][qt] = __builtin_amdgcn_mfma_f32_16x16x32_bf16(kf1, qf[qt][1], c, 0, 0, 0);
            }
        }
        #pragma unroll
        for (int kt = 0; kt < 4; kt++) {
            f32x4 mk = *(f32x4*)&mskf[kc * 64 + kt * 16 + quad * 4];
            #pragma unroll
            for (int qt = 0; qt < 4; qt++)
                #pragma unroll
                for (int r = 0; r < 4; r++)
                    sc[kt][qt][r] = sc[kt][qt][r] * scale + mk[r];
        }
        #pragma unroll
        for (int qt = 0; qt < 4; qt++) {
            float rm = -1e30f;
            #pragma unroll
            for (int kt = 0; kt < 4; kt++)
                #pragma unroll
                for (int r = 0; r < 4; r++) rm = fmaxf(rm, sc[kt][qt][r]);
            rm = fmaxf(rm, __shfl_xor(rm, 16));
            rm = fmaxf(rm, __shfl_xor(rm, 32));
            float mnew = fmaxf(m_st[qt], rm);
            float corr = __expf(m_st[qt] - mnew);
            m_st[qt] = mnew;
            float ps = 0.f;
            #pragma unroll
            for (int kt = 0; kt < 4; kt++) {
                union { uint2 u; short s[4]; } pk;
                #pragma unroll
                for (int r = 0; r < 4; r++) {
                    float p = __expf(sc[kt][qt][r] - mnew);
                    ps += p;
                    pk.s[r] = f2bf_s(p);
                }
                *(uint2*)&myP[(qt * 16 + l16) * 64 +
                              (((kt * 2 + (quad >> 1)) ^ (l16 & 7)) * 8) + (quad & 1) * 4] = pk.u;
            }
            ps += __shfl_xor(ps, 16);
            ps += __shfl_xor(ps, 32);
            l_st[qt] = l_st[qt] * corr + ps;
            #pragma unroll
            for (int dt = 0; dt < 4; dt++) accO[dt][qt] *= corr;
        }
        asm volatile("" ::: "memory");
        #pragma unroll
        for (int qt = 0; qt < 4; qt++) {
            bf16x8 pf0 = *(bf16x8*)&myP[(qt * 16 + l16) * 64 + ((quad ^ (l16 & 7)) * 8)];
            bf16x8 pf1 = *(bf16x8*)&myP[(qt * 16 + l16) * 64 + (((4 + quad) ^ (l16 & 7)) * 8)];
            #pragma unroll
            for (int dt = 0; dt < 4; dt++) {
                accO[dt][qt] = __builtin_amdgcn_mfma_f32_16x16x32_bf16(vf[dt][0], pf0, accO[dt][qt], 0, 0, 0);
                accO[dt][qt] = __builtin_amdgcn_mfma_f32_16x16x32_bf16(vf[dt][1], pf1, accO[dt][qt], 0, 0, 0);
            }
        }
        __syncthreads();
        buf ^= 1;
    }

    #pragma unroll
    for (int qt = 0; qt < 4; qt++) {
        float inv = 1.f / l_st[qt];
        int row = qb0 + qt * 16 + l16;
        __hip_bfloat16* orow = ao + ((size_t)(b * SEQ + row)) * D_MODEL + hh * HS;
        #pragma unroll
        for (int dt = 0; dt < 4; dt++) {
            union { uint2 u; short s[4]; } pk;
            #pragma unroll
            for (int r = 0; r < 4; r++) pk.s[r] = f2bf_s(accO[dt][qt][r] * inv);
            *(uint2*)(orow + dt * 16 + quad * 4) = pk.u;
        }
    }
}

// ---------------------------------------------------------------- head FC1: (8,768)@(768,3072)+relu
__global__ __launch_bounds__(256) void fc1_kernel(
    const float* __restrict__ A, const float* __restrict__ W,
    const float* __restrict__ bias, float* __restrict__ out)
{
    __shared__ float sa[D_MODEL];
    int row = blockIdx.x, t = threadIdx.x;
    for (int i = t; i < D_MODEL; i += 256) sa[i] = A[(size_t)row * D_MODEL + i];
    __syncthreads();
    int col = blockIdx.y * 256 + t;
    float s = 0.f;
    #pragma unroll 8
    for (int kk = 0; kk < D_MODEL; kk++) s = fmaf(sa[kk], W[(size_t)kk * DFF + col], s);
    s += bias[col];
    out[(size_t)row * DFF + col] = fmaxf(s, 0.f);
}

// ---------------------------------------------------------------- head FC2: (8,3072)@(3072,16)
__global__ __launch_bounds__(256) void fc2_kernel(
    const float* __restrict__ A, const float* __restrict__ W,
    const float* __restrict__ bias, float* __restrict__ out)
{
    __shared__ float wred[4][NCLS];
    int row = blockIdx.x, t = threadIdx.x;
    int wave = t >> 6, lane = t & 63;
    const float* a = A + (size_t)row * DFF;
    float acc[NCLS];
    #pragma unroll
    for (int c = 0; c < NCLS; c++) acc[c] = 0.f;
    for (int kk = t; kk < DFF; kk += 256) {
        float av = a[kk];
        const float4* wr = (const float4*)(W + (size_t)kk * NCLS);
        float4 w0 = wr[0], w1 = wr[1], w2 = wr[2], w3 = wr[3];
        acc[0]  = fmaf(av, w0.x, acc[0]);  acc[1]  = fmaf(av, w0.y, acc[1]);
        acc[2]  = fmaf(av, w0.z, acc[2]);  acc[3]  = fmaf(av, w0.w, acc[3]);
        acc[4]  = fmaf(av, w1.x, acc[4]);  acc[5]  = fmaf(av, w1.y, acc[5]);
        acc[6]  = fmaf(av, w1.z, acc[6]);  acc[7]  = fmaf(av, w1.w, acc[7]);
        acc[8]  = fmaf(av, w2.x, acc[8]);  acc[9]  = fmaf(av, w2.y, acc[9]);
        acc[10] = fmaf(av, w2.z, acc[10]); acc[11] = fmaf(av, w2.w, acc[11]);
        acc[12] = fmaf(av, w3.x, acc[12]); acc[13] = fmaf(av, w3.y, acc[13]);
        acc[14] = fmaf(av, w3.z, acc[14]); acc[15] = fmaf(av, w3.w, acc[15]);
    }
    #pragma unroll
    for (int c = 0; c < NCLS; c++)
        #pragma unroll
        for (int off = 32; off; off >>= 1) acc[c] += __shfl_down(acc[c], off);
    if (lane == 0)
        #pragma unroll
        for (int c = 0; c < NCLS; c++) wred[wave][c] = acc[c];
    __syncthreads();
    if (t < NCLS)
        out[row * NCLS + t] = wred[0][t] + wred[1][t] + wred[2][t] + wred[3][t] + bias[t];
}

// ---------------------------------------------------------------- launch
extern "C" void kernel_launch(void* const* d_in, const int* in_sizes, int n_in,
                              void* d_out, int out_size, void* d_ws, size_t ws_size,
                              hipStream_t stream)
{
    const int*   x     = (const int*)  d_in[0];
    const int*   amask = (const int*)  d_in[1];
    const float* tok   = (const float*)d_in[2];
    const float* pos   = (const float*)d_in[3];
    const float* Wq    = (const float*)d_in[4];
    const float* Wk    = (const float*)d_in[5];
    const float* Wv    = (const float*)d_in[6];
    const float* Wo    = (const float*)d_in[7];
    const float* bo    = (const float*)d_in[8];
    const float* ln1w  = (const float*)d_in[9];
    const float* ln1b  = (const float*)d_in[10];
    const float* ln2w  = (const float*)d_in[11];
    const float* ln2b  = (const float*)d_in[12];
    const float* W1    = (const float*)d_in[13];
    const float* b1    = (const float*)d_in[14];
    const float* W2    = (const float*)d_in[15];
    const float* b2    = (const float*)d_in[16];
    const float* lnfw  = (const float*)d_in[17];
    const float* lnfb  = (const float*)d_in[18];
    const float* cW1   = (const float*)d_in[19];
    const float* cb1   = (const float*)d_in[20];
    const float* cW2   = (const float*)d_in[21];
    const float* cb2   = (const float*)d_in[22];

    char* base = (char*)d_ws;
    const size_t MD = (size_t)MROWS * D_MODEL;
    float* h = (float*)base;                         base += MD * 4;
    __hip_bfloat16* xn = (__hip_bfloat16*)base;      base += MD * 2;
    __hip_bfloat16* qb = (__hip_bfloat16*)base;      base += MD * 2;
    __hip_bfloat16* kb = (__hip_bfloat16*)base;      base += MD * 2;
    __hip_bfloat16* vb = (__hip_bfloat16*)base;      base += MD * 2;
    __hip_bfloat16* vT = (__hip_bfloat16*)base;      base += MD * 2;
    __hip_bfloat16* ff = (__hip_bfloat16*)base;      base += (size_t)MROWS * DFF * 2;
    float* lnf = (float*)base;                       base += (size_t)NB * D_MODEL * 4;
    float* cls = (float*)base;                       base += (size_t)NB * DFF * 4;
    __hip_bfloat16* wQKV = (__hip_bfloat16*)base;    base += (size_t)NLAYER * 3 * D_MODEL * D_MODEL * 2;
    __hip_bfloat16* wTo = (__hip_bfloat16*)base;     base += (size_t)NLAYER * D_MODEL * D_MODEL * 2;
    __hip_bfloat16* wT1 = (__hip_bfloat16*)base;     base += (size_t)NLAYER * D_MODEL * DFF * 2;
    __hip_bfloat16* wT2 = (__hip_bfloat16*)base;     base += (size_t)NLAYER * DFF * D_MODEL * 2;

    const size_t SQW = (size_t)D_MODEL * D_MODEL;
    const size_t SFF = (size_t)D_MODEL * DFF;

    convw_kernel<1><<<dim3(12,12,4), 256, 0, stream>>>(Wq, wQKV + 0 * SQW, D_MODEL, D_MODEL, SQW, 3 * SQW);
    convw_kernel<1><<<dim3(12,12,4), 256, 0, stream>>>(Wk, wQKV + 1 * SQW, D_MODEL, D_MODEL, SQW, 3 * SQW);
    convw_kernel<1><<<dim3(12,12,4), 256, 0, stream>>>(Wv, wQKV + 2 * SQW, D_MODEL, D_MODEL, SQW, 3 * SQW);
    convw_kernel<0><<<dim3(12,12,4), 256, 0, stream>>>(Wo, wTo, D_MODEL, D_MODEL, SQW, SQW);
    convw_kernel<0><<<dim3(12,48,4), 256, 0, stream>>>(W1, wT1, D_MODEL, DFF, SFF, SFF);
    convw_kernel<0><<<dim3(48,12,4), 256, 0, stream>>>(W2, wT2, DFF, D_MODEL, SFF, SFF);

    embed_kernel<<<MROWS, 256, 0, stream>>>(x, tok, pos, h);

    dim3 gQKV(MROWS / 256, (3 * D_MODEL) / 256);        // 32 x 9
    dim3 gF1(MROWS / 256, DFF / 256);                   // 32 x 12
    dim3 gF2(MROWS / 256, D_MODEL / 256, 2);            // 32 x 3 x 2 (split-K)
    dim3 gDS(MROWS / 128, D_MODEL / 128, 2);            // Wo 128^2 split-K
    for (int l = 0; l < NLAYER; l++) {
        ln_kernel<1><<<MROWS, 256, 0, stream>>>(h, ln1w + l * D_MODEL, ln1b + l * D_MODEL, xn, 1, 0);
        gemm256<1><<<gQKV, 512, 0, stream>>>(xn, wQKV + l * 3 * SQW, nullptr, nullptr, qb, MROWS, 3 * D_MODEL, D_MODEL, 0);
        vtrans_kernel<<<dim3(NB * NHEAD, SEQ / 64), 256, 0, stream>>>(vb, vT);
        attn_mfma_kernel<<<NB * NHEAD * 8, 128, 0, stream>>>(qb, kb, vT, amask, xn);
        gemm128<3><<<gDS, 256, 0, stream>>>(xn, wTo + l * SQW, bo + l * D_MODEL, nullptr, h, MROWS, D_MODEL, D_MODEL, 0);
        ln_kernel<1><<<MROWS, 256, 0, stream>>>(h, ln2w + l * D_MODEL, ln2b + l * D_MODEL, xn, 1, 0);
        gemm256<2><<<gF1, 512, 0, stream>>>(xn, wT1 + l * SFF, b1 + l * DFF, nullptr, ff, MROWS, DFF, D_MODEL, 1);
        gemm256<3><<<gF2, 512, 0, stream>>>(ff, wT2 + l * SFF, b2 + l * D_MODEL, nullptr, h, MROWS, D_MODEL, DFF, 0);
    }
    ln_kernel<0><<<NB, 256, 0, stream>>>(h, lnfw, lnfb, lnf, SEQ, SEQ - 1);
    fc1_kernel<<<dim3(NB, DFF / 256), 256, 0, stream>>>(lnf, cW1, cb1, cls);
    fc2_kernel<<<NB, 256, 0, stream>>>(cls, cW2, cb2, (float*)d_out);
}

// Round 5
// 1629.124 us; speedup vs baseline: 1.1845x; 1.1657x over previous
//
#include <hip/hip_runtime.h>
#include <hip/hip_bf16.h>

#define D_MODEL 768
#define SEQ     1024
#define NB      8
#define NHEAD   12
#define HS      64
#define NLAYER  4
#define DFF     3072
#define NCLS    16
#define MROWS   (NB*SEQ)   // 8192

typedef float f32x4  __attribute__((ext_vector_type(4)));
typedef short bf16x8 __attribute__((ext_vector_type(8)));

__device__ __forceinline__ short f2bf_s(float x) {
    __hip_bfloat16 h = __float2bfloat16(x);
    union { __hip_bfloat16 h; short s; } u; u.h = h; return u.s;
}

// async global->LDS, 16B per lane; lds base must be wave-uniform (HW adds lane*16)
__device__ __forceinline__ void gld16(const void* g, void* l) {
    __builtin_amdgcn_global_load_lds((const __attribute__((address_space(1))) void*)g,
                                     (__attribute__((address_space(3))) void*)l, 16, 0, 0);
}

// ---------------------------------------------------------------- embedding
__global__ __launch_bounds__(256) void embed_kernel(
    const int* __restrict__ x, const float* __restrict__ tok,
    const float* __restrict__ pos, float* __restrict__ h)
{
    int row = blockIdx.x;
    int s   = row & (SEQ - 1);
    int t   = threadIdx.x;
    int id  = x[row];
    const float* te = tok + (size_t)id * D_MODEL;
    const float* pe = pos + (size_t)s  * D_MODEL;
    float* hr = h + (size_t)row * D_MODEL;
    for (int d = t; d < D_MODEL; d += 256) hr[d] = te[d] + pe[d];
}

// ---------------------------------------------------------------- layernorm
// wave shuffle-reduce + 4-slot LDS combine
template<int BF16OUT>
__global__ __launch_bounds__(256) void ln_kernel(
    const float* __restrict__ in, const float* __restrict__ w,
    const float* __restrict__ b, void* __restrict__ outv,
    int row_stride, int row_offset)
{
    __shared__ float part[8];
    int r = blockIdx.x;
    const float* xr = in + (size_t)(r * row_stride + row_offset) * D_MODEL;
    int t = threadIdx.x, wave = t >> 6, lane = t & 63;
    float v0 = xr[t], v1 = xr[t + 256], v2 = xr[t + 512];
    float s = v0 + v1 + v2;
    #pragma unroll
    for (int off = 32; off; off >>= 1) s += __shfl_xor(s, off);
    if (lane == 0) part[wave] = s;
    __syncthreads();
    float mu = (part[0] + part[1] + part[2] + part[3]) * (1.f / D_MODEL);
    float d0 = v0 - mu, d1 = v1 - mu, d2 = v2 - mu;
    float q = d0*d0 + d1*d1 + d2*d2;
    #pragma unroll
    for (int off = 32; off; off >>= 1) q += __shfl_xor(q, off);
    if (lane == 0) part[4 + wave] = q;
    __syncthreads();
    float rstd = rsqrtf((part[4] + part[5] + part[6] + part[7]) * (1.f / D_MODEL) + 1e-5f);
    float y0 = d0 * rstd * w[t]       + b[t];
    float y1 = d1 * rstd * w[t + 256] + b[t + 256];
    float y2 = d2 * rstd * w[t + 512] + b[t + 512];
    if (BF16OUT) {
        __hip_bfloat16* yr = (__hip_bfloat16*)outv + (size_t)r * D_MODEL;
        yr[t] = __float2bfloat16(y0); yr[t+256] = __float2bfloat16(y1); yr[t+512] = __float2bfloat16(y2);
    } else {
        float* yr = (float*)outv + (size_t)r * D_MODEL;
        yr[t] = y0; yr[t+256] = y1; yr[t+512] = y2;
    }
}

// --------------------------------------------- weight convert+transpose to bf16
template<int MODE>
__global__ __launch_bounds__(256) void convw_kernel(
    const float* __restrict__ W, __hip_bfloat16* __restrict__ BT,
    int K, int N, size_t in_stride, size_t out_stride)
{
    __shared__ __hip_bfloat16 sT[64][72];
    W  += (size_t)blockIdx.z * in_stride;
    BT += (size_t)blockIdx.z * out_stride;
    int k0 = blockIdx.x * 64, n0 = blockIdx.y * 64;
    int t = threadIdx.x;
    int kl = t >> 4, nl4 = (t & 15) * 4;
    #pragma unroll
    for (int i = 0; i < 4; i++) {
        int k = k0 + kl + i * 16;
        int n = n0 + nl4;
        const float* src = (MODE == 0) ? (W + (size_t)k * N + n)
                                       : (W + ((size_t)(n >> 6) * K + k) * 64 + (n & 63));
        float4 v = *(const float4*)src;
        sT[nl4 + 0][kl + i*16] = __float2bfloat16(v.x);
        sT[nl4 + 1][kl + i*16] = __float2bfloat16(v.y);
        sT[nl4 + 2][kl + i*16] = __float2bfloat16(v.z);
        sT[nl4 + 3][kl + i*16] = __float2bfloat16(v.w);
    }
    __syncthreads();
    int nl = t >> 2, seg = (t & 3) * 16;
    uint4* dst = (uint4*)(BT + (size_t)(n0 + nl) * K + k0 + seg);
    dst[0] = *(uint4*)&sT[nl][seg];
    dst[1] = *(uint4*)&sT[nl][seg + 8];
}

// ---------------------------------------------------------------- bf16 MFMA GEMM
// R2-proven: 3 LDS buffers, 2-deep prefetch, raw s_barrier, counted vmcnt.
// OMODE: 0 = f32 out (+bias,+res)   1 = QKV scatter (V third written TRANSPOSED
//        to (bh,e,s) with packed uint2 stores — feeds attn directly, no vtrans)
//        2 = bf16 out   3 = split-K over blockIdx.z, atomicAdd f32 into C
template<int OMODE>
__global__ __launch_bounds__(256, 3) void gemm128(
    const __hip_bfloat16* __restrict__ A, const __hip_bfloat16* __restrict__ BT,
    const float* __restrict__ bias, const float* __restrict__ res,
    void* __restrict__ Cv, int M, int N, int K, int relu)
{
    __shared__ short sA[3][128 * 32];
    __shared__ short sB[3][128 * 32];
    int t = threadIdx.x;
    int wave = t >> 6, lane = t & 63;
    int l16 = lane & 15, quad = (lane >> 4) & 3;
    int wm = wave >> 1, wn = wave & 1;
    int bm = blockIdx.x * 128, bn = blockIdx.y * 128;

    int kbeg = 0, kend = K;
    if (OMODE == 3) { int KS = K >> 1; kbeg = blockIdx.z * KS; kend = kbeg + KS; }
    int nsteps = (kend - kbeg) >> 5;

    int u = lane >> 2;
    int skey = ((u & 3) ^ ((u >> 2) & 3));
    int sseg = (lane & 3) ^ skey;
    int c0 = wave * 2, c1 = wave * 2 + 1;
    int rA0 = c0 * 16 + u, rA1 = c1 * 16 + u;
    int fkey = ((l16 & 3) ^ ((l16 >> 2) & 3));

    const f32x4 zf = {0.f, 0.f, 0.f, 0.f};
    f32x4 acc[4][4];
    #pragma unroll
    for (int mi = 0; mi < 4; mi++)
        #pragma unroll
        for (int ni = 0; ni < 4; ni++) acc[mi][ni] = zf;

    const __hip_bfloat16* pA0 = A  + (size_t)(bm + rA0) * K + kbeg + sseg * 8;
    const __hip_bfloat16* pA1 = A  + (size_t)(bm + rA1) * K + kbeg + sseg * 8;
    const __hip_bfloat16* pB0 = BT + (size_t)(bn + rA0) * K + kbeg + sseg * 8;
    const __hip_bfloat16* pB1 = BT + (size_t)(bn + rA1) * K + kbeg + sseg * 8;

    #define STAGE(bufi, kk) do { \
        gld16(pA0 + (kk), &sA[bufi][c0 * 512]); \
        gld16(pA1 + (kk), &sA[bufi][c1 * 512]); \
        gld16(pB0 + (kk), &sB[bufi][c0 * 512]); \
        gld16(pB1 + (kk), &sB[bufi][c1 * 512]); \
    } while (0)

    STAGE(0, 0);
    if (nsteps > 1) STAGE(1, 32);

    int bufr = 0, bufs = 2;
    for (int it = 0; it < nsteps; ++it) {
        if (it + 1 < nsteps) { asm volatile("s_waitcnt vmcnt(4)" ::: "memory"); }
        else                 { asm volatile("s_waitcnt vmcnt(0)" ::: "memory"); }
        __builtin_amdgcn_sched_barrier(0);
        __builtin_amdgcn_s_barrier();
        __builtin_amdgcn_sched_barrier(0);

        const short* curA = &sA[bufr][0];
        const short* curB = &sB[bufr][0];
        bf16x8 aF[4], bF[4];
        #pragma unroll
        for (int mi = 0; mi < 4; mi++)
            aF[mi] = *(const bf16x8*)&curA[(wm * 64 + mi * 16 + l16) * 32 + ((quad ^ fkey) * 8)];
        #pragma unroll
        for (int ni = 0; ni < 4; ni++)
            bF[ni] = *(const bf16x8*)&curB[(wn * 64 + ni * 16 + l16) * 32 + ((quad ^ fkey) * 8)];

        asm volatile("s_waitcnt lgkmcnt(0)" ::: "memory");
        __builtin_amdgcn_sched_barrier(0);
        __builtin_amdgcn_s_barrier();
        __builtin_amdgcn_sched_barrier(0);

        if (it + 2 < nsteps) STAGE(bufs, (it + 2) * 32);

        #pragma unroll
        for (int ni = 0; ni < 4; ni++)
            #pragma unroll
            for (int mi = 0; mi < 4; mi++)
                acc[mi][ni] = __builtin_amdgcn_mfma_f32_16x16x32_bf16(aF[mi], bF[ni], acc[mi][ni], 0, 0, 0);

        bufr = (bufr == 2) ? 0 : bufr + 1;
        bufs = (bufs == 2) ? 0 : bufs + 1;
    }
    #undef STAGE

    #pragma unroll
    for (int mi = 0; mi < 4; mi++) {
        #pragma unroll
        for (int ni = 0; ni < 4; ni++) {
            int row0 = bm + wm * 64 + mi * 16 + quad * 4;
            int col  = bn + wn * 64 + ni * 16 + l16;
            if (OMODE == 1) {
                // QKV scatter. row0 % 4 == 0, rows row0..row0+3 share bb.
                int which = col / D_MODEL, cc = col % D_MODEL;
                int hh = cc >> 6, e = cc & 63;
                int bb = row0 >> 10, ss0 = row0 & 1023;
                union { uint2 u; short s[4]; } pk;
                #pragma unroll
                for (int r = 0; r < 4; r++) pk.s[r] = f2bf_s(acc[mi][ni][r]);
                __hip_bfloat16* dstb = (__hip_bfloat16*)Cv + (size_t)which * MROWS * D_MODEL;
                if (which == 2) {
                    // V -> (bh, e, s) transposed; 4 consecutive s -> one uint2
                    *(uint2*)(dstb + ((size_t)(bb * NHEAD + hh)) * HS * SEQ + (size_t)e * SEQ + ss0) = pk.u;
                } else {
                    short* p = (short*)(dstb + (((size_t)(bb * NHEAD + hh)) * SEQ + ss0) * HS + e);
                    #pragma unroll
                    for (int r = 0; r < 4; r++) p[r * HS] = pk.s[r];
                }
                continue;
            }
            #pragma unroll
            for (int r = 0; r < 4; r++) {
                int row = row0 + r;
                float v = acc[mi][ni][r];
                if (OMODE == 3) {
                    float* C = (float*)Cv;
                    if (blockIdx.z == 0 && bias) v += bias[col];
                    unsafeAtomicAdd(&C[(size_t)row * N + col], v);
                    continue;
                }
                if (bias) v += bias[col];
                if (relu) v = fmaxf(v, 0.f);
                if (OMODE == 0) {
                    float* C = (float*)Cv;
                    if (res) v += res[(size_t)row * N + col];
                    C[(size_t)row * N + col] = v;
                } else {
                    ((__hip_bfloat16*)Cv)[(size_t)row * N + col] = __float2bfloat16(v);
                }
            }
        }
    }
    (void)M;
}

// ---------------------------------------------------------------- MFMA flash attention (S^T orientation)
// Block = 4 waves = 256 queries of one (b,h); wave owns 64 queries (4 qt-tiles).
// K/VT staging shared by all 4 waves (each wave stages 2 of 8 column-groups)
// -> staging bytes per MFMA halved vs 2-wave version. 384 blocks, 2 blocks/CU.
// XCD-bijective remap keeps the 4 q-blocks of one (b,h) on one XCD (K/VT L2-local).
__global__ __launch_bounds__(256, 2) void attn_mfma_kernel(
    const __hip_bfloat16* __restrict__ q, const __hip_bfloat16* __restrict__ k,
    const __hip_bfloat16* __restrict__ v, const int* __restrict__ mask,
    __hip_bfloat16* __restrict__ ao)
{
    __shared__ short sK[2][64 * 64];
    __shared__ short sVT[2][64 * 64];
    __shared__ short sP[4][64 * 64];
    __shared__ float mskf[SEQ];
    int bid = blockIdx.x;                 // 384 = 8 XCD x 48
    int xcd = bid & 7, j = bid >> 3;      // j in 0..47
    int bh  = ((j >> 2) << 3) | xcd;      // bijective: bh in 0..95
    int qt4 = j & 3;
    int b = bh / NHEAD, hh = bh % NHEAD;
    int t = threadIdx.x, w = t >> 6, lane = t & 63;
    int l16 = lane & 15, quad = lane >> 4;
    const float scale = 0.036084391824351615f;  // 768^-0.5
    const f32x4 zf = {0.f, 0.f, 0.f, 0.f};

    #pragma unroll
    for (int i = 0; i < 4; i++) {
        int idx = t + i * 256;
        mskf[idx] = mask[b * SEQ + idx] ? 0.f : -1e30f;
    }

    // Q B-frags: lane n=query(l16), k=dim s*32+quad*8..+7
    int qb0 = qt4 * 256 + w * 64;
    const __hip_bfloat16* qbase = q + ((size_t)bh * SEQ + qb0) * HS;
    bf16x8 qf[4][2];
    #pragma unroll
    for (int qt = 0; qt < 4; qt++)
        #pragma unroll
        for (int s = 0; s < 2; s++)
            qf[qt][s] = *(const bf16x8*)(qbase + (qt * 16 + l16) * HS + s * 32 + quad * 8);

    f32x4 accO[4][4];            // [dt][qt]: O^T tile, row=dim dt*16+quad*4+r, col=query qt*16+l16
    float m_st[4], l_st[4];
    #pragma unroll
    for (int dt = 0; dt < 4; dt++)
        #pragma unroll
        for (int qt = 0; qt < 4; qt++) accO[dt][qt] = zf;
    #pragma unroll
    for (int qt = 0; qt < 4; qt++) { m_st[qt] = -1e30f; l_st[qt] = 0.f; }

    // staging geometry: 4 waves x 2 column-groups cover c=0..7 (8 rows each)
    int rowL = lane >> 3;
    int sgl = ((lane & 7) ^ ((lane >> 3) & 7)) * 8;   // swizzled global seg (shorts)
    const __hip_bfloat16* kg0 = k + ((size_t)bh * SEQ) * HS;
    const __hip_bfloat16* vtg0 = v + (size_t)bh * HS * SEQ;   // v pre-transposed (bh,e,s)
    short* myP = &sP[w][0];

    // prologue: stage K-tile 0 into buffer 0
    #pragma unroll
    for (int i = 0; i < 2; i++) {
        int c = w * 2 + i;
        int rr = c * 8 + rowL;
        gld16(kg0  + (size_t)rr * HS  + sgl, (char*)&sK[0][0]  + c * 1024);
        gld16(vtg0 + (size_t)rr * SEQ + sgl, (char*)&sVT[0][0] + c * 1024);
    }
    __syncthreads();

    int buf = 0;
    for (int kc = 0; kc < 16; kc++) {
        // prefetch next K-tile into the other buffer (in flight during compute)
        if (kc < 15) {
            const __hip_bfloat16* kg  = kg0  + (size_t)(kc + 1) * 64 * HS;
            const __hip_bfloat16* vtg = vtg0 + (kc + 1) * 64;
            #pragma unroll
            for (int i = 0; i < 2; i++) {
                int c = w * 2 + i;
                int rr = c * 8 + rowL;
                gld16(kg  + (size_t)rr * HS  + sgl, (char*)&sK[buf ^ 1][0]  + c * 1024);
                gld16(vtg + (size_t)rr * SEQ + sgl, (char*)&sVT[buf ^ 1][0] + c * 1024);
            }
        }
        short* cK  = &sK[buf][0];
        short* cVT = &sVT[buf][0];

        // all sK/sVT reads up front
        bf16x8 vf[4][2];
        #pragma unroll
        for (int dt = 0; dt < 4; dt++)
            #pragma unroll
            for (int s = 0; s < 2; s++)
                vf[dt][s] = *(bf16x8*)&cVT[(dt * 16 + l16) * 64 + (((s * 4 + quad) ^ (l16 & 7)) * 8)];
        f32x4 sc[4][4];   // [kt][qt]
        #pragma unroll
        for (int kt = 0; kt < 4; kt++) {
            bf16x8 kf0 = *(bf16x8*)&cK[(kt * 16 + l16) * 64 + ((quad ^ (l16 & 7)) * 8)];
            bf16x8 kf1 = *(bf16x8*)&cK[(kt * 16 + l16) * 64 + (((4 + quad) ^ (l16 & 7)) * 8)];
            #pragma unroll
            for (int qt = 0; qt < 4; qt++) {
                f32x4 c = __builtin_amdgcn_mfma_f32_16x16x32_bf16(kf0, qf[qt][0], zf, 0, 0, 0);
                sc[kt][qt] = __builtin_amdgcn_mfma_f32_16x16x32_bf16(kf1, qf[qt][1], c, 0, 0, 0);
            }
        }
        // scale + mask (mask indexed by key row)
        #pragma unroll
        for (int kt = 0; kt < 4; kt++) {
            f32x4 mk = *(f32x4*)&mskf[kc * 64 + kt * 16 + quad * 4];
            #pragma unroll
            for (int qt = 0; qt < 4; qt++)
                #pragma unroll
                for (int r = 0; r < 4; r++)
                    sc[kt][qt][r] = sc[kt][qt][r] * scale + mk[r];
        }
        // online softmax per query column
        #pragma unroll
        for (int qt = 0; qt < 4; qt++) {
            float rm = -1e30f;
            #pragma unroll
            for (int kt = 0; kt < 4; kt++)
                #pragma unroll
                for (int r = 0; r < 4; r++) rm = fmaxf(rm, sc[kt][qt][r]);
            rm = fmaxf(rm, __shfl_xor(rm, 16));
            rm = fmaxf(rm, __shfl_xor(rm, 32));
            float mnew = fmaxf(m_st[qt], rm);
            float corr = __expf(m_st[qt] - mnew);
            m_st[qt] = mnew;
            float ps = 0.f;
            #pragma unroll
            for (int kt = 0; kt < 4; kt++) {
                union { uint2 u; short s[4]; } pk;
                #pragma unroll
                for (int r = 0; r < 4; r++) {
                    float p = __expf(sc[kt][qt][r] - mnew);
                    ps += p;
                    pk.s[r] = f2bf_s(p);
                }
                *(uint2*)&myP[(qt * 16 + l16) * 64 +
                              (((kt * 2 + (quad >> 1)) ^ (l16 & 7)) * 8) + (quad & 1) * 4] = pk.u;
            }
            ps += __shfl_xor(ps, 16);
            ps += __shfl_xor(ps, 32);
            l_st[qt] = l_st[qt] * corr + ps;
            #pragma unroll
            for (int dt = 0; dt < 4; dt++) accO[dt][qt] *= corr;
        }
        asm volatile("" ::: "memory");   // keep pf reads after P writes (same-wave DS is in-order)
        // PV: O^T += V^T @ P^T
        #pragma unroll
        for (int qt = 0; qt < 4; qt++) {
            bf16x8 pf0 = *(bf16x8*)&myP[(qt * 16 + l16) * 64 + ((quad ^ (l16 & 7)) * 8)];
            bf16x8 pf1 = *(bf16x8*)&myP[(qt * 16 + l16) * 64 + (((4 + quad) ^ (l16 & 7)) * 8)];
            #pragma unroll
            for (int dt = 0; dt < 4; dt++) {
                accO[dt][qt] = __builtin_amdgcn_mfma_f32_16x16x32_bf16(vf[dt][0], pf0, accO[dt][qt], 0, 0, 0);
                accO[dt][qt] = __builtin_amdgcn_mfma_f32_16x16x32_bf16(vf[dt][1], pf1, accO[dt][qt], 0, 0, 0);
            }
        }
        __syncthreads();   // drains prefetch (full compute phase to land); next buffer ready
        buf ^= 1;
    }

    // epilogue: O = O^T / l, pack 4 consecutive dims per b64 store
    #pragma unroll
    for (int qt = 0; qt < 4; qt++) {
        float inv = 1.f / l_st[qt];
        int row = qb0 + qt * 16 + l16;
        __hip_bfloat16* orow = ao + ((size_t)(b * SEQ + row)) * D_MODEL + hh * HS;
        #pragma unroll
        for (int dt = 0; dt < 4; dt++) {
            union { uint2 u; short s[4]; } pk;
            #pragma unroll
            for (int r = 0; r < 4; r++) pk.s[r] = f2bf_s(accO[dt][qt][r] * inv);
            *(uint2*)(orow + dt * 16 + quad * 4) = pk.u;
        }
    }
}

// ---------------------------------------------------------------- head FC1: (8,768)@(768,3072)+relu
__global__ __launch_bounds__(256) void fc1_kernel(
    const float* __restrict__ A, const float* __restrict__ W,
    const float* __restrict__ bias, float* __restrict__ out)
{
    __shared__ float sa[D_MODEL];
    int row = blockIdx.x, t = threadIdx.x;
    for (int i = t; i < D_MODEL; i += 256) sa[i] = A[(size_t)row * D_MODEL + i];
    __syncthreads();
    int col = blockIdx.y * 256 + t;
    float s = 0.f;
    #pragma unroll 8
    for (int kk = 0; kk < D_MODEL; kk++) s = fmaf(sa[kk], W[(size_t)kk * DFF + col], s);
    s += bias[col];
    out[(size_t)row * DFF + col] = fmaxf(s, 0.f);
}

// ---------------------------------------------------------------- head FC2: (8,3072)@(3072,16)
__global__ __launch_bounds__(256) void fc2_kernel(
    const float* __restrict__ A, const float* __restrict__ W,
    const float* __restrict__ bias, float* __restrict__ out)
{
    __shared__ float wred[4][NCLS];
    int row = blockIdx.x, t = threadIdx.x;
    int wave = t >> 6, lane = t & 63;
    const float* a = A + (size_t)row * DFF;
    float acc[NCLS];
    #pragma unroll
    for (int c = 0; c < NCLS; c++) acc[c] = 0.f;
    for (int kk = t; kk < DFF; kk += 256) {
        float av = a[kk];
        const float4* wr = (const float4*)(W + (size_t)kk * NCLS);
        float4 w0 = wr[0], w1 = wr[1], w2 = wr[2], w3 = wr[3];
        acc[0]  = fmaf(av, w0.x, acc[0]);  acc[1]  = fmaf(av, w0.y, acc[1]);
        acc[2]  = fmaf(av, w0.z, acc[2]);  acc[3]  = fmaf(av, w0.w, acc[3]);
        acc[4]  = fmaf(av, w1.x, acc[4]);  acc[5]  = fmaf(av, w1.y, acc[5]);
        acc[6]  = fmaf(av, w1.z, acc[6]);  acc[7]  = fmaf(av, w1.w, acc[7]);
        acc[8]  = fmaf(av, w2.x, acc[8]);  acc[9]  = fmaf(av, w2.y, acc[9]);
        acc[10] = fmaf(av, w2.z, acc[10]); acc[11] = fmaf(av, w2.w, acc[11]);
        acc[12] = fmaf(av, w3.x, acc[12]); acc[13] = fmaf(av, w3.y, acc[13]);
        acc[14] = fmaf(av, w3.z, acc[14]); acc[15] = fmaf(av, w3.w, acc[15]);
    }
    #pragma unroll
    for (int c = 0; c < NCLS; c++)
        #pragma unroll
        for (int off = 32; off; off >>= 1) acc[c] += __shfl_down(acc[c], off);
    if (lane == 0)
        #pragma unroll
        for (int c = 0; c < NCLS; c++) wred[wave][c] = acc[c];
    __syncthreads();
    if (t < NCLS)
        out[row * NCLS + t] = wred[0][t] + wred[1][t] + wred[2][t] + wred[3][t] + bias[t];
}

// ---------------------------------------------------------------- launch
extern "C" void kernel_launch(void* const* d_in, const int* in_sizes, int n_in,
                              void* d_out, int out_size, void* d_ws, size_t ws_size,
                              hipStream_t stream)
{
    const int*   x     = (const int*)  d_in[0];
    const int*   amask = (const int*)  d_in[1];
    const float* tok   = (const float*)d_in[2];
    const float* pos   = (const float*)d_in[3];
    const float* Wq    = (const float*)d_in[4];
    const float* Wk    = (const float*)d_in[5];
    const float* Wv    = (const float*)d_in[6];
    const float* Wo    = (const float*)d_in[7];
    const float* bo    = (const float*)d_in[8];
    const float* ln1w  = (const float*)d_in[9];
    const float* ln1b  = (const float*)d_in[10];
    const float* ln2w  = (const float*)d_in[11];
    const float* ln2b  = (const float*)d_in[12];
    const float* W1    = (const float*)d_in[13];
    const float* b1    = (const float*)d_in[14];
    const float* W2    = (const float*)d_in[15];
    const float* b2    = (const float*)d_in[16];
    const float* lnfw  = (const float*)d_in[17];
    const float* lnfb  = (const float*)d_in[18];
    const float* cW1   = (const float*)d_in[19];
    const float* cb1   = (const float*)d_in[20];
    const float* cW2   = (const float*)d_in[21];
    const float* cb2   = (const float*)d_in[22];

    char* base = (char*)d_ws;
    const size_t MD = (size_t)MROWS * D_MODEL;
    float* h = (float*)base;                         base += MD * 4;
    __hip_bfloat16* xn = (__hip_bfloat16*)base;      base += MD * 2;
    __hip_bfloat16* qb = (__hip_bfloat16*)base;      base += MD * 2;
    __hip_bfloat16* kb = (__hip_bfloat16*)base;      base += MD * 2;
    __hip_bfloat16* vb = (__hip_bfloat16*)base;      base += MD * 2;   // holds V^T (bh,e,s)
    __hip_bfloat16* vT = (__hip_bfloat16*)base;      base += MD * 2;   // unused (kept for layout)
    __hip_bfloat16* ff = (__hip_bfloat16*)base;      base += (size_t)MROWS * DFF * 2;
    float* lnf = (float*)base;                       base += (size_t)NB * D_MODEL * 4;
    float* cls = (float*)base;                       base += (size_t)NB * DFF * 4;
    __hip_bfloat16* wQKV = (__hip_bfloat16*)base;    base += (size_t)NLAYER * 3 * D_MODEL * D_MODEL * 2;
    __hip_bfloat16* wTo = (__hip_bfloat16*)base;     base += (size_t)NLAYER * D_MODEL * D_MODEL * 2;
    __hip_bfloat16* wT1 = (__hip_bfloat16*)base;     base += (size_t)NLAYER * D_MODEL * DFF * 2;
    __hip_bfloat16* wT2 = (__hip_bfloat16*)base;     base += (size_t)NLAYER * DFF * D_MODEL * 2;
    (void)vT;

    const size_t SQW = (size_t)D_MODEL * D_MODEL;
    const size_t SFF = (size_t)D_MODEL * DFF;

    convw_kernel<1><<<dim3(12,12,4), 256, 0, stream>>>(Wq, wQKV + 0 * SQW, D_MODEL, D_MODEL, SQW, 3 * SQW);
    convw_kernel<1><<<dim3(12,12,4), 256, 0, stream>>>(Wk, wQKV + 1 * SQW, D_MODEL, D_MODEL, SQW, 3 * SQW);
    convw_kernel<1><<<dim3(12,12,4), 256, 0, stream>>>(Wv, wQKV + 2 * SQW, D_MODEL, D_MODEL, SQW, 3 * SQW);
    convw_kernel<0><<<dim3(12,12,4), 256, 0, stream>>>(Wo, wTo, D_MODEL, D_MODEL, SQW, SQW);
    convw_kernel<0><<<dim3(12,48,4), 256, 0, stream>>>(W1, wT1, D_MODEL, DFF, SFF, SFF);
    convw_kernel<0><<<dim3(48,12,4), 256, 0, stream>>>(W2, wT2, DFF, D_MODEL, SFF, SFF);

    embed_kernel<<<MROWS, 256, 0, stream>>>(x, tok, pos, h);

    dim3 gQKV(MROWS / 128, (3 * D_MODEL) / 128);
    dim3 gDS(MROWS / 128, D_MODEL / 128, 2);   // split-K=2
    dim3 gF(MROWS / 128, DFF / 128);
    for (int l = 0; l < NLAYER; l++) {
        ln_kernel<1><<<MROWS, 256, 0, stream>>>(h, ln1w + l * D_MODEL, ln1b + l * D_MODEL, xn, 1, 0);
        gemm128<1><<<gQKV, 256, 0, stream>>>(xn, wQKV + l * 3 * SQW, nullptr, nullptr, qb, MROWS, 3 * D_MODEL, D_MODEL, 0);
        attn_mfma_kernel<<<NB * NHEAD * 4, 256, 0, stream>>>(qb, kb, vb, amask, xn);
        gemm128<3><<<gDS, 256, 0, stream>>>(xn, wTo + l * SQW, bo + l * D_MODEL, nullptr, h, MROWS, D_MODEL, D_MODEL, 0);
        ln_kernel<1><<<MROWS, 256, 0, stream>>>(h, ln2w + l * D_MODEL, ln2b + l * D_MODEL, xn, 1, 0);
        gemm128<2><<<gF, 256, 0, stream>>>(xn, wT1 + l * SFF, b1 + l * DFF, nullptr, ff, MROWS, DFF, D_MODEL, 1);
        gemm128<3><<<gDS, 256, 0, stream>>>(ff, wT2 + l * SFF, b2 + l * D_MODEL, nullptr, h, MROWS, D_MODEL, DFF, 0);
    }
    ln_kernel<0><<<NB, 256, 0, stream>>>(h, lnfw, lnfb, lnf, SEQ, SEQ - 1);
    fc1_kernel<<<dim3(NB, DFF / 256), 256, 0, stream>>>(lnf, cW1, cb1, cls);
    fc2_kernel<<<NB, 256, 0, stream>>>(cls, cW2, cb2, (float*)d_out);
}

// Round 6
// 1623.455 us; speedup vs baseline: 1.1887x; 1.0035x over previous
//
#include <hip/hip_runtime.h>
#include <hip/hip_bf16.h>

#define D_MODEL 768
#define SEQ     1024
#define NB      8
#define NHEAD   12
#define HS      64
#define NLAYER  4
#define DFF     3072
#define NCLS    16
#define MROWS   (NB*SEQ)   // 8192

typedef float f32x4  __attribute__((ext_vector_type(4)));
typedef short bf16x8 __attribute__((ext_vector_type(8)));

__device__ __forceinline__ short f2bf_s(float x) {
    __hip_bfloat16 h = __float2bfloat16(x);
    union { __hip_bfloat16 h; short s; } u; u.h = h; return u.s;
}

// async global->LDS, 16B per lane; lds base must be wave-uniform (HW adds lane*16)
__device__ __forceinline__ void gld16(const void* g, void* l) {
    __builtin_amdgcn_global_load_lds((const __attribute__((address_space(1))) void*)g,
                                     (__attribute__((address_space(3))) void*)l, 16, 0, 0);
}

// ---------------------------------------------------------------- embedding
__global__ __launch_bounds__(256) void embed_kernel(
    const int* __restrict__ x, const float* __restrict__ tok,
    const float* __restrict__ pos, float* __restrict__ h)
{
    int row = blockIdx.x;
    int s   = row & (SEQ - 1);
    int t   = threadIdx.x;
    int id  = x[row];
    const float* te = tok + (size_t)id * D_MODEL;
    const float* pe = pos + (size_t)s  * D_MODEL;
    float* hr = h + (size_t)row * D_MODEL;
    for (int d = t; d < D_MODEL; d += 256) hr[d] = te[d] + pe[d];
}

// ---------------------------------------------------------------- layernorm
// wave shuffle-reduce + 4-slot LDS combine
template<int BF16OUT>
__global__ __launch_bounds__(256) void ln_kernel(
    const float* __restrict__ in, const float* __restrict__ w,
    const float* __restrict__ b, void* __restrict__ outv,
    int row_stride, int row_offset)
{
    __shared__ float part[8];
    int r = blockIdx.x;
    const float* xr = in + (size_t)(r * row_stride + row_offset) * D_MODEL;
    int t = threadIdx.x, wave = t >> 6, lane = t & 63;
    float v0 = xr[t], v1 = xr[t + 256], v2 = xr[t + 512];
    float s = v0 + v1 + v2;
    #pragma unroll
    for (int off = 32; off; off >>= 1) s += __shfl_xor(s, off);
    if (lane == 0) part[wave] = s;
    __syncthreads();
    float mu = (part[0] + part[1] + part[2] + part[3]) * (1.f / D_MODEL);
    float d0 = v0 - mu, d1 = v1 - mu, d2 = v2 - mu;
    float q = d0*d0 + d1*d1 + d2*d2;
    #pragma unroll
    for (int off = 32; off; off >>= 1) q += __shfl_xor(q, off);
    if (lane == 0) part[4 + wave] = q;
    __syncthreads();
    float rstd = rsqrtf((part[4] + part[5] + part[6] + part[7]) * (1.f / D_MODEL) + 1e-5f);
    float y0 = d0 * rstd * w[t]       + b[t];
    float y1 = d1 * rstd * w[t + 256] + b[t + 256];
    float y2 = d2 * rstd * w[t + 512] + b[t + 512];
    if (BF16OUT) {
        __hip_bfloat16* yr = (__hip_bfloat16*)outv + (size_t)r * D_MODEL;
        yr[t] = __float2bfloat16(y0); yr[t+256] = __float2bfloat16(y1); yr[t+512] = __float2bfloat16(y2);
    } else {
        float* yr = (float*)outv + (size_t)r * D_MODEL;
        yr[t] = y0; yr[t+256] = y1; yr[t+512] = y2;
    }
}

// --------------------------------------------- weight convert+transpose to bf16
template<int MODE>
__global__ __launch_bounds__(256) void convw_kernel(
    const float* __restrict__ W, __hip_bfloat16* __restrict__ BT,
    int K, int N, size_t in_stride, size_t out_stride)
{
    __shared__ __hip_bfloat16 sT[64][72];
    W  += (size_t)blockIdx.z * in_stride;
    BT += (size_t)blockIdx.z * out_stride;
    int k0 = blockIdx.x * 64, n0 = blockIdx.y * 64;
    int t = threadIdx.x;
    int kl = t >> 4, nl4 = (t & 15) * 4;
    #pragma unroll
    for (int i = 0; i < 4; i++) {
        int k = k0 + kl + i * 16;
        int n = n0 + nl4;
        const float* src = (MODE == 0) ? (W + (size_t)k * N + n)
                                       : (W + ((size_t)(n >> 6) * K + k) * 64 + (n & 63));
        float4 v = *(const float4*)src;
        sT[nl4 + 0][kl + i*16] = __float2bfloat16(v.x);
        sT[nl4 + 1][kl + i*16] = __float2bfloat16(v.y);
        sT[nl4 + 2][kl + i*16] = __float2bfloat16(v.z);
        sT[nl4 + 3][kl + i*16] = __float2bfloat16(v.w);
    }
    __syncthreads();
    int nl = t >> 2, seg = (t & 3) * 16;
    uint4* dst = (uint4*)(BT + (size_t)(n0 + nl) * K + k0 + seg);
    dst[0] = *(uint4*)&sT[nl][seg];
    dst[1] = *(uint4*)&sT[nl][seg + 8];
}

// ---------------------------------------------------------------- bf16 MFMA GEMM
// SINGLE-barrier K-step (R5->R6 change): 3 LDS buffers, 2-deep prefetch, counted
// vmcnt, ONE s_barrier per K-step, compiler-managed lgkm waits for frag reads.
// WAR proof for dropping the 2nd barrier: wave A stages buf[t+2] (=buf[t-1]
// storage) only after the top barrier of iter t; any wave B arrives there only
// after its iter-t-1 MFMAs, whose operand waitcnts forced completion of all its
// buf[t-1] ds_reads. RAW: vmcnt(4)+top-barrier confirms tile t staged (t+1 stays
// in flight; never drain to 0 in steady state).
// OMODE: 0 = f32 out (+bias,+res)   1 = QKV scatter (V third written TRANSPOSED
//        to (bh,e,s) with packed uint2 stores — feeds attn directly, no vtrans)
//        2 = bf16 out   3 = split-K over blockIdx.z, atomicAdd f32 into C
template<int OMODE>
__global__ __launch_bounds__(256, 3) void gemm128(
    const __hip_bfloat16* __restrict__ A, const __hip_bfloat16* __restrict__ BT,
    const float* __restrict__ bias, const float* __restrict__ res,
    void* __restrict__ Cv, int M, int N, int K, int relu)
{
    __shared__ short sA[3][128 * 32];
    __shared__ short sB[3][128 * 32];
    int t = threadIdx.x;
    int wave = t >> 6, lane = t & 63;
    int l16 = lane & 15, quad = (lane >> 4) & 3;
    int wm = wave >> 1, wn = wave & 1;
    int bm = blockIdx.x * 128, bn = blockIdx.y * 128;

    int kbeg = 0, kend = K;
    if (OMODE == 3) { int KS = K >> 1; kbeg = blockIdx.z * KS; kend = kbeg + KS; }
    int nsteps = (kend - kbeg) >> 5;

    int u = lane >> 2;
    int skey = ((u & 3) ^ ((u >> 2) & 3));
    int sseg = (lane & 3) ^ skey;
    int c0 = wave * 2, c1 = wave * 2 + 1;
    int rA0 = c0 * 16 + u, rA1 = c1 * 16 + u;
    int fkey = ((l16 & 3) ^ ((l16 >> 2) & 3));

    const f32x4 zf = {0.f, 0.f, 0.f, 0.f};
    f32x4 acc[4][4];
    #pragma unroll
    for (int mi = 0; mi < 4; mi++)
        #pragma unroll
        for (int ni = 0; ni < 4; ni++) acc[mi][ni] = zf;

    const __hip_bfloat16* pA0 = A  + (size_t)(bm + rA0) * K + kbeg + sseg * 8;
    const __hip_bfloat16* pA1 = A  + (size_t)(bm + rA1) * K + kbeg + sseg * 8;
    const __hip_bfloat16* pB0 = BT + (size_t)(bn + rA0) * K + kbeg + sseg * 8;
    const __hip_bfloat16* pB1 = BT + (size_t)(bn + rA1) * K + kbeg + sseg * 8;

    #define STAGE(bufi, kk) do { \
        gld16(pA0 + (kk), &sA[bufi][c0 * 512]); \
        gld16(pA1 + (kk), &sA[bufi][c1 * 512]); \
        gld16(pB0 + (kk), &sB[bufi][c0 * 512]); \
        gld16(pB1 + (kk), &sB[bufi][c1 * 512]); \
    } while (0)

    STAGE(0, 0);
    if (nsteps > 1) STAGE(1, 32);

    int bufr = 0, bufs = 2;
    for (int it = 0; it < nsteps; ++it) {
        // wait own loads for tile 'it' (tile it+1 stays in flight), then the
        // ONE rendezvous per K-step
        if (it + 1 < nsteps) { asm volatile("s_waitcnt vmcnt(4)" ::: "memory"); }
        else                 { asm volatile("s_waitcnt vmcnt(0)" ::: "memory"); }
        __builtin_amdgcn_sched_barrier(0);
        __builtin_amdgcn_s_barrier();
        __builtin_amdgcn_sched_barrier(0);

        const short* curA = &sA[bufr][0];
        const short* curB = &sB[bufr][0];
        bf16x8 aF[4], bF[4];
        #pragma unroll
        for (int mi = 0; mi < 4; mi++)
            aF[mi] = *(const bf16x8*)&curA[(wm * 64 + mi * 16 + l16) * 32 + ((quad ^ fkey) * 8)];
        #pragma unroll
        for (int ni = 0; ni < 4; ni++)
            bF[ni] = *(const bf16x8*)&curB[(wn * 64 + ni * 16 + l16) * 32 + ((quad ^ fkey) * 8)];

        if (it + 2 < nsteps) STAGE(bufs, (it + 2) * 32);   // 2-ahead prefetch

        // compiler inserts counted lgkm waits before each dependent MFMA;
        // all frags consumed below => this wave's ds_reads complete before it
        // reaches the next iteration's barrier (WAR invariant upheld).
        #pragma unroll
        for (int ni = 0; ni < 4; ni++)
            #pragma unroll
            for (int mi = 0; mi < 4; mi++)
                acc[mi][ni] = __builtin_amdgcn_mfma_f32_16x16x32_bf16(aF[mi], bF[ni], acc[mi][ni], 0, 0, 0);

        bufr = (bufr == 2) ? 0 : bufr + 1;
        bufs = (bufs == 2) ? 0 : bufs + 1;
    }
    #undef STAGE

    #pragma unroll
    for (int mi = 0; mi < 4; mi++) {
        #pragma unroll
        for (int ni = 0; ni < 4; ni++) {
            int row0 = bm + wm * 64 + mi * 16 + quad * 4;
            int col  = bn + wn * 64 + ni * 16 + l16;
            if (OMODE == 1) {
                // QKV scatter. row0 % 4 == 0, rows row0..row0+3 share bb.
                int which = col / D_MODEL, cc = col % D_MODEL;
                int hh = cc >> 6, e = cc & 63;
                int bb = row0 >> 10, ss0 = row0 & 1023;
                union { uint2 u; short s[4]; } pk;
                #pragma unroll
                for (int r = 0; r < 4; r++) pk.s[r] = f2bf_s(acc[mi][ni][r]);
                __hip_bfloat16* dstb = (__hip_bfloat16*)Cv + (size_t)which * MROWS * D_MODEL;
                if (which == 2) {
                    // V -> (bh, e, s) transposed; 4 consecutive s -> one uint2
                    *(uint2*)(dstb + ((size_t)(bb * NHEAD + hh)) * HS * SEQ + (size_t)e * SEQ + ss0) = pk.u;
                } else {
                    short* p = (short*)(dstb + (((size_t)(bb * NHEAD + hh)) * SEQ + ss0) * HS + e);
                    #pragma unroll
                    for (int r = 0; r < 4; r++) p[r * HS] = pk.s[r];
                }
                continue;
            }
            #pragma unroll
            for (int r = 0; r < 4; r++) {
                int row = row0 + r;
                float v = acc[mi][ni][r];
                if (OMODE == 3) {
                    float* C = (float*)Cv;
                    if (blockIdx.z == 0 && bias) v += bias[col];
                    unsafeAtomicAdd(&C[(size_t)row * N + col], v);
                    continue;
                }
                if (bias) v += bias[col];
                if (relu) v = fmaxf(v, 0.f);
                if (OMODE == 0) {
                    float* C = (float*)Cv;
                    if (res) v += res[(size_t)row * N + col];
                    C[(size_t)row * N + col] = v;
                } else {
                    ((__hip_bfloat16*)Cv)[(size_t)row * N + col] = __float2bfloat16(v);
                }
            }
        }
    }
    (void)M;
}

// ---------------------------------------------------------------- MFMA flash attention (S^T orientation)
// Block = 4 waves = 256 queries of one (b,h); wave owns 64 queries (4 qt-tiles).
// K/VT staging shared by all 4 waves (each wave stages 2 of 8 column-groups).
// XCD-bijective remap keeps the 4 q-blocks of one (b,h) on one XCD (K/VT L2-local).
__global__ __launch_bounds__(256, 2) void attn_mfma_kernel(
    const __hip_bfloat16* __restrict__ q, const __hip_bfloat16* __restrict__ k,
    const __hip_bfloat16* __restrict__ v, const int* __restrict__ mask,
    __hip_bfloat16* __restrict__ ao)
{
    __shared__ short sK[2][64 * 64];
    __shared__ short sVT[2][64 * 64];
    __shared__ short sP[4][64 * 64];
    __shared__ float mskf[SEQ];
    int bid = blockIdx.x;                 // 384 = 8 XCD x 48
    int xcd = bid & 7, j = bid >> 3;      // j in 0..47
    int bh  = ((j >> 2) << 3) | xcd;      // bijective: bh in 0..95
    int qt4 = j & 3;
    int b = bh / NHEAD, hh = bh % NHEAD;
    int t = threadIdx.x, w = t >> 6, lane = t & 63;
    int l16 = lane & 15, quad = lane >> 4;
    const float scale = 0.036084391824351615f;  // 768^-0.5
    const f32x4 zf = {0.f, 0.f, 0.f, 0.f};

    #pragma unroll
    for (int i = 0; i < 4; i++) {
        int idx = t + i * 256;
        mskf[idx] = mask[b * SEQ + idx] ? 0.f : -1e30f;
    }

    // Q B-frags: lane n=query(l16), k=dim s*32+quad*8..+7
    int qb0 = qt4 * 256 + w * 64;
    const __hip_bfloat16* qbase = q + ((size_t)bh * SEQ + qb0) * HS;
    bf16x8 qf[4][2];
    #pragma unroll
    for (int qt = 0; qt < 4; qt++)
        #pragma unroll
        for (int s = 0; s < 2; s++)
            qf[qt][s] = *(const bf16x8*)(qbase + (qt * 16 + l16) * HS + s * 32 + quad * 8);

    f32x4 accO[4][4];            // [dt][qt]: O^T tile, row=dim dt*16+quad*4+r, col=query qt*16+l16
    float m_st[4], l_st[4];
    #pragma unroll
    for (int dt = 0; dt < 4; dt++)
        #pragma unroll
        for (int qt = 0; qt < 4; qt++) accO[dt][qt] = zf;
    #pragma unroll
    for (int qt = 0; qt < 4; qt++) { m_st[qt] = -1e30f; l_st[qt] = 0.f; }

    // staging geometry: 4 waves x 2 column-groups cover c=0..7 (8 rows each)
    int rowL = lane >> 3;
    int sgl = ((lane & 7) ^ ((lane >> 3) & 7)) * 8;   // swizzled global seg (shorts)
    const __hip_bfloat16* kg0 = k + ((size_t)bh * SEQ) * HS;
    const __hip_bfloat16* vtg0 = v + (size_t)bh * HS * SEQ;   // v pre-transposed (bh,e,s)
    short* myP = &sP[w][0];

    // prologue: stage K-tile 0 into buffer 0
    #pragma unroll
    for (int i = 0; i < 2; i++) {
        int c = w * 2 + i;
        int rr = c * 8 + rowL;
        gld16(kg0  + (size_t)rr * HS  + sgl, (char*)&sK[0][0]  + c * 1024);
        gld16(vtg0 + (size_t)rr * SEQ + sgl, (char*)&sVT[0][0] + c * 1024);
    }
    __syncthreads();

    int buf = 0;
    for (int kc = 0; kc < 16; kc++) {
        // prefetch next K-tile into the other buffer (in flight during compute)
        if (kc < 15) {
            const __hip_bfloat16* kg  = kg0  + (size_t)(kc + 1) * 64 * HS;
            const __hip_bfloat16* vtg = vtg0 + (kc + 1) * 64;
            #pragma unroll
            for (int i = 0; i < 2; i++) {
                int c = w * 2 + i;
                int rr = c * 8 + rowL;
                gld16(kg  + (size_t)rr * HS  + sgl, (char*)&sK[buf ^ 1][0]  + c * 1024);
                gld16(vtg + (size_t)rr * SEQ + sgl, (char*)&sVT[buf ^ 1][0] + c * 1024);
            }
        }
        short* cK  = &sK[buf][0];
        short* cVT = &sVT[buf][0];

        // all sK/sVT reads up front
        bf16x8 vf[4][2];
        #pragma unroll
        for (int dt = 0; dt < 4; dt++)
            #pragma unroll
            for (int s = 0; s < 2; s++)
                vf[dt][s] = *(bf16x8*)&cVT[(dt * 16 + l16) * 64 + (((s * 4 + quad) ^ (l16 & 7)) * 8)];
        f32x4 sc[4][4];   // [kt][qt]
        #pragma unroll
        for (int kt = 0; kt < 4; kt++) {
            bf16x8 kf0 = *(bf16x8*)&cK[(kt * 16 + l16) * 64 + ((quad ^ (l16 & 7)) * 8)];
            bf16x8 kf1 = *(bf16x8*)&cK[(kt * 16 + l16) * 64 + (((4 + quad) ^ (l16 & 7)) * 8)];
            #pragma unroll
            for (int qt = 0; qt < 4; qt++) {
                f32x4 c = __builtin_amdgcn_mfma_f32_16x16x32_bf16(kf0, qf[qt][0], zf, 0, 0, 0);
                sc[kt][qt] = __builtin_amdgcn_mfma_f32_16x16x32_bf16(kf1, qf[qt][1], c, 0, 0, 0);
            }
        }
        // scale + mask (mask indexed by key row)
        #pragma unroll
        for (int kt = 0; kt < 4; kt++) {
            f32x4 mk = *(f32x4*)&mskf[kc * 64 + kt * 16 + quad * 4];
            #pragma unroll
            for (int qt = 0; qt < 4; qt++)
                #pragma unroll
                for (int r = 0; r < 4; r++)
                    sc[kt][qt][r] = sc[kt][qt][r] * scale + mk[r];
        }
        // online softmax per query column
        #pragma unroll
        for (int qt = 0; qt < 4; qt++) {
            float rm = -1e30f;
            #pragma unroll
            for (int kt = 0; kt < 4; kt++)
                #pragma unroll
                for (int r = 0; r < 4; r++) rm = fmaxf(rm, sc[kt][qt][r]);
            rm = fmaxf(rm, __shfl_xor(rm, 16));
            rm = fmaxf(rm, __shfl_xor(rm, 32));
            float mnew = fmaxf(m_st[qt], rm);
            float corr = __expf(m_st[qt] - mnew);
            m_st[qt] = mnew;
            float ps = 0.f;
            #pragma unroll
            for (int kt = 0; kt < 4; kt++) {
                union { uint2 u; short s[4]; } pk;
                #pragma unroll
                for (int r = 0; r < 4; r++) {
                    float p = __expf(sc[kt][qt][r] - mnew);
                    ps += p;
                    pk.s[r] = f2bf_s(p);
                }
                *(uint2*)&myP[(qt * 16 + l16) * 64 +
                              (((kt * 2 + (quad >> 1)) ^ (l16 & 7)) * 8) + (quad & 1) * 4] = pk.u;
            }
            ps += __shfl_xor(ps, 16);
            ps += __shfl_xor(ps, 32);
            l_st[qt] = l_st[qt] * corr + ps;
            #pragma unroll
            for (int dt = 0; dt < 4; dt++) accO[dt][qt] *= corr;
        }
        asm volatile("" ::: "memory");   // keep pf reads after P writes (same-wave DS is in-order)
        // PV: O^T += V^T @ P^T
        #pragma unroll
        for (int qt = 0; qt < 4; qt++) {
            bf16x8 pf0 = *(bf16x8*)&myP[(qt * 16 + l16) * 64 + ((quad ^ (l16 & 7)) * 8)];
            bf16x8 pf1 = *(bf16x8*)&myP[(qt * 16 + l16) * 64 + (((4 + quad) ^ (l16 & 7)) * 8)];
            #pragma unroll
            for (int dt = 0; dt < 4; dt++) {
                accO[dt][qt] = __builtin_amdgcn_mfma_f32_16x16x32_bf16(vf[dt][0], pf0, accO[dt][qt], 0, 0, 0);
                accO[dt][qt] = __builtin_amdgcn_mfma_f32_16x16x32_bf16(vf[dt][1], pf1, accO[dt][qt], 0, 0, 0);
            }
        }
        __syncthreads();   // drains prefetch (full compute phase to land); next buffer ready
        buf ^= 1;
    }

    // epilogue: O = O^T / l, pack 4 consecutive dims per b64 store
    #pragma unroll
    for (int qt = 0; qt < 4; qt++) {
        float inv = 1.f / l_st[qt];
        int row = qb0 + qt * 16 + l16;
        __hip_bfloat16* orow = ao + ((size_t)(b * SEQ + row)) * D_MODEL + hh * HS;
        #pragma unroll
        for (int dt = 0; dt < 4; dt++) {
            union { uint2 u; short s[4]; } pk;
            #pragma unroll
            for (int r = 0; r < 4; r++) pk.s[r] = f2bf_s(accO[dt][qt][r] * inv);
            *(uint2*)(orow + dt * 16 + quad * 4) = pk.u;
        }
    }
}

// ---------------------------------------------------------------- head FC1: (8,768)@(768,3072)+relu
__global__ __launch_bounds__(256) void fc1_kernel(
    const float* __restrict__ A, const float* __restrict__ W,
    const float* __restrict__ bias, float* __restrict__ out)
{
    __shared__ float sa[D_MODEL];
    int row = blockIdx.x, t = threadIdx.x;
    for (int i = t; i < D_MODEL; i += 256) sa[i] = A[(size_t)row * D_MODEL + i];
    __syncthreads();
    int col = blockIdx.y * 256 + t;
    float s = 0.f;
    #pragma unroll 8
    for (int kk = 0; kk < D_MODEL; kk++) s = fmaf(sa[kk], W[(size_t)kk * DFF + col], s);
    s += bias[col];
    out[(size_t)row * DFF + col] = fmaxf(s, 0.f);
}

// ---------------------------------------------------------------- head FC2: (8,3072)@(3072,16)
__global__ __launch_bounds__(256) void fc2_kernel(
    const float* __restrict__ A, const float* __restrict__ W,
    const float* __restrict__ bias, float* __restrict__ out)
{
    __shared__ float wred[4][NCLS];
    int row = blockIdx.x, t = threadIdx.x;
    int wave = t >> 6, lane = t & 63;
    const float* a = A + (size_t)row * DFF;
    float acc[NCLS];
    #pragma unroll
    for (int c = 0; c < NCLS; c++) acc[c] = 0.f;
    for (int kk = t; kk < DFF; kk += 256) {
        float av = a[kk];
        const float4* wr = (const float4*)(W + (size_t)kk * NCLS);
        float4 w0 = wr[0], w1 = wr[1], w2 = wr[2], w3 = wr[3];
        acc[0]  = fmaf(av, w0.x, acc[0]);  acc[1]  = fmaf(av, w0.y, acc[1]);
        acc[2]  = fmaf(av, w0.z, acc[2]);  acc[3]  = fmaf(av, w0.w, acc[3]);
        acc[4]  = fmaf(av, w1.x, acc[4]);  acc[5]  = fmaf(av, w1.y, acc[5]);
        acc[6]  = fmaf(av, w1.z, acc[6]);  acc[7]  = fmaf(av, w1.w, acc[7]);
        acc[8]  = fmaf(av, w2.x, acc[8]);  acc[9]  = fmaf(av, w2.y, acc[9]);
        acc[10] = fmaf(av, w2.z, acc[10]); acc[11] = fmaf(av, w2.w, acc[11]);
        acc[12] = fmaf(av, w3.x, acc[12]); acc[13] = fmaf(av, w3.y, acc[13]);
        acc[14] = fmaf(av, w3.z, acc[14]); acc[15] = fmaf(av, w3.w, acc[15]);
    }
    #pragma unroll
    for (int c = 0; c < NCLS; c++)
        #pragma unroll
        for (int off = 32; off; off >>= 1) acc[c] += __shfl_down(acc[c], off);
    if (lane == 0)
        #pragma unroll
        for (int c = 0; c < NCLS; c++) wred[wave][c] = acc[c];
    __syncthreads();
    if (t < NCLS)
        out[row * NCLS + t] = wred[0][t] + wred[1][t] + wred[2][t] + wred[3][t] + bias[t];
}

// ---------------------------------------------------------------- launch
extern "C" void kernel_launch(void* const* d_in, const int* in_sizes, int n_in,
                              void* d_out, int out_size, void* d_ws, size_t ws_size,
                              hipStream_t stream)
{
    const int*   x     = (const int*)  d_in[0];
    const int*   amask = (const int*)  d_in[1];
    const float* tok   = (const float*)d_in[2];
    const float* pos   = (const float*)d_in[3];
    const float* Wq    = (const float*)d_in[4];
    const float* Wk    = (const float*)d_in[5];
    const float* Wv    = (const float*)d_in[6];
    const float* Wo    = (const float*)d_in[7];
    const float* bo    = (const float*)d_in[8];
    const float* ln1w  = (const float*)d_in[9];
    const float* ln1b  = (const float*)d_in[10];
    const float* ln2w  = (const float*)d_in[11];
    const float* ln2b  = (const float*)d_in[12];
    const float* W1    = (const float*)d_in[13];
    const float* b1    = (const float*)d_in[14];
    const float* W2    = (const float*)d_in[15];
    const float* b2    = (const float*)d_in[16];
    const float* lnfw  = (const float*)d_in[17];
    const float* lnfb  = (const float*)d_in[18];
    const float* cW1   = (const float*)d_in[19];
    const float* cb1   = (const float*)d_in[20];
    const float* cW2   = (const float*)d_in[21];
    const float* cb2   = (const float*)d_in[22];

    char* base = (char*)d_ws;
    const size_t MD = (size_t)MROWS * D_MODEL;
    float* h = (float*)base;                         base += MD * 4;
    __hip_bfloat16* xn = (__hip_bfloat16*)base;      base += MD * 2;
    __hip_bfloat16* qb = (__hip_bfloat16*)base;      base += MD * 2;
    __hip_bfloat16* kb = (__hip_bfloat16*)base;      base += MD * 2;
    __hip_bfloat16* vb = (__hip_bfloat16*)base;      base += MD * 2;   // holds V^T (bh,e,s)
    __hip_bfloat16* vT = (__hip_bfloat16*)base;      base += MD * 2;   // unused (kept for layout)
    __hip_bfloat16* ff = (__hip_bfloat16*)base;      base += (size_t)MROWS * DFF * 2;
    float* lnf = (float*)base;                       base += (size_t)NB * D_MODEL * 4;
    float* cls = (float*)base;                       base += (size_t)NB * DFF * 4;
    __hip_bfloat16* wQKV = (__hip_bfloat16*)base;    base += (size_t)NLAYER * 3 * D_MODEL * D_MODEL * 2;
    __hip_bfloat16* wTo = (__hip_bfloat16*)base;     base += (size_t)NLAYER * D_MODEL * D_MODEL * 2;
    __hip_bfloat16* wT1 = (__hip_bfloat16*)base;     base += (size_t)NLAYER * D_MODEL * DFF * 2;
    __hip_bfloat16* wT2 = (__hip_bfloat16*)base;     base += (size_t)NLAYER * DFF * D_MODEL * 2;
    (void)vT;

    const size_t SQW = (size_t)D_MODEL * D_MODEL;
    const size_t SFF = (size_t)D_MODEL * DFF;

    convw_kernel<1><<<dim3(12,12,4), 256, 0, stream>>>(Wq, wQKV + 0 * SQW, D_MODEL, D_MODEL, SQW, 3 * SQW);
    convw_kernel<1><<<dim3(12,12,4), 256, 0, stream>>>(Wk, wQKV + 1 * SQW, D_MODEL, D_MODEL, SQW, 3 * SQW);
    convw_kernel<1><<<dim3(12,12,4), 256, 0, stream>>>(Wv, wQKV + 2 * SQW, D_MODEL, D_MODEL, SQW, 3 * SQW);
    convw_kernel<0><<<dim3(12,12,4), 256, 0, stream>>>(Wo, wTo, D_MODEL, D_MODEL, SQW, SQW);
    convw_kernel<0><<<dim3(12,48,4), 256, 0, stream>>>(W1, wT1, D_MODEL, DFF, SFF, SFF);
    convw_kernel<0><<<dim3(48,12,4), 256, 0, stream>>>(W2, wT2, DFF, D_MODEL, SFF, SFF);

    embed_kernel<<<MROWS, 256, 0, stream>>>(x, tok, pos, h);

    dim3 gQKV(MROWS / 128, (3 * D_MODEL) / 128);
    dim3 gDS(MROWS / 128, D_MODEL / 128, 2);   // split-K=2
    dim3 gF(MROWS / 128, DFF / 128);
    for (int l = 0; l < NLAYER; l++) {
        ln_kernel<1><<<MROWS, 256, 0, stream>>>(h, ln1w + l * D_MODEL, ln1b + l * D_MODEL, xn, 1, 0);
        gemm128<1><<<gQKV, 256, 0, stream>>>(xn, wQKV + l * 3 * SQW, nullptr, nullptr, qb, MROWS, 3 * D_MODEL, D_MODEL, 0);
        attn_mfma_kernel<<<NB * NHEAD * 4, 256, 0, stream>>>(qb, kb, vb, amask, xn);
        gemm128<3><<<gDS, 256, 0, stream>>>(xn, wTo + l * SQW, bo + l * D_MODEL, nullptr, h, MROWS, D_MODEL, D_MODEL, 0);
        ln_kernel<1><<<MROWS, 256, 0, stream>>>(h, ln2w + l * D_MODEL, ln2b + l * D_MODEL, xn, 1, 0);
        gemm128<2><<<gF, 256, 0, stream>>>(xn, wT1 + l * SFF, b1 + l * DFF, nullptr, ff, MROWS, DFF, D_MODEL, 1);
        gemm128<3><<<gDS, 256, 0, stream>>>(ff, wT2 + l * SFF, b2 + l * D_MODEL, nullptr, h, MROWS, D_MODEL, DFF, 0);
    }
    ln_kernel<0><<<NB, 256, 0, stream>>>(h, lnfw, lnfb, lnf, SEQ, SEQ - 1);
    fc1_kernel<<<dim3(NB, DFF / 256), 256, 0, stream>>>(lnf, cW1, cb1, cls);
    fc2_kernel<<<NB, 256, 0, stream>>>(cls, cW2, cb2, (float*)d_out);
}

// Round 7
// 1610.151 us; speedup vs baseline: 1.1985x; 1.0083x over previous
//
#include <hip/hip_runtime.h>
#include <hip/hip_bf16.h>

#define D_MODEL 768
#define SEQ     1024
#define NB      8
#define NHEAD   12
#define HS      64
#define NLAYER  4
#define DFF     3072
#define NCLS    16
#define MROWS   (NB*SEQ)   // 8192

typedef float f32x4  __attribute__((ext_vector_type(4)));
typedef short bf16x8 __attribute__((ext_vector_type(8)));

__device__ __forceinline__ short f2bf_s(float x) {
    __hip_bfloat16 h = __float2bfloat16(x);
    union { __hip_bfloat16 h; short s; } u; u.h = h; return u.s;
}

// async global->LDS, 16B per lane; lds base must be wave-uniform (HW adds lane*16)
__device__ __forceinline__ void gld16(const void* g, void* l) {
    __builtin_amdgcn_global_load_lds((const __attribute__((address_space(1))) void*)g,
                                     (__attribute__((address_space(3))) void*)l, 16, 0, 0);
}

// ---------------------------------------------------------------- embedding
// one row per WAVE: 12 f32/lane via float4, no LDS/barriers. grid = MROWS/4.
__global__ __launch_bounds__(256) void embed_kernel(
    const int* __restrict__ x, const float* __restrict__ tok,
    const float* __restrict__ pos, float* __restrict__ h)
{
    int wave = threadIdx.x >> 6, lane = threadIdx.x & 63;
    int row = blockIdx.x * 4 + wave;
    int s   = row & (SEQ - 1);
    int id  = x[row];
    const float4* te = (const float4*)(tok + (size_t)id * D_MODEL);
    const float4* pe = (const float4*)(pos + (size_t)s  * D_MODEL);
    float4* hr = (float4*)(h + (size_t)row * D_MODEL);
    #pragma unroll
    for (int j = 0; j < 3; j++) {
        float4 a = te[j * 64 + lane], p = pe[j * 64 + lane];
        a.x += p.x; a.y += p.y; a.z += p.z; a.w += p.w;
        hr[j * 64 + lane] = a;
    }
}

// ---------------------------------------------------------------- layernorm
// one row per WAVE (4 rows/block): float4 loads, full-wave shfl_xor reduce,
// ZERO LDS / barriers. grid = rows/4.
template<int BF16OUT>
__global__ __launch_bounds__(256) void ln_kernel(
    const float* __restrict__ in, const float* __restrict__ w,
    const float* __restrict__ b, void* __restrict__ outv,
    int row_stride, int row_offset)
{
    int wave = threadIdx.x >> 6, lane = threadIdx.x & 63;
    int r = blockIdx.x * 4 + wave;
    const float4* xr = (const float4*)(in + (size_t)(r * row_stride + row_offset) * D_MODEL);
    float4 v0 = xr[lane], v1 = xr[64 + lane], v2 = xr[128 + lane];
    float s = v0.x + v0.y + v0.z + v0.w
            + v1.x + v1.y + v1.z + v1.w
            + v2.x + v2.y + v2.z + v2.w;
    #pragma unroll
    for (int off = 32; off; off >>= 1) s += __shfl_xor(s, off);
    float mu = s * (1.f / D_MODEL);
    float4 d0, d1, d2;
    d0.x = v0.x - mu; d0.y = v0.y - mu; d0.z = v0.z - mu; d0.w = v0.w - mu;
    d1.x = v1.x - mu; d1.y = v1.y - mu; d1.z = v1.z - mu; d1.w = v1.w - mu;
    d2.x = v2.x - mu; d2.y = v2.y - mu; d2.z = v2.z - mu; d2.w = v2.w - mu;
    float q = d0.x*d0.x + d0.y*d0.y + d0.z*d0.z + d0.w*d0.w
            + d1.x*d1.x + d1.y*d1.y + d1.z*d1.z + d1.w*d1.w
            + d2.x*d2.x + d2.y*d2.y + d2.z*d2.z + d2.w*d2.w;
    #pragma unroll
    for (int off = 32; off; off >>= 1) q += __shfl_xor(q, off);
    float rstd = rsqrtf(q * (1.f / D_MODEL) + 1e-5f);
    const float4* w4 = (const float4*)w;
    const float4* b4 = (const float4*)b;
    float4 dd[3] = {d0, d1, d2};
    if (BF16OUT) {
        short* yr = (short*)outv + (size_t)r * D_MODEL;
        #pragma unroll
        for (int j = 0; j < 3; j++) {
            float4 ww = w4[j * 64 + lane], bb = b4[j * 64 + lane];
            union { uint2 u; short s[4]; } pk;
            pk.s[0] = f2bf_s(dd[j].x * rstd * ww.x + bb.x);
            pk.s[1] = f2bf_s(dd[j].y * rstd * ww.y + bb.y);
            pk.s[2] = f2bf_s(dd[j].z * rstd * ww.z + bb.z);
            pk.s[3] = f2bf_s(dd[j].w * rstd * ww.w + bb.w);
            *(uint2*)(yr + j * 256 + lane * 4) = pk.u;
        }
    } else {
        float4* yr = (float4*)((float*)outv + (size_t)r * D_MODEL);
        #pragma unroll
        for (int j = 0; j < 3; j++) {
            float4 ww = w4[j * 64 + lane], bb = b4[j * 64 + lane];
            float4 y;
            y.x = dd[j].x * rstd * ww.x + bb.x;
            y.y = dd[j].y * rstd * ww.y + bb.y;
            y.z = dd[j].z * rstd * ww.z + bb.z;
            y.w = dd[j].w * rstd * ww.w + bb.w;
            yr[j * 64 + lane] = y;
        }
    }
}

// --------------------------------------------- weight convert+transpose to bf16
template<int MODE>
__global__ __launch_bounds__(256) void convw_kernel(
    const float* __restrict__ W, __hip_bfloat16* __restrict__ BT,
    int K, int N, size_t in_stride, size_t out_stride)
{
    __shared__ __hip_bfloat16 sT[64][72];
    W  += (size_t)blockIdx.z * in_stride;
    BT += (size_t)blockIdx.z * out_stride;
    int k0 = blockIdx.x * 64, n0 = blockIdx.y * 64;
    int t = threadIdx.x;
    int kl = t >> 4, nl4 = (t & 15) * 4;
    #pragma unroll
    for (int i = 0; i < 4; i++) {
        int k = k0 + kl + i * 16;
        int n = n0 + nl4;
        const float* src = (MODE == 0) ? (W + (size_t)k * N + n)
                                       : (W + ((size_t)(n >> 6) * K + k) * 64 + (n & 63));
        float4 v = *(const float4*)src;
        sT[nl4 + 0][kl + i*16] = __float2bfloat16(v.x);
        sT[nl4 + 1][kl + i*16] = __float2bfloat16(v.y);
        sT[nl4 + 2][kl + i*16] = __float2bfloat16(v.z);
        sT[nl4 + 3][kl + i*16] = __float2bfloat16(v.w);
    }
    __syncthreads();
    int nl = t >> 2, seg = (t & 3) * 16;
    uint4* dst = (uint4*)(BT + (size_t)(n0 + nl) * K + k0 + seg);
    dst[0] = *(uint4*)&sT[nl][seg];
    dst[1] = *(uint4*)&sT[nl][seg + 8];
}

// ---------------------------------------------------------------- bf16 MFMA GEMM
// SINGLE-barrier K-step: 3 LDS buffers, 2-deep prefetch, counted vmcnt,
// ONE s_barrier per K-step, compiler-managed lgkm waits for frag reads.
// OMODE: 0 = f32 out (+bias,+res)   1 = QKV scatter (V third written TRANSPOSED
//        to (bh,e,s) with packed uint2 stores — feeds attn directly, no vtrans)
//        2 = bf16 out   3 = split-K over blockIdx.z, atomicAdd f32 into C
template<int OMODE>
__global__ __launch_bounds__(256, 3) void gemm128(
    const __hip_bfloat16* __restrict__ A, const __hip_bfloat16* __restrict__ BT,
    const float* __restrict__ bias, const float* __restrict__ res,
    void* __restrict__ Cv, int M, int N, int K, int relu)
{
    __shared__ short sA[3][128 * 32];
    __shared__ short sB[3][128 * 32];
    int t = threadIdx.x;
    int wave = t >> 6, lane = t & 63;
    int l16 = lane & 15, quad = (lane >> 4) & 3;
    int wm = wave >> 1, wn = wave & 1;
    int bm = blockIdx.x * 128, bn = blockIdx.y * 128;

    int kbeg = 0, kend = K;
    if (OMODE == 3) { int KS = K >> 1; kbeg = blockIdx.z * KS; kend = kbeg + KS; }
    int nsteps = (kend - kbeg) >> 5;

    int u = lane >> 2;
    int skey = ((u & 3) ^ ((u >> 2) & 3));
    int sseg = (lane & 3) ^ skey;
    int c0 = wave * 2, c1 = wave * 2 + 1;
    int rA0 = c0 * 16 + u, rA1 = c1 * 16 + u;
    int fkey = ((l16 & 3) ^ ((l16 >> 2) & 3));

    const f32x4 zf = {0.f, 0.f, 0.f, 0.f};
    f32x4 acc[4][4];
    #pragma unroll
    for (int mi = 0; mi < 4; mi++)
        #pragma unroll
        for (int ni = 0; ni < 4; ni++) acc[mi][ni] = zf;

    const __hip_bfloat16* pA0 = A  + (size_t)(bm + rA0) * K + kbeg + sseg * 8;
    const __hip_bfloat16* pA1 = A  + (size_t)(bm + rA1) * K + kbeg + sseg * 8;
    const __hip_bfloat16* pB0 = BT + (size_t)(bn + rA0) * K + kbeg + sseg * 8;
    const __hip_bfloat16* pB1 = BT + (size_t)(bn + rA1) * K + kbeg + sseg * 8;

    #define STAGE(bufi, kk) do { \
        gld16(pA0 + (kk), &sA[bufi][c0 * 512]); \
        gld16(pA1 + (kk), &sA[bufi][c1 * 512]); \
        gld16(pB0 + (kk), &sB[bufi][c0 * 512]); \
        gld16(pB1 + (kk), &sB[bufi][c1 * 512]); \
    } while (0)

    STAGE(0, 0);
    if (nsteps > 1) STAGE(1, 32);

    int bufr = 0, bufs = 2;
    for (int it = 0; it < nsteps; ++it) {
        if (it + 1 < nsteps) { asm volatile("s_waitcnt vmcnt(4)" ::: "memory"); }
        else                 { asm volatile("s_waitcnt vmcnt(0)" ::: "memory"); }
        __builtin_amdgcn_sched_barrier(0);
        __builtin_amdgcn_s_barrier();
        __builtin_amdgcn_sched_barrier(0);

        const short* curA = &sA[bufr][0];
        const short* curB = &sB[bufr][0];
        bf16x8 aF[4], bF[4];
        #pragma unroll
        for (int mi = 0; mi < 4; mi++)
            aF[mi] = *(const bf16x8*)&curA[(wm * 64 + mi * 16 + l16) * 32 + ((quad ^ fkey) * 8)];
        #pragma unroll
        for (int ni = 0; ni < 4; ni++)
            bF[ni] = *(const bf16x8*)&curB[(wn * 64 + ni * 16 + l16) * 32 + ((quad ^ fkey) * 8)];

        if (it + 2 < nsteps) STAGE(bufs, (it + 2) * 32);   // 2-ahead prefetch

        #pragma unroll
        for (int ni = 0; ni < 4; ni++)
            #pragma unroll
            for (int mi = 0; mi < 4; mi++)
                acc[mi][ni] = __builtin_amdgcn_mfma_f32_16x16x32_bf16(aF[mi], bF[ni], acc[mi][ni], 0, 0, 0);

        bufr = (bufr == 2) ? 0 : bufr + 1;
        bufs = (bufs == 2) ? 0 : bufs + 1;
    }
    #undef STAGE

    #pragma unroll
    for (int mi = 0; mi < 4; mi++) {
        #pragma unroll
        for (int ni = 0; ni < 4; ni++) {
            int row0 = bm + wm * 64 + mi * 16 + quad * 4;
            int col  = bn + wn * 64 + ni * 16 + l16;
            if (OMODE == 1) {
                // QKV scatter. row0 % 4 == 0, rows row0..row0+3 share bb.
                int which = col / D_MODEL, cc = col % D_MODEL;
                int hh = cc >> 6, e = cc & 63;
                int bb = row0 >> 10, ss0 = row0 & 1023;
                union { uint2 u; short s[4]; } pk;
                #pragma unroll
                for (int r = 0; r < 4; r++) pk.s[r] = f2bf_s(acc[mi][ni][r]);
                __hip_bfloat16* dstb = (__hip_bfloat16*)Cv + (size_t)which * MROWS * D_MODEL;
                if (which == 2) {
                    // V -> (bh, e, s) transposed; 4 consecutive s -> one uint2
                    *(uint2*)(dstb + ((size_t)(bb * NHEAD + hh)) * HS * SEQ + (size_t)e * SEQ + ss0) = pk.u;
                } else {
                    short* p = (short*)(dstb + (((size_t)(bb * NHEAD + hh)) * SEQ + ss0) * HS + e);
                    #pragma unroll
                    for (int r = 0; r < 4; r++) p[r * HS] = pk.s[r];
                }
                continue;
            }
            #pragma unroll
            for (int r = 0; r < 4; r++) {
                int row = row0 + r;
                float v = acc[mi][ni][r];
                if (OMODE == 3) {
                    float* C = (float*)Cv;
                    if (blockIdx.z == 0 && bias) v += bias[col];
                    unsafeAtomicAdd(&C[(size_t)row * N + col], v);
                    continue;
                }
                if (bias) v += bias[col];
                if (relu) v = fmaxf(v, 0.f);
                if (OMODE == 0) {
                    float* C = (float*)Cv;
                    if (res) v += res[(size_t)row * N + col];
                    C[(size_t)row * N + col] = v;
                } else {
                    ((__hip_bfloat16*)Cv)[(size_t)row * N + col] = __float2bfloat16(v);
                }
            }
        }
    }
    (void)M;
}

// ---------------------------------------------------------------- MFMA flash attention (S^T orientation)
// Block = 4 waves = 256 queries of one (b,h); wave owns 64 queries (4 qt-tiles).
// K/VT staging shared by all 4 waves (each wave stages 2 of 8 column-groups).
// XCD-bijective remap keeps the 4 q-blocks of one (b,h) on one XCD (K/VT L2-local).
__global__ __launch_bounds__(256, 2) void attn_mfma_kernel(
    const __hip_bfloat16* __restrict__ q, const __hip_bfloat16* __restrict__ k,
    const __hip_bfloat16* __restrict__ v, const int* __restrict__ mask,
    __hip_bfloat16* __restrict__ ao)
{
    __shared__ short sK[2][64 * 64];
    __shared__ short sVT[2][64 * 64];
    __shared__ short sP[4][64 * 64];
    __shared__ float mskf[SEQ];
    int bid = blockIdx.x;                 // 384 = 8 XCD x 48
    int xcd = bid & 7, j = bid >> 3;      // j in 0..47
    int bh  = ((j >> 2) << 3) | xcd;      // bijective: bh in 0..95
    int qt4 = j & 3;
    int b = bh / NHEAD, hh = bh % NHEAD;
    int t = threadIdx.x, w = t >> 6, lane = t & 63;
    int l16 = lane & 15, quad = lane >> 4;
    const float scale = 0.036084391824351615f;  // 768^-0.5
    const f32x4 zf = {0.f, 0.f, 0.f, 0.f};

    #pragma unroll
    for (int i = 0; i < 4; i++) {
        int idx = t + i * 256;
        mskf[idx] = mask[b * SEQ + idx] ? 0.f : -1e30f;
    }

    // Q B-frags: lane n=query(l16), k=dim s*32+quad*8..+7
    int qb0 = qt4 * 256 + w * 64;
    const __hip_bfloat16* qbase = q + ((size_t)bh * SEQ + qb0) * HS;
    bf16x8 qf[4][2];
    #pragma unroll
    for (int qt = 0; qt < 4; qt++)
        #pragma unroll
        for (int s = 0; s < 2; s++)
            qf[qt][s] = *(const bf16x8*)(qbase + (qt * 16 + l16) * HS + s * 32 + quad * 8);

    f32x4 accO[4][4];            // [dt][qt]: O^T tile, row=dim dt*16+quad*4+r, col=query qt*16+l16
    float m_st[4], l_st[4];
    #pragma unroll
    for (int dt = 0; dt < 4; dt++)
        #pragma unroll
        for (int qt = 0; qt < 4; qt++) accO[dt][qt] = zf;
    #pragma unroll
    for (int qt = 0; qt < 4; qt++) { m_st[qt] = -1e30f; l_st[qt] = 0.f; }

    // staging geometry: 4 waves x 2 column-groups cover c=0..7 (8 rows each)
    int rowL = lane >> 3;
    int sgl = ((lane & 7) ^ ((lane >> 3) & 7)) * 8;   // swizzled global seg (shorts)
    const __hip_bfloat16* kg0 = k + ((size_t)bh * SEQ) * HS;
    const __hip_bfloat16* vtg0 = v + (size_t)bh * HS * SEQ;   // v pre-transposed (bh,e,s)
    short* myP = &sP[w][0];

    // prologue: stage K-tile 0 into buffer 0
    #pragma unroll
    for (int i = 0; i < 2; i++) {
        int c = w * 2 + i;
        int rr = c * 8 + rowL;
        gld16(kg0  + (size_t)rr * HS  + sgl, (char*)&sK[0][0]  + c * 1024);
        gld16(vtg0 + (size_t)rr * SEQ + sgl, (char*)&sVT[0][0] + c * 1024);
    }
    __syncthreads();

    int buf = 0;
    for (int kc = 0; kc < 16; kc++) {
        // prefetch next K-tile into the other buffer (in flight during compute)
        if (kc < 15) {
            const __hip_bfloat16* kg  = kg0  + (size_t)(kc + 1) * 64 * HS;
            const __hip_bfloat16* vtg = vtg0 + (kc + 1) * 64;
            #pragma unroll
            for (int i = 0; i < 2; i++) {
                int c = w * 2 + i;
                int rr = c * 8 + rowL;
                gld16(kg  + (size_t)rr * HS  + sgl, (char*)&sK[buf ^ 1][0]  + c * 1024);
                gld16(vtg + (size_t)rr * SEQ + sgl, (char*)&sVT[buf ^ 1][0] + c * 1024);
            }
        }
        short* cK  = &sK[buf][0];
        short* cVT = &sVT[buf][0];

        // all sK/sVT reads up front
        bf16x8 vf[4][2];
        #pragma unroll
        for (int dt = 0; dt < 4; dt++)
            #pragma unroll
            for (int s = 0; s < 2; s++)
                vf[dt][s] = *(bf16x8*)&cVT[(dt * 16 + l16) * 64 + (((s * 4 + quad) ^ (l16 & 7)) * 8)];
        f32x4 sc[4][4];   // [kt][qt]
        #pragma unroll
        for (int kt = 0; kt < 4; kt++) {
            bf16x8 kf0 = *(bf16x8*)&cK[(kt * 16 + l16) * 64 + ((quad ^ (l16 & 7)) * 8)];
            bf16x8 kf1 = *(bf16x8*)&cK[(kt * 16 + l16) * 64 + (((4 + quad) ^ (l16 & 7)) * 8)];
            #pragma unroll
            for (int qt = 0; qt < 4; qt++) {
                f32x4 c = __builtin_amdgcn_mfma_f32_16x16x32_bf16(kf0, qf[qt][0], zf, 0, 0, 0);
                sc[kt][qt] = __builtin_amdgcn_mfma_f32_16x16x32_bf16(kf1, qf[qt][1], c, 0, 0, 0);
            }
        }
        // scale + mask (mask indexed by key row)
        #pragma unroll
        for (int kt = 0; kt < 4; kt++) {
            f32x4 mk = *(f32x4*)&mskf[kc * 64 + kt * 16 + quad * 4];
            #pragma unroll
            for (int qt = 0; qt < 4; qt++)
                #pragma unroll
                for (int r = 0; r < 4; r++)
                    sc[kt][qt][r] = sc[kt][qt][r] * scale + mk[r];
        }
        // online softmax per query column
        #pragma unroll
        for (int qt = 0; qt < 4; qt++) {
            float rm = -1e30f;
            #pragma unroll
            for (int kt = 0; kt < 4; kt++)
                #pragma unroll
                for (int r = 0; r < 4; r++) rm = fmaxf(rm, sc[kt][qt][r]);
            rm = fmaxf(rm, __shfl_xor(rm, 16));
            rm = fmaxf(rm, __shfl_xor(rm, 32));
            float mnew = fmaxf(m_st[qt], rm);
            float corr = __expf(m_st[qt] - mnew);
            m_st[qt] = mnew;
            float ps = 0.f;
            #pragma unroll
            for (int kt = 0; kt < 4; kt++) {
                union { uint2 u; short s[4]; } pk;
                #pragma unroll
                for (int r = 0; r < 4; r++) {
                    float p = __expf(sc[kt][qt][r] - mnew);
                    ps += p;
                    pk.s[r] = f2bf_s(p);
                }
                *(uint2*)&myP[(qt * 16 + l16) * 64 +
                              (((kt * 2 + (quad >> 1)) ^ (l16 & 7)) * 8) + (quad & 1) * 4] = pk.u;
            }
            ps += __shfl_xor(ps, 16);
            ps += __shfl_xor(ps, 32);
            l_st[qt] = l_st[qt] * corr + ps;
            #pragma unroll
            for (int dt = 0; dt < 4; dt++) accO[dt][qt] *= corr;
        }
        asm volatile("" ::: "memory");   // keep pf reads after P writes (same-wave DS is in-order)
        // PV: O^T += V^T @ P^T
        #pragma unroll
        for (int qt = 0; qt < 4; qt++) {
            bf16x8 pf0 = *(bf16x8*)&myP[(qt * 16 + l16) * 64 + ((quad ^ (l16 & 7)) * 8)];
            bf16x8 pf1 = *(bf16x8*)&myP[(qt * 16 + l16) * 64 + (((4 + quad) ^ (l16 & 7)) * 8)];
            #pragma unroll
            for (int dt = 0; dt < 4; dt++) {
                accO[dt][qt] = __builtin_amdgcn_mfma_f32_16x16x32_bf16(vf[dt][0], pf0, accO[dt][qt], 0, 0, 0);
                accO[dt][qt] = __builtin_amdgcn_mfma_f32_16x16x32_bf16(vf[dt][1], pf1, accO[dt][qt], 0, 0, 0);
            }
        }
        __syncthreads();   // drains prefetch (full compute phase to land); next buffer ready
        buf ^= 1;
    }

    // epilogue: O = O^T / l, pack 4 consecutive dims per b64 store
    #pragma unroll
    for (int qt = 0; qt < 4; qt++) {
        float inv = 1.f / l_st[qt];
        int row = qb0 + qt * 16 + l16;
        __hip_bfloat16* orow = ao + ((size_t)(b * SEQ + row)) * D_MODEL + hh * HS;
        #pragma unroll
        for (int dt = 0; dt < 4; dt++) {
            union { uint2 u; short s[4]; } pk;
            #pragma unroll
            for (int r = 0; r < 4; r++) pk.s[r] = f2bf_s(accO[dt][qt][r] * inv);
            *(uint2*)(orow + dt * 16 + quad * 4) = pk.u;
        }
    }
}

// ---------------------------------------------------------------- head FC1: (8,768)@(768,3072)+relu
__global__ __launch_bounds__(256) void fc1_kernel(
    const float* __restrict__ A, const float* __restrict__ W,
    const float* __restrict__ bias, float* __restrict__ out)
{
    __shared__ float sa[D_MODEL];
    int row = blockIdx.x, t = threadIdx.x;
    for (int i = t; i < D_MODEL; i += 256) sa[i] = A[(size_t)row * D_MODEL + i];
    __syncthreads();
    int col = blockIdx.y * 256 + t;
    float s = 0.f;
    #pragma unroll 8
    for (int kk = 0; kk < D_MODEL; kk++) s = fmaf(sa[kk], W[(size_t)kk * DFF + col], s);
    s += bias[col];
    out[(size_t)row * DFF + col] = fmaxf(s, 0.f);
}

// ---------------------------------------------------------------- head FC2: (8,3072)@(3072,16)
__global__ __launch_bounds__(256) void fc2_kernel(
    const float* __restrict__ A, const float* __restrict__ W,
    const float* __restrict__ bias, float* __restrict__ out)
{
    __shared__ float wred[4][NCLS];
    int row = blockIdx.x, t = threadIdx.x;
    int wave = t >> 6, lane = t & 63;
    const float* a = A + (size_t)row * DFF;
    float acc[NCLS];
    #pragma unroll
    for (int c = 0; c < NCLS; c++) acc[c] = 0.f;
    for (int kk = t; kk < DFF; kk += 256) {
        float av = a[kk];
        const float4* wr = (const float4*)(W + (size_t)kk * NCLS);
        float4 w0 = wr[0], w1 = wr[1], w2 = wr[2], w3 = wr[3];
        acc[0]  = fmaf(av, w0.x, acc[0]);  acc[1]  = fmaf(av, w0.y, acc[1]);
        acc[2]  = fmaf(av, w0.z, acc[2]);  acc[3]  = fmaf(av, w0.w, acc[3]);
        acc[4]  = fmaf(av, w1.x, acc[4]);  acc[5]  = fmaf(av, w1.y, acc[5]);
        acc[6]  = fmaf(av, w1.z, acc[6]);  acc[7]  = fmaf(av, w1.w, acc[7]);
        acc[8]  = fmaf(av, w2.x, acc[8]);  acc[9]  = fmaf(av, w2.y, acc[9]);
        acc[10] = fmaf(av, w2.z, acc[10]); acc[11] = fmaf(av, w2.w, acc[11]);
        acc[12] = fmaf(av, w3.x, acc[12]); acc[13] = fmaf(av, w3.y, acc[13]);
        acc[14] = fmaf(av, w3.z, acc[14]); acc[15] = fmaf(av, w3.w, acc[15]);
    }
    #pragma unroll
    for (int c = 0; c < NCLS; c++)
        #pragma unroll
        for (int off = 32; off; off >>= 1) acc[c] += __shfl_down(acc[c], off);
    if (lane == 0)
        #pragma unroll
        for (int c = 0; c < NCLS; c++) wred[wave][c] = acc[c];
    __syncthreads();
    if (t < NCLS)
        out[row * NCLS + t] = wred[0][t] + wred[1][t] + wred[2][t] + wred[3][t] + bias[t];
}

// ---------------------------------------------------------------- launch
extern "C" void kernel_launch(void* const* d_in, const int* in_sizes, int n_in,
                              void* d_out, int out_size, void* d_ws, size_t ws_size,
                              hipStream_t stream)
{
    const int*   x     = (const int*)  d_in[0];
    const int*   amask = (const int*)  d_in[1];
    const float* tok   = (const float*)d_in[2];
    const float* pos   = (const float*)d_in[3];
    const float* Wq    = (const float*)d_in[4];
    const float* Wk    = (const float*)d_in[5];
    const float* Wv    = (const float*)d_in[6];
    const float* Wo    = (const float*)d_in[7];
    const float* bo    = (const float*)d_in[8];
    const float* ln1w  = (const float*)d_in[9];
    const float* ln1b  = (const float*)d_in[10];
    const float* ln2w  = (const float*)d_in[11];
    const float* ln2b  = (const float*)d_in[12];
    const float* W1    = (const float*)d_in[13];
    const float* b1    = (const float*)d_in[14];
    const float* W2    = (const float*)d_in[15];
    const float* b2    = (const float*)d_in[16];
    const float* lnfw  = (const float*)d_in[17];
    const float* lnfb  = (const float*)d_in[18];
    const float* cW1   = (const float*)d_in[19];
    const float* cb1   = (const float*)d_in[20];
    const float* cW2   = (const float*)d_in[21];
    const float* cb2   = (const float*)d_in[22];

    char* base = (char*)d_ws;
    const size_t MD = (size_t)MROWS * D_MODEL;
    float* h = (float*)base;                         base += MD * 4;
    __hip_bfloat16* xn = (__hip_bfloat16*)base;      base += MD * 2;
    __hip_bfloat16* qb = (__hip_bfloat16*)base;      base += MD * 2;
    __hip_bfloat16* kb = (__hip_bfloat16*)base;      base += MD * 2;
    __hip_bfloat16* vb = (__hip_bfloat16*)base;      base += MD * 2;   // holds V^T (bh,e,s)
    __hip_bfloat16* vT = (__hip_bfloat16*)base;      base += MD * 2;   // unused (kept for layout)
    __hip_bfloat16* ff = (__hip_bfloat16*)base;      base += (size_t)MROWS * DFF * 2;
    float* lnf = (float*)base;                       base += (size_t)NB * D_MODEL * 4;
    float* cls = (float*)base;                       base += (size_t)NB * DFF * 4;
    __hip_bfloat16* wQKV = (__hip_bfloat16*)base;    base += (size_t)NLAYER * 3 * D_MODEL * D_MODEL * 2;
    __hip_bfloat16* wTo = (__hip_bfloat16*)base;     base += (size_t)NLAYER * D_MODEL * D_MODEL * 2;
    __hip_bfloat16* wT1 = (__hip_bfloat16*)base;     base += (size_t)NLAYER * D_MODEL * DFF * 2;
    __hip_bfloat16* wT2 = (__hip_bfloat16*)base;     base += (size_t)NLAYER * DFF * D_MODEL * 2;
    (void)vT;

    const size_t SQW = (size_t)D_MODEL * D_MODEL;
    const size_t SFF = (size_t)D_MODEL * DFF;

    convw_kernel<1><<<dim3(12,12,4), 256, 0, stream>>>(Wq, wQKV + 0 * SQW, D_MODEL, D_MODEL, SQW, 3 * SQW);
    convw_kernel<1><<<dim3(12,12,4), 256, 0, stream>>>(Wk, wQKV + 1 * SQW, D_MODEL, D_MODEL, SQW, 3 * SQW);
    convw_kernel<1><<<dim3(12,12,4), 256, 0, stream>>>(Wv, wQKV + 2 * SQW, D_MODEL, D_MODEL, SQW, 3 * SQW);
    convw_kernel<0><<<dim3(12,12,4), 256, 0, stream>>>(Wo, wTo, D_MODEL, D_MODEL, SQW, SQW);
    convw_kernel<0><<<dim3(12,48,4), 256, 0, stream>>>(W1, wT1, D_MODEL, DFF, SFF, SFF);
    convw_kernel<0><<<dim3(48,12,4), 256, 0, stream>>>(W2, wT2, DFF, D_MODEL, SFF, SFF);

    embed_kernel<<<MROWS / 4, 256, 0, stream>>>(x, tok, pos, h);

    dim3 gQKV(MROWS / 128, (3 * D_MODEL) / 128);
    dim3 gDS(MROWS / 128, D_MODEL / 128, 2);   // split-K=2
    dim3 gF(MROWS / 128, DFF / 128);
    for (int l = 0; l < NLAYER; l++) {
        ln_kernel<1><<<MROWS / 4, 256, 0, stream>>>(h, ln1w + l * D_MODEL, ln1b + l * D_MODEL, xn, 1, 0);
        gemm128<1><<<gQKV, 256, 0, stream>>>(xn, wQKV + l * 3 * SQW, nullptr, nullptr, qb, MROWS, 3 * D_MODEL, D_MODEL, 0);
        attn_mfma_kernel<<<NB * NHEAD * 4, 256, 0, stream>>>(qb, kb, vb, amask, xn);
        gemm128<3><<<gDS, 256, 0, stream>>>(xn, wTo + l * SQW, bo + l * D_MODEL, nullptr, h, MROWS, D_MODEL, D_MODEL, 0);
        ln_kernel<1><<<MROWS / 4, 256, 0, stream>>>(h, ln2w + l * D_MODEL, ln2b + l * D_MODEL, xn, 1, 0);
        gemm128<2><<<gF, 256, 0, stream>>>(xn, wT1 + l * SFF, b1 + l * DFF, nullptr, ff, MROWS, DFF, D_MODEL, 1);
        gemm128<3><<<gDS, 256, 0, stream>>>(ff, wT2 + l * SFF, b2 + l * D_MODEL, nullptr, h, MROWS, D_MODEL, DFF, 0);
    }
    ln_kernel<0><<<NB / 4, 256, 0, stream>>>(h, lnfw, lnfb, lnf, SEQ, SEQ - 1);
    fc1_kernel<<<dim3(NB, DFF / 256), 256, 0, stream>>>(lnf, cW1, cb1, cls);
    fc2_kernel<<<NB, 256, 0, stream>>>(cls, cW2, cb2, (float*)d_out);
}

// Round 8
// 1553.551 us; speedup vs baseline: 1.2422x; 1.0364x over previous
//
#include <hip/hip_runtime.h>
#include <hip/hip_bf16.h>

#define D_MODEL 768
#define SEQ     1024
#define NB      8
#define NHEAD   12
#define HS      64
#define NLAYER  4
#define DFF     3072
#define NCLS    16
#define MROWS   (NB*SEQ)   // 8192

typedef float f32x4  __attribute__((ext_vector_type(4)));
typedef short bf16x8 __attribute__((ext_vector_type(8)));

__device__ __forceinline__ short f2bf_s(float x) {
    __hip_bfloat16 h = __float2bfloat16(x);
    union { __hip_bfloat16 h; short s; } u; u.h = h; return u.s;
}

// async global->LDS, 16B per lane; lds base must be wave-uniform (HW adds lane*16)
__device__ __forceinline__ void gld16(const void* g, void* l) {
    __builtin_amdgcn_global_load_lds((const __attribute__((address_space(1))) void*)g,
                                     (__attribute__((address_space(3))) void*)l, 16, 0, 0);
}

// ---------------------------------------------------------------- embedding
// one row per WAVE: 12 f32/lane via float4, no LDS/barriers. grid = MROWS/4.
__global__ __launch_bounds__(256) void embed_kernel(
    const int* __restrict__ x, const float* __restrict__ tok,
    const float* __restrict__ pos, float* __restrict__ h)
{
    int wave = threadIdx.x >> 6, lane = threadIdx.x & 63;
    int row = blockIdx.x * 4 + wave;
    int s   = row & (SEQ - 1);
    int id  = x[row];
    const float4* te = (const float4*)(tok + (size_t)id * D_MODEL);
    const float4* pe = (const float4*)(pos + (size_t)s  * D_MODEL);
    float4* hr = (float4*)(h + (size_t)row * D_MODEL);
    #pragma unroll
    for (int j = 0; j < 3; j++) {
        float4 a = te[j * 64 + lane], p = pe[j * 64 + lane];
        a.x += p.x; a.y += p.y; a.z += p.z; a.w += p.w;
        hr[j * 64 + lane] = a;
    }
}

// ---------------------------------------------------------------- layernorm
// one row per WAVE (4 rows/block): float4 loads, full-wave shfl_xor reduce,
// ZERO LDS / barriers. grid = rows/4.
template<int BF16OUT>
__global__ __launch_bounds__(256) void ln_kernel(
    const float* __restrict__ in, const float* __restrict__ w,
    const float* __restrict__ b, void* __restrict__ outv,
    int row_stride, int row_offset)
{
    int wave = threadIdx.x >> 6, lane = threadIdx.x & 63;
    int r = blockIdx.x * 4 + wave;
    const float4* xr = (const float4*)(in + (size_t)(r * row_stride + row_offset) * D_MODEL);
    float4 v0 = xr[lane], v1 = xr[64 + lane], v2 = xr[128 + lane];
    float s = v0.x + v0.y + v0.z + v0.w
            + v1.x + v1.y + v1.z + v1.w
            + v2.x + v2.y + v2.z + v2.w;
    #pragma unroll
    for (int off = 32; off; off >>= 1) s += __shfl_xor(s, off);
    float mu = s * (1.f / D_MODEL);
    float4 d0, d1, d2;
    d0.x = v0.x - mu; d0.y = v0.y - mu; d0.z = v0.z - mu; d0.w = v0.w - mu;
    d1.x = v1.x - mu; d1.y = v1.y - mu; d1.z = v1.z - mu; d1.w = v1.w - mu;
    d2.x = v2.x - mu; d2.y = v2.y - mu; d2.z = v2.z - mu; d2.w = v2.w - mu;
    float q = d0.x*d0.x + d0.y*d0.y + d0.z*d0.z + d0.w*d0.w
            + d1.x*d1.x + d1.y*d1.y + d1.z*d1.z + d1.w*d1.w
            + d2.x*d2.x + d2.y*d2.y + d2.z*d2.z + d2.w*d2.w;
    #pragma unroll
    for (int off = 32; off; off >>= 1) q += __shfl_xor(q, off);
    float rstd = rsqrtf(q * (1.f / D_MODEL) + 1e-5f);
    const float4* w4 = (const float4*)w;
    const float4* b4 = (const float4*)b;
    float4 dd[3] = {d0, d1, d2};
    if (BF16OUT) {
        short* yr = (short*)outv + (size_t)r * D_MODEL;
        #pragma unroll
        for (int j = 0; j < 3; j++) {
            float4 ww = w4[j * 64 + lane], bb = b4[j * 64 + lane];
            union { uint2 u; short s[4]; } pk;
            pk.s[0] = f2bf_s(dd[j].x * rstd * ww.x + bb.x);
            pk.s[1] = f2bf_s(dd[j].y * rstd * ww.y + bb.y);
            pk.s[2] = f2bf_s(dd[j].z * rstd * ww.z + bb.z);
            pk.s[3] = f2bf_s(dd[j].w * rstd * ww.w + bb.w);
            *(uint2*)(yr + j * 256 + lane * 4) = pk.u;
        }
    } else {
        float4* yr = (float4*)((float*)outv + (size_t)r * D_MODEL);
        #pragma unroll
        for (int j = 0; j < 3; j++) {
            float4 ww = w4[j * 64 + lane], bb = b4[j * 64 + lane];
            float4 y;
            y.x = dd[j].x * rstd * ww.x + bb.x;
            y.y = dd[j].y * rstd * ww.y + bb.y;
            y.z = dd[j].z * rstd * ww.z + bb.z;
            y.w = dd[j].w * rstd * ww.w + bb.w;
            yr[j * 64 + lane] = y;
        }
    }
}

// --------------------------------------------- weight convert+transpose to bf16
template<int MODE>
__global__ __launch_bounds__(256) void convw_kernel(
    const float* __restrict__ W, __hip_bfloat16* __restrict__ BT,
    int K, int N, size_t in_stride, size_t out_stride)
{
    __shared__ __hip_bfloat16 sT[64][72];
    W  += (size_t)blockIdx.z * in_stride;
    BT += (size_t)blockIdx.z * out_stride;
    int k0 = blockIdx.x * 64, n0 = blockIdx.y * 64;
    int t = threadIdx.x;
    int kl = t >> 4, nl4 = (t & 15) * 4;
    #pragma unroll
    for (int i = 0; i < 4; i++) {
        int k = k0 + kl + i * 16;
        int n = n0 + nl4;
        const float* src = (MODE == 0) ? (W + (size_t)k * N + n)
                                       : (W + ((size_t)(n >> 6) * K + k) * 64 + (n & 63));
        float4 v = *(const float4*)src;
        sT[nl4 + 0][kl + i*16] = __float2bfloat16(v.x);
        sT[nl4 + 1][kl + i*16] = __float2bfloat16(v.y);
        sT[nl4 + 2][kl + i*16] = __float2bfloat16(v.z);
        sT[nl4 + 3][kl + i*16] = __float2bfloat16(v.w);
    }
    __syncthreads();
    int nl = t >> 2, seg = (t & 3) * 16;
    uint4* dst = (uint4*)(BT + (size_t)(n0 + nl) * K + k0 + seg);
    dst[0] = *(uint4*)&sT[nl][seg];
    dst[1] = *(uint4*)&sT[nl][seg + 8];
}

// ---------------------------------------------------------------- bf16 MFMA GEMM
// 128x128 tile, 8 WAVES (512 thr): wave grid 2M x 4N, each wave owns 64x32
// (acc 4x2, 6 ds_reads, 8 MFMA per K-step). Same 3-buffer / 2-deep prefetch /
// counted-vmcnt / single-barrier schedule as before; waves/SIMD 3 -> 6 for
// latency hiding (the measured limiter: no pipe above ~57%, convoy-bound).
// Staging: each wave stages one 16-row chunk of A and of B (2 gld16/thread,
// so steady-state wait is vmcnt(2)). Swizzle algebra unchanged.
// OMODE: 0 = f32 out (+bias,+res)   1 = QKV scatter (V third written TRANSPOSED
//        to (bh,e,s) with packed uint2 stores)   2 = bf16 out
//        3 = split-K over blockIdx.z, atomicAdd f32 into C
template<int OMODE>
__global__ __launch_bounds__(512, 6) void gemm128(
    const __hip_bfloat16* __restrict__ A, const __hip_bfloat16* __restrict__ BT,
    const float* __restrict__ bias, const float* __restrict__ res,
    void* __restrict__ Cv, int M, int N, int K, int relu)
{
    __shared__ short sA[3][128 * 32];
    __shared__ short sB[3][128 * 32];
    int t = threadIdx.x;
    int wave = t >> 6, lane = t & 63;
    int l16 = lane & 15, quad = (lane >> 4) & 3;
    int wm = wave >> 2, wn = wave & 3;          // 2M x 4N wave grid
    int bm = blockIdx.x * 128, bn = blockIdx.y * 128;

    int kbeg = 0, kend = K;
    if (OMODE == 3) { int KS = K >> 1; kbeg = blockIdx.z * KS; kend = kbeg + KS; }
    int nsteps = (kend - kbeg) >> 5;

    int u = lane >> 2;
    int skey = ((u & 3) ^ ((u >> 2) & 3));
    int sseg = (lane & 3) ^ skey;
    int fkey = ((l16 & 3) ^ ((l16 >> 2) & 3));

    const f32x4 zf = {0.f, 0.f, 0.f, 0.f};
    f32x4 acc[4][2];
    #pragma unroll
    for (int mi = 0; mi < 4; mi++)
        #pragma unroll
        for (int ni = 0; ni < 2; ni++) acc[mi][ni] = zf;

    // each wave stages chunk 'wave' (16 rows) of A and of B
    const __hip_bfloat16* pA = A  + (size_t)(bm + (wave << 4) + u) * K + kbeg + sseg * 8;
    const __hip_bfloat16* pB = BT + (size_t)(bn + (wave << 4) + u) * K + kbeg + sseg * 8;

    #define STAGE(bufi, kk) do { \
        gld16(pA + (kk), &sA[bufi][wave * 512]); \
        gld16(pB + (kk), &sB[bufi][wave * 512]); \
    } while (0)

    STAGE(0, 0);
    if (nsteps > 1) STAGE(1, 32);

    int bufr = 0, bufs = 2;
    for (int it = 0; it < nsteps; ++it) {
        // wait own loads for tile 'it' (tile it+1's 2 ops stay in flight)
        if (it + 1 < nsteps) { asm volatile("s_waitcnt vmcnt(2)" ::: "memory"); }
        else                 { asm volatile("s_waitcnt vmcnt(0)" ::: "memory"); }
        __builtin_amdgcn_sched_barrier(0);
        __builtin_amdgcn_s_barrier();
        __builtin_amdgcn_sched_barrier(0);

        const short* curA = &sA[bufr][0];
        const short* curB = &sB[bufr][0];
        bf16x8 aF[4], bF[2];
        #pragma unroll
        for (int mi = 0; mi < 4; mi++)
            aF[mi] = *(const bf16x8*)&curA[(wm * 64 + mi * 16 + l16) * 32 + ((quad ^ fkey) * 8)];
        #pragma unroll
        for (int ni = 0; ni < 2; ni++)
            bF[ni] = *(const bf16x8*)&curB[(wn * 32 + ni * 16 + l16) * 32 + ((quad ^ fkey) * 8)];

        if (it + 2 < nsteps) STAGE(bufs, (it + 2) * 32);   // 2-ahead prefetch

        // compiler-managed counted lgkm waits; all frags consumed below, so this
        // wave's ds_reads complete before it reaches the next barrier (WAR ok).
        #pragma unroll
        for (int ni = 0; ni < 2; ni++)
            #pragma unroll
            for (int mi = 0; mi < 4; mi++)
                acc[mi][ni] = __builtin_amdgcn_mfma_f32_16x16x32_bf16(aF[mi], bF[ni], acc[mi][ni], 0, 0, 0);

        bufr = (bufr == 2) ? 0 : bufr + 1;
        bufs = (bufs == 2) ? 0 : bufs + 1;
    }
    #undef STAGE

    #pragma unroll
    for (int mi = 0; mi < 4; mi++) {
        #pragma unroll
        for (int ni = 0; ni < 2; ni++) {
            int row0 = bm + wm * 64 + mi * 16 + quad * 4;
            int col  = bn + wn * 32 + ni * 16 + l16;
            if (OMODE == 1) {
                // QKV scatter. row0 % 4 == 0, rows row0..row0+3 share bb.
                int which = col / D_MODEL, cc = col % D_MODEL;
                int hh = cc >> 6, e = cc & 63;
                int bb = row0 >> 10, ss0 = row0 & 1023;
                union { uint2 u; short s[4]; } pk;
                #pragma unroll
                for (int r = 0; r < 4; r++) pk.s[r] = f2bf_s(acc[mi][ni][r]);
                __hip_bfloat16* dstb = (__hip_bfloat16*)Cv + (size_t)which * MROWS * D_MODEL;
                if (which == 2) {
                    // V -> (bh, e, s) transposed; 4 consecutive s -> one uint2
                    *(uint2*)(dstb + ((size_t)(bb * NHEAD + hh)) * HS * SEQ + (size_t)e * SEQ + ss0) = pk.u;
                } else {
                    short* p = (short*)(dstb + (((size_t)(bb * NHEAD + hh)) * SEQ + ss0) * HS + e);
                    #pragma unroll
                    for (int r = 0; r < 4; r++) p[r * HS] = pk.s[r];
                }
                continue;
            }
            #pragma unroll
            for (int r = 0; r < 4; r++) {
                int row = row0 + r;
                float v = acc[mi][ni][r];
                if (OMODE == 3) {
                    float* C = (float*)Cv;
                    if (blockIdx.z == 0 && bias) v += bias[col];
                    unsafeAtomicAdd(&C[(size_t)row * N + col], v);
                    continue;
                }
                if (bias) v += bias[col];
                if (relu) v = fmaxf(v, 0.f);
                if (OMODE == 0) {
                    float* C = (float*)Cv;
                    if (res) v += res[(size_t)row * N + col];
                    C[(size_t)row * N + col] = v;
                } else {
                    ((__hip_bfloat16*)Cv)[(size_t)row * N + col] = __float2bfloat16(v);
                }
            }
        }
    }
    (void)M;
}

// ---------------------------------------------------------------- MFMA flash attention (S^T orientation)
// Block = 4 waves = 256 queries of one (b,h); wave owns 64 queries (4 qt-tiles).
// K/VT staging shared by all 4 waves (each wave stages 2 of 8 column-groups).
// XCD-bijective remap keeps the 4 q-blocks of one (b,h) on one XCD (K/VT L2-local).
__global__ __launch_bounds__(256, 2) void attn_mfma_kernel(
    const __hip_bfloat16* __restrict__ q, const __hip_bfloat16* __restrict__ k,
    const __hip_bfloat16* __restrict__ v, const int* __restrict__ mask,
    __hip_bfloat16* __restrict__ ao)
{
    __shared__ short sK[2][64 * 64];
    __shared__ short sVT[2][64 * 64];
    __shared__ short sP[4][64 * 64];
    __shared__ float mskf[SEQ];
    int bid = blockIdx.x;                 // 384 = 8 XCD x 48
    int xcd = bid & 7, j = bid >> 3;      // j in 0..47
    int bh  = ((j >> 2) << 3) | xcd;      // bijective: bh in 0..95
    int qt4 = j & 3;
    int b = bh / NHEAD, hh = bh % NHEAD;
    int t = threadIdx.x, w = t >> 6, lane = t & 63;
    int l16 = lane & 15, quad = lane >> 4;
    const float scale = 0.036084391824351615f;  // 768^-0.5
    const f32x4 zf = {0.f, 0.f, 0.f, 0.f};

    #pragma unroll
    for (int i = 0; i < 4; i++) {
        int idx = t + i * 256;
        mskf[idx] = mask[b * SEQ + idx] ? 0.f : -1e30f;
    }

    // Q B-frags: lane n=query(l16), k=dim s*32+quad*8..+7
    int qb0 = qt4 * 256 + w * 64;
    const __hip_bfloat16* qbase = q + ((size_t)bh * SEQ + qb0) * HS;
    bf16x8 qf[4][2];
    #pragma unroll
    for (int qt = 0; qt < 4; qt++)
        #pragma unroll
        for (int s = 0; s < 2; s++)
            qf[qt][s] = *(const bf16x8*)(qbase + (qt * 16 + l16) * HS + s * 32 + quad * 8);

    f32x4 accO[4][4];            // [dt][qt]: O^T tile, row=dim dt*16+quad*4+r, col=query qt*16+l16
    float m_st[4], l_st[4];
    #pragma unroll
    for (int dt = 0; dt < 4; dt++)
        #pragma unroll
        for (int qt = 0; qt < 4; qt++) accO[dt][qt] = zf;
    #pragma unroll
    for (int qt = 0; qt < 4; qt++) { m_st[qt] = -1e30f; l_st[qt] = 0.f; }

    // staging geometry: 4 waves x 2 column-groups cover c=0..7 (8 rows each)
    int rowL = lane >> 3;
    int sgl = ((lane & 7) ^ ((lane >> 3) & 7)) * 8;   // swizzled global seg (shorts)
    const __hip_bfloat16* kg0 = k + ((size_t)bh * SEQ) * HS;
    const __hip_bfloat16* vtg0 = v + (size_t)bh * HS * SEQ;   // v pre-transposed (bh,e,s)
    short* myP = &sP[w][0];

    // prologue: stage K-tile 0 into buffer 0
    #pragma unroll
    for (int i = 0; i < 2; i++) {
        int c = w * 2 + i;
        int rr = c * 8 + rowL;
        gld16(kg0  + (size_t)rr * HS  + sgl, (char*)&sK[0][0]  + c * 1024);
        gld16(vtg0 + (size_t)rr * SEQ + sgl, (char*)&sVT[0][0] + c * 1024);
    }
    __syncthreads();

    int buf = 0;
    for (int kc = 0; kc < 16; kc++) {
        // prefetch next K-tile into the other buffer (in flight during compute)
        if (kc < 15) {
            const __hip_bfloat16* kg  = kg0  + (size_t)(kc + 1) * 64 * HS;
            const __hip_bfloat16* vtg = vtg0 + (kc + 1) * 64;
            #pragma unroll
            for (int i = 0; i < 2; i++) {
                int c = w * 2 + i;
                int rr = c * 8 + rowL;
                gld16(kg  + (size_t)rr * HS  + sgl, (char*)&sK[buf ^ 1][0]  + c * 1024);
                gld16(vtg + (size_t)rr * SEQ + sgl, (char*)&sVT[buf ^ 1][0] + c * 1024);
            }
        }
        short* cK  = &sK[buf][0];
        short* cVT = &sVT[buf][0];

        // all sK/sVT reads up front
        bf16x8 vf[4][2];
        #pragma unroll
        for (int dt = 0; dt < 4; dt++)
            #pragma unroll
            for (int s = 0; s < 2; s++)
                vf[dt][s] = *(bf16x8*)&cVT[(dt * 16 + l16) * 64 + (((s * 4 + quad) ^ (l16 & 7)) * 8)];
        f32x4 sc[4][4];   // [kt][qt]
        #pragma unroll
        for (int kt = 0; kt < 4; kt++) {
            bf16x8 kf0 = *(bf16x8*)&cK[(kt * 16 + l16) * 64 + ((quad ^ (l16 & 7)) * 8)];
            bf16x8 kf1 = *(bf16x8*)&cK[(kt * 16 + l16) * 64 + (((4 + quad) ^ (l16 & 7)) * 8)];
            #pragma unroll
            for (int qt = 0; qt < 4; qt++) {
                f32x4 c = __builtin_amdgcn_mfma_f32_16x16x32_bf16(kf0, qf[qt][0], zf, 0, 0, 0);
                sc[kt][qt] = __builtin_amdgcn_mfma_f32_16x16x32_bf16(kf1, qf[qt][1], c, 0, 0, 0);
            }
        }
        // scale + mask (mask indexed by key row)
        #pragma unroll
        for (int kt = 0; kt < 4; kt++) {
            f32x4 mk = *(f32x4*)&mskf[kc * 64 + kt * 16 + quad * 4];
            #pragma unroll
            for (int qt = 0; qt < 4; qt++)
                #pragma unroll
                for (int r = 0; r < 4; r++)
                    sc[kt][qt][r] = sc[kt][qt][r] * scale + mk[r];
        }
        // online softmax per query column
        #pragma unroll
        for (int qt = 0; qt < 4; qt++) {
            float rm = -1e30f;
            #pragma unroll
            for (int kt = 0; kt < 4; kt++)
                #pragma unroll
                for (int r = 0; r < 4; r++) rm = fmaxf(rm, sc[kt][qt][r]);
            rm = fmaxf(rm, __shfl_xor(rm, 16));
            rm = fmaxf(rm, __shfl_xor(rm, 32));
            float mnew = fmaxf(m_st[qt], rm);
            float corr = __expf(m_st[qt] - mnew);
            m_st[qt] = mnew;
            float ps = 0.f;
            #pragma unroll
            for (int kt = 0; kt < 4; kt++) {
                union { uint2 u; short s[4]; } pk;
                #pragma unroll
                for (int r = 0; r < 4; r++) {
                    float p = __expf(sc[kt][qt][r] - mnew);
                    ps += p;
                    pk.s[r] = f2bf_s(p);
                }
                *(uint2*)&myP[(qt * 16 + l16) * 64 +
                              (((kt * 2 + (quad >> 1)) ^ (l16 & 7)) * 8) + (quad & 1) * 4] = pk.u;
            }
            ps += __shfl_xor(ps, 16);
            ps += __shfl_xor(ps, 32);
            l_st[qt] = l_st[qt] * corr + ps;
            #pragma unroll
            for (int dt = 0; dt < 4; dt++) accO[dt][qt] *= corr;
        }
        asm volatile("" ::: "memory");   // keep pf reads after P writes (same-wave DS is in-order)
        // PV: O^T += V^T @ P^T
        #pragma unroll
        for (int qt = 0; qt < 4; qt++) {
            bf16x8 pf0 = *(bf16x8*)&myP[(qt * 16 + l16) * 64 + ((quad ^ (l16 & 7)) * 8)];
            bf16x8 pf1 = *(bf16x8*)&myP[(qt * 16 + l16) * 64 + (((4 + quad) ^ (l16 & 7)) * 8)];
            #pragma unroll
            for (int dt = 0; dt < 4; dt++) {
                accO[dt][qt] = __builtin_amdgcn_mfma_f32_16x16x32_bf16(vf[dt][0], pf0, accO[dt][qt], 0, 0, 0);
                accO[dt][qt] = __builtin_amdgcn_mfma_f32_16x16x32_bf16(vf[dt][1], pf1, accO[dt][qt], 0, 0, 0);
            }
        }
        __syncthreads();   // drains prefetch (full compute phase to land); next buffer ready
        buf ^= 1;
    }

    // epilogue: O = O^T / l, pack 4 consecutive dims per b64 store
    #pragma unroll
    for (int qt = 0; qt < 4; qt++) {
        float inv = 1.f / l_st[qt];
        int row = qb0 + qt * 16 + l16;
        __hip_bfloat16* orow = ao + ((size_t)(b * SEQ + row)) * D_MODEL + hh * HS;
        #pragma unroll
        for (int dt = 0; dt < 4; dt++) {
            union { uint2 u; short s[4]; } pk;
            #pragma unroll
            for (int r = 0; r < 4; r++) pk.s[r] = f2bf_s(accO[dt][qt][r] * inv);
            *(uint2*)(orow + dt * 16 + quad * 4) = pk.u;
        }
    }
}

// ---------------------------------------------------------------- head FC1: (8,768)@(768,3072)+relu
__global__ __launch_bounds__(256) void fc1_kernel(
    const float* __restrict__ A, const float* __restrict__ W,
    const float* __restrict__ bias, float* __restrict__ out)
{
    __shared__ float sa[D_MODEL];
    int row = blockIdx.x, t = threadIdx.x;
    for (int i = t; i < D_MODEL; i += 256) sa[i] = A[(size_t)row * D_MODEL + i];
    __syncthreads();
    int col = blockIdx.y * 256 + t;
    float s = 0.f;
    #pragma unroll 8
    for (int kk = 0; kk < D_MODEL; kk++) s = fmaf(sa[kk], W[(size_t)kk * DFF + col], s);
    s += bias[col];
    out[(size_t)row * DFF + col] = fmaxf(s, 0.f);
}

// ---------------------------------------------------------------- head FC2: (8,3072)@(3072,16)
__global__ __launch_bounds__(256) void fc2_kernel(
    const float* __restrict__ A, const float* __restrict__ W,
    const float* __restrict__ bias, float* __restrict__ out)
{
    __shared__ float wred[4][NCLS];
    int row = blockIdx.x, t = threadIdx.x;
    int wave = t >> 6, lane = t & 63;
    const float* a = A + (size_t)row * DFF;
    float acc[NCLS];
    #pragma unroll
    for (int c = 0; c < NCLS; c++) acc[c] = 0.f;
    for (int kk = t; kk < DFF; kk += 256) {
        float av = a[kk];
        const float4* wr = (const float4*)(W + (size_t)kk * NCLS);
        float4 w0 = wr[0], w1 = wr[1], w2 = wr[2], w3 = wr[3];
        acc[0]  = fmaf(av, w0.x, acc[0]);  acc[1]  = fmaf(av, w0.y, acc[1]);
        acc[2]  = fmaf(av, w0.z, acc[2]);  acc[3]  = fmaf(av, w0.w, acc[3]);
        acc[4]  = fmaf(av, w1.x, acc[4]);  acc[5]  = fmaf(av, w1.y, acc[5]);
        acc[6]  = fmaf(av, w1.z, acc[6]);  acc[7]  = fmaf(av, w1.w, acc[7]);
        acc[8]  = fmaf(av, w2.x, acc[8]);  acc[9]  = fmaf(av, w2.y, acc[9]);
        acc[10] = fmaf(av, w2.z, acc[10]); acc[11] = fmaf(av, w2.w, acc[11]);
        acc[12] = fmaf(av, w3.x, acc[12]); acc[13] = fmaf(av, w3.y, acc[13]);
        acc[14] = fmaf(av, w3.z, acc[14]); acc[15] = fmaf(av, w3.w, acc[15]);
    }
    #pragma unroll
    for (int c = 0; c < NCLS; c++)
        #pragma unroll
        for (int off = 32; off; off >>= 1) acc[c] += __shfl_down(acc[c], off);
    if (lane == 0)
        #pragma unroll
        for (int c = 0; c < NCLS; c++) wred[wave][c] = acc[c];
    __syncthreads();
    if (t < NCLS)
        out[row * NCLS + t] = wred[0][t] + wred[1][t] + wred[2][t] + wred[3][t] + bias[t];
}

// ---------------------------------------------------------------- launch
extern "C" void kernel_launch(void* const* d_in, const int* in_sizes, int n_in,
                              void* d_out, int out_size, void* d_ws, size_t ws_size,
                              hipStream_t stream)
{
    const int*   x     = (const int*)  d_in[0];
    const int*   amask = (const int*)  d_in[1];
    const float* tok   = (const float*)d_in[2];
    const float* pos   = (const float*)d_in[3];
    const float* Wq    = (const float*)d_in[4];
    const float* Wk    = (const float*)d_in[5];
    const float* Wv    = (const float*)d_in[6];
    const float* Wo    = (const float*)d_in[7];
    const float* bo    = (const float*)d_in[8];
    const float* ln1w  = (const float*)d_in[9];
    const float* ln1b  = (const float*)d_in[10];
    const float* ln2w  = (const float*)d_in[11];
    const float* ln2b  = (const float*)d_in[12];
    const float* W1    = (const float*)d_in[13];
    const float* b1    = (const float*)d_in[14];
    const float* W2    = (const float*)d_in[15];
    const float* b2    = (const float*)d_in[16];
    const float* lnfw  = (const float*)d_in[17];
    const float* lnfb  = (const float*)d_in[18];
    const float* cW1   = (const float*)d_in[19];
    const float* cb1   = (const float*)d_in[20];
    const float* cW2   = (const float*)d_in[21];
    const float* cb2   = (const float*)d_in[22];

    char* base = (char*)d_ws;
    const size_t MD = (size_t)MROWS * D_MODEL;
    float* h = (float*)base;                         base += MD * 4;
    __hip_bfloat16* xn = (__hip_bfloat16*)base;      base += MD * 2;
    __hip_bfloat16* qb = (__hip_bfloat16*)base;      base += MD * 2;
    __hip_bfloat16* kb = (__hip_bfloat16*)base;      base += MD * 2;
    __hip_bfloat16* vb = (__hip_bfloat16*)base;      base += MD * 2;   // holds V^T (bh,e,s)
    __hip_bfloat16* vT = (__hip_bfloat16*)base;      base += MD * 2;   // unused (kept for layout)
    __hip_bfloat16* ff = (__hip_bfloat16*)base;      base += (size_t)MROWS * DFF * 2;
    float* lnf = (float*)base;                       base += (size_t)NB * D_MODEL * 4;
    float* cls = (float*)base;                       base += (size_t)NB * DFF * 4;
    __hip_bfloat16* wQKV = (__hip_bfloat16*)base;    base += (size_t)NLAYER * 3 * D_MODEL * D_MODEL * 2;
    __hip_bfloat16* wTo = (__hip_bfloat16*)base;     base += (size_t)NLAYER * D_MODEL * D_MODEL * 2;
    __hip_bfloat16* wT1 = (__hip_bfloat16*)base;     base += (size_t)NLAYER * D_MODEL * DFF * 2;
    __hip_bfloat16* wT2 = (__hip_bfloat16*)base;     base += (size_t)NLAYER * DFF * D_MODEL * 2;
    (void)vT;

    const size_t SQW = (size_t)D_MODEL * D_MODEL;
    const size_t SFF = (size_t)D_MODEL * DFF;

    convw_kernel<1><<<dim3(12,12,4), 256, 0, stream>>>(Wq, wQKV + 0 * SQW, D_MODEL, D_MODEL, SQW, 3 * SQW);
    convw_kernel<1><<<dim3(12,12,4), 256, 0, stream>>>(Wk, wQKV + 1 * SQW, D_MODEL, D_MODEL, SQW, 3 * SQW);
    convw_kernel<1><<<dim3(12,12,4), 256, 0, stream>>>(Wv, wQKV + 2 * SQW, D_MODEL, D_MODEL, SQW, 3 * SQW);
    convw_kernel<0><<<dim3(12,12,4), 256, 0, stream>>>(Wo, wTo, D_MODEL, D_MODEL, SQW, SQW);
    convw_kernel<0><<<dim3(12,48,4), 256, 0, stream>>>(W1, wT1, D_MODEL, DFF, SFF, SFF);
    convw_kernel<0><<<dim3(48,12,4), 256, 0, stream>>>(W2, wT2, DFF, D_MODEL, SFF, SFF);

    embed_kernel<<<MROWS / 4, 256, 0, stream>>>(x, tok, pos, h);

    dim3 gQKV(MROWS / 128, (3 * D_MODEL) / 128);
    dim3 gDS(MROWS / 128, D_MODEL / 128, 2);   // split-K=2
    dim3 gF(MROWS / 128, DFF / 128);
    for (int l = 0; l < NLAYER; l++) {
        ln_kernel<1><<<MROWS / 4, 256, 0, stream>>>(h, ln1w + l * D_MODEL, ln1b + l * D_MODEL, xn, 1, 0);
        gemm128<1><<<gQKV, 512, 0, stream>>>(xn, wQKV + l * 3 * SQW, nullptr, nullptr, qb, MROWS, 3 * D_MODEL, D_MODEL, 0);
        attn_mfma_kernel<<<NB * NHEAD * 4, 256, 0, stream>>>(qb, kb, vb, amask, xn);
        gemm128<3><<<gDS, 512, 0, stream>>>(xn, wTo + l * SQW, bo + l * D_MODEL, nullptr, h, MROWS, D_MODEL, D_MODEL, 0);
        ln_kernel<1><<<MROWS / 4, 256, 0, stream>>>(h, ln2w + l * D_MODEL, ln2b + l * D_MODEL, xn, 1, 0);
        gemm128<2><<<gF, 512, 0, stream>>>(xn, wT1 + l * SFF, b1 + l * DFF, nullptr, ff, MROWS, DFF, D_MODEL, 1);
        gemm128<3><<<gDS, 512, 0, stream>>>(ff, wT2 + l * SFF, b2 + l * D_MODEL, nullptr, h, MROWS, D_MODEL, DFF, 0);
    }
    ln_kernel<0><<<NB / 4, 256, 0, stream>>>(h, lnfw, lnfb, lnf, SEQ, SEQ - 1);
    fc1_kernel<<<dim3(NB, DFF / 256), 256, 0, stream>>>(lnf, cW1, cb1, cls);
    fc2_kernel<<<NB, 256, 0, stream>>>(cls, cW2, cb2, (float*)d_out);
}